// Round 1
// baseline (2915.897 us; speedup 1.0000x reference)
//
#include <hip/hip_runtime.h>
#include <math.h>

#define BB 32
#define NN 512
#define TT 24
#define CC 64
#define CT 1536   // CC*TT
#define YD 3624   // 151*TT

// ---------------- small precompute: w0u3[t'][t] = sum_f u3a[f]*u0_w[(f*24+t')*24+t], etc.
__global__ void k_prep0(const float* __restrict__ u0_w, const float* __restrict__ u0_b,
                        const float* __restrict__ u1a, const float* __restrict__ u3a,
                        const float* __restrict__ u1b,
                        float* __restrict__ w0u3, float* __restrict__ b0u3, float* __restrict__ sums){
  int tid = threadIdx.x;
  if (tid < 576){
    int tp = tid / TT, t = tid % TT;
    float acc = 0.f;
    for (int f = 0; f < CC; ++f) acc += u3a[f] * u0_w[(f*TT + tp)*TT + t];
    w0u3[tid] = acc;
  }
  if (tid < TT){
    float acc = 0.f;
    for (int f = 0; f < CC; ++f) acc += u3a[f] * u0_b[f*TT + tid];
    b0u3[tid] = acc;
  }
  if (tid == 0){ float s = 0.f; for (int n = 0; n < NN; ++n) s += u1a[n]; sums[0] = s; }
  if (tid == 1){ float s = 0.f; for (int n = 0; n < NN; ++n) s += u1b[n]; sums[1] = s; }
}

// ---------------- dt[b][o] = dot(y[b,:], tl_w[o,:]) + tl_b[o]   (o = t*64+c)
__global__ void k_dt(const float* __restrict__ y, const float* __restrict__ tl_w,
                     const float* __restrict__ tl_b, float* __restrict__ dt){
  __shared__ float row[YD];
  int o = blockIdx.x;
  for (int j = threadIdx.x; j < YD; j += 256) row[j] = tl_w[(size_t)o*YD + j];
  __syncthreads();
  int wv = threadIdx.x >> 6, ln = threadIdx.x & 63;
  float bias = tl_b[o];
  for (int b = wv; b < BB; b += 4){
    float acc = 0.f;
    const float* yb = y + (size_t)b*YD;
    for (int j = ln; j < YD; j += 64) acc += row[j]*yb[j];
    for (int off = 32; off; off >>= 1) acc += __shfl_down(acc, off);
    if (ln == 0) dt[b*CT + o] = acc + bias;
  }
}

// ---------------- temporal attention 1 reductions (x64 folded analytically)
__global__ void k_att1_pre(const float* __restrict__ x, const float* __restrict__ dt,
                           const float* __restrict__ u0_w, const float* __restrict__ u0_b,
                           const float* __restrict__ u1a, const float* __restrict__ u2a,
                           const float* __restrict__ u3a,
                           const float* __restrict__ w0u3, const float* __restrict__ b0u3,
                           const float* __restrict__ sums,
                           float* __restrict__ lhs1, float* __restrict__ rhs1){
  __shared__ float xu_s[TT], du3_s[TT], w1_s[CC*TT], w0u3_s[576], b0u3_s[TT], u1a_s[NN];
  int b = blockIdx.x, tid = threadIdx.x;
  for (int i = tid; i < 576; i += 256) w0u3_s[i] = w0u3[i];
  for (int i = tid; i < NN; i += 256) u1a_s[i] = u1a[i];
  if (tid < TT){
    b0u3_s[tid] = b0u3[tid];
    float acc = 0.f;
    for (int f = 0; f < CC; ++f) acc += u3a[f]*dt[b*CT + tid*CC + f];
    du3_s[tid] = acc;
  }
  __syncthreads();
  // xu[t] = sum_n u1a[n]*x[b,n,t]
  int wv = tid >> 6, ln = tid & 63;
  for (int t = wv; t < TT; t += 4){
    float acc = 0.f;
    for (int n = ln; n < NN; n += 64) acc += u1a_s[n]*x[(size_t)(b*NN + n)*TT + t];
    for (int off = 32; off; off >>= 1) acc += __shfl_down(acc, off);
    if (ln == 0) xu_s[t] = acc;
  }
  __syncthreads();
  float S1 = sums[0];
  // w1[f][t'] = sum_t u0_w[(f*24+t')*24+t]*xu[t] + S1*(u0_b[f*24+t'] + dt[b,t',f])
  for (int idx = tid; idx < CC*TT; idx += 256){
    int f = idx / TT, tp = idx % TT;
    float acc = 0.f;
    const float* wrow = u0_w + (f*TT + tp)*TT;
    for (int t = 0; t < TT; ++t) acc += wrow[t]*xu_s[t];
    w1_s[idx] = acc + S1*(u0_b[f*TT + tp] + dt[b*CT + tp*CC + f]);
  }
  __syncthreads();
  // rhs1[b][n][t'] = sum_t w0u3[t'][t]*x[b,n,t] + b0u3[t'] + du3[t']
  for (int idx = tid; idx < NN*TT; idx += 256){
    int n = idx / TT, tp = idx % TT;
    float acc = b0u3_s[tp] + du3_s[tp];
    const float* xr = x + (size_t)(b*NN + n)*TT;
    const float* wr = w0u3_s + tp*TT;
    for (int t = 0; t < TT; ++t) acc += wr[t]*xr[t];
    rhs1[(size_t)b*NN*TT + idx] = acc;
  }
  // lhs1[b][t][m] = sum_f u2a[f,m]*w1[f][t]
  for (int idx = tid; idx < TT*NN; idx += 256){
    int t = idx / NN, m = idx % NN;
    float acc = 0.f;
    for (int f = 0; f < CC; ++f) acc += u2a[f*NN + m]*w1_s[f*TT + t];
    lhs1[(size_t)b*TT*NN + idx] = acc;
  }
}

// ---------------- shared attention tail: prod -> sigmoid -> ve -> softmax(axis t)
__global__ void k_att_post(const float* __restrict__ lhs, const float* __restrict__ rhs,
                           const float* __restrict__ ve, const float* __restrict__ be,
                           float* __restrict__ E){
  __shared__ float sig_s[TT*TT], E_s[TT*TT];
  int b = blockIdx.x, tid = threadIdx.x;
  if (tid < 576){
    int t = tid / TT, s = tid % TT;
    float acc = 0.f;
    const float* lr = lhs + (size_t)b*TT*NN + t*NN;
    const float* rr = rhs + (size_t)b*NN*TT + s;
    for (int n = 0; n < NN; ++n) acc += lr[n]*rr[n*TT];
    sig_s[tid] = 1.f/(1.f + expf(-(acc + be[tid])));
  }
  __syncthreads();
  if (tid < 576){
    int t = tid / TT, r = tid % TT;
    float acc = 0.f;
    for (int s = 0; s < TT; ++s) acc += ve[t*TT + s]*sig_s[s*TT + r];
    E_s[tid] = acc;
  }
  __syncthreads();
  if (tid < TT){
    int r = tid;
    float mx = -1e30f;
    for (int t = 0; t < TT; ++t) mx = fmaxf(mx, E_s[t*TT + r]);
    float sum = 0.f;
    for (int t = 0; t < TT; ++t) sum += expf(E_s[t*TT + r] - mx);
    float inv = 1.f/sum;
    for (int t = 0; t < TT; ++t) E[(size_t)b*TT*TT + t*TT + r] = expf(E_s[t*TT + r] - mx)*inv;
  }
}

// ---------------- x_tat = x @ E1, plus lx/r2 for spatial attention
__global__ void k_xtat(const float* __restrict__ x, const float* __restrict__ E1,
                       const float* __restrict__ sw1, const float* __restrict__ sw2,
                       const float* __restrict__ sw3,
                       float* __restrict__ xtat, float* __restrict__ lx, float* __restrict__ r2){
  __shared__ float E_s[TT*TT], sw1_s[TT], sw2_s[TT];
  int b = blockIdx.x >> 1, half = blockIdx.x & 1, tid = threadIdx.x;
  for (int i = tid; i < 576; i += 256) E_s[i] = E1[(size_t)b*576 + i];
  if (tid < TT){ sw1_s[tid] = sw1[tid]; sw2_s[tid] = sw2[tid]; }
  __syncthreads();
  int n = half*256 + tid;
  float xr[TT];
  const float* xp = x + (size_t)(b*NN + n)*TT;
  for (int t = 0; t < TT; ++t) xr[t] = xp[t];
  float l = 0.f, r = 0.f;
  float* xo = xtat + (size_t)(b*NN + n)*TT;
  for (int s = 0; s < TT; ++s){
    float acc = 0.f;
    for (int t = 0; t < TT; ++t) acc += xr[t]*E_s[t*TT + s];
    xo[s] = acc;
    l += acc*sw1_s[s];
    r += acc*sw2_s[s];
  }
  lx[b*NN + n] = l;
  r2[b*NN + n] = r*sw3[0];
}

// ---------------- S0[b] = s_vs @ sigmoid(lx[b]⊗r2[b] + s_bs)   (128x128 tile, 8x8 micro)
__global__ __launch_bounds__(256) void k_S0(const float* __restrict__ s_vs, const float* __restrict__ s_bs,
                    const float* __restrict__ lx, const float* __restrict__ r2,
                    float* __restrict__ S0){
  __shared__ float As[128][17], Bs[128][17];
  int kt = blockIdx.x, nt = blockIdx.y, b = blockIdx.z;
  int n0 = nt*128, k0 = kt*128, tid = threadIdx.x;
  int tr = tid >> 4, tc = tid & 15;
  float acc[8][8];
  #pragma unroll
  for (int i = 0; i < 8; ++i)
    #pragma unroll
    for (int j = 0; j < 8; ++j) acc[i][j] = 0.f;
  const float* lxb = lx + b*NN;
  const float* r2b = r2 + b*NN;
  for (int m0 = 0; m0 < NN; m0 += 16){
    for (int p = 0; p < 8; ++p){
      int idx = tid + p*256;
      int r = idx >> 4, cc = idx & 15;
      As[r][cc] = s_vs[(size_t)(n0 + r)*NN + m0 + cc];
      int mm = idx >> 7, j = idx & 127;
      float v = lxb[m0 + mm]*r2b[k0 + j] + s_bs[(size_t)(m0 + mm)*NN + k0 + j];
      Bs[j][mm] = 1.f/(1.f + expf(-v));
    }
    __syncthreads();
    #pragma unroll
    for (int kk = 0; kk < 16; ++kk){
      float a[8], bv[8];
      #pragma unroll
      for (int ii = 0; ii < 8; ++ii) a[ii] = As[tr*8 + ii][kk];
      #pragma unroll
      for (int jj = 0; jj < 8; ++jj) bv[jj] = Bs[tc*8 + jj][kk];
      #pragma unroll
      for (int ii = 0; ii < 8; ++ii)
        #pragma unroll
        for (int jj = 0; jj < 8; ++jj) acc[ii][jj] += a[ii]*bv[jj];
    }
    __syncthreads();
  }
  for (int ii = 0; ii < 8; ++ii){
    int i = n0 + tr*8 + ii;
    for (int jj = 0; jj < 8; ++jj){
      S0[(size_t)b*NN*NN + (size_t)i*NN + k0 + tc*8 + jj] = acc[ii][jj];
    }
  }
}

// ---------------- column softmax over n (axis=1) in place
__global__ void k_softmaxS(float* __restrict__ S){
  int b = blockIdx.y;
  int k = blockIdx.x*256 + threadIdx.x;
  float* Sb = S + (size_t)b*NN*NN + k;
  float mx = -1e30f;
  for (int n = 0; n < NN; ++n) mx = fmaxf(mx, Sb[(size_t)n*NN]);
  float sum = 0.f;
  for (int n = 0; n < NN; ++n){ float e = expf(Sb[(size_t)n*NN] - mx); sum += e; Sb[(size_t)n*NN] = e; }
  float inv = 1.f/sum;
  for (int n = 0; n < NN; ++n) Sb[(size_t)n*NN] *= inv;
}

// ---------------- tmp_k[b,i,t] = sum_j cheb[k][j,i]*S[b,j,i]*x[b,j,t]
__global__ __launch_bounds__(384) void k_tmp(const float* __restrict__ S, const float* __restrict__ cheb,
                     const float* __restrict__ x, float* __restrict__ tmp){
  __shared__ float Ssub[NN*16];   // S[b, j, i0+ii]
  int i0 = blockIdx.x*16, b = blockIdx.y, tid = threadIdx.x;
  for (int idx = tid; idx < NN*16; idx += 384){
    int j = idx >> 4, ii = idx & 15;
    Ssub[idx] = S[(size_t)b*NN*NN + (size_t)j*NN + i0 + ii];
  }
  __syncthreads();
  int ii = tid / TT, t = tid % TT;       // 384 = 16*24
  const float* xb = x + (size_t)b*NN*TT;
  const float* c0 = cheb;
  const float* c1 = cheb + (size_t)NN*NN;
  const float* c2 = cheb + (size_t)2*NN*NN;
  float a0 = 0.f, a1 = 0.f, a2 = 0.f;
  for (int j = 0; j < NN; ++j){
    float sx = Ssub[j*16 + ii]*xb[j*TT + t];
    a0 += c0[(size_t)j*NN + i0 + ii]*sx;
    a1 += c1[(size_t)j*NN + i0 + ii]*sx;
    a2 += c2[(size_t)j*NN + i0 + ii]*sx;
  }
  tmp[((size_t)(0*BB + b)*NN + i0 + ii)*TT + t] = a0;
  tmp[((size_t)(1*BB + b)*NN + i0 + ii)*TT + t] = a1;
  tmp[((size_t)(2*BB + b)*NN + i0 + ii)*TT + t] = a2;
}

// ---------------- temporal attention 2 reductions on g = relu(theta·tmp), g never materialized
__global__ void k_att2_pre(const float* __restrict__ tmp, const float* __restrict__ dt,
                           const float* __restrict__ theta,
                           const float* __restrict__ u1b, const float* __restrict__ u2b,
                           const float* __restrict__ u3b, const float* __restrict__ sums,
                           float* __restrict__ lhsg, float* __restrict__ rhsg){
  __shared__ float th_s[192], u3b_s[CC], u1b_s[NN], du3b_s[TT], w1g_s[CC*TT];
  __shared__ float tile[3*128*TT];
  int b = blockIdx.x, tid = threadIdx.x;
  for (int i = tid; i < 192; i += 256) th_s[i] = theta[i];
  for (int i = tid; i < CC; i += 256) u3b_s[i] = u3b[i];
  for (int i = tid; i < NN; i += 256) u1b_s[i] = u1b[i];
  if (tid < TT){
    float acc = 0.f;
    for (int f = 0; f < CC; ++f) acc += u3b[f]*dt[b*CT + tid*CC + f];
    du3b_s[tid] = acc;
  }
  __syncthreads();
  float acc6[6];
  #pragma unroll
  for (int p = 0; p < 6; ++p) acc6[p] = 0.f;
  for (int nt = 0; nt < 4; ++nt){
    for (int idx = tid; idx < 3*128*TT; idx += 256){
      int k = idx / (128*TT), rem = idx % (128*TT);
      int r = rem / TT, t = rem % TT;
      tile[idx] = tmp[((size_t)(k*BB + b)*NN + nt*128 + r)*TT + t];
    }
    __syncthreads();
    #pragma unroll
    for (int p = 0; p < 6; ++p){
      int oidx = tid + p*256;
      int f = oidx / TT, t = oidx % TT;
      float a = 0.f;
      for (int n = 0; n < 128; ++n){
        float v = th_s[f]*tile[n*TT + t] + th_s[64 + f]*tile[128*TT + n*TT + t]
                + th_s[128 + f]*tile[2*128*TT + n*TT + t];
        a += u1b_s[nt*128 + n]*fmaxf(v, 0.f);
      }
      acc6[p] += a;
    }
    __syncthreads();
  }
  float S2 = sums[1];
  #pragma unroll
  for (int p = 0; p < 6; ++p){
    int oidx = tid + p*256;
    int f = oidx / TT, t = oidx % TT;
    w1g_s[oidx] = acc6[p] + S2*dt[b*CT + t*CC + f];
  }
  __syncthreads();
  // rhs_g[b][n][t] = du3b[t] + sum_f u3b[f]*relu(theta_f · tmp[.,b,n,t])
  const float* t0 = tmp + (size_t)(0*BB + b)*NN*TT;
  const float* t1 = tmp + (size_t)(1*BB + b)*NN*TT;
  const float* t2 = tmp + (size_t)(2*BB + b)*NN*TT;
  for (int idx = tid; idx < NN*TT; idx += 256){
    int t = idx % TT;
    float a0 = t0[idx], a1 = t1[idx], a2 = t2[idx];
    float acc = du3b_s[t];
    for (int f = 0; f < CC; ++f){
      float v = th_s[f]*a0 + th_s[64 + f]*a1 + th_s[128 + f]*a2;
      acc += u3b_s[f]*fmaxf(v, 0.f);
    }
    rhsg[(size_t)b*NN*TT + idx] = acc;
  }
  // lhs_g[b][t][m] = sum_f u2b[f,m]*w1g[f][t]
  for (int idx = tid; idx < TT*NN; idx += 256){
    int t = idx / NN, m = idx % NN;
    float acc = 0.f;
    for (int f = 0; f < CC; ++f) acc += u2b[f*NN + m]*w1g_s[f*TT + t];
    lhsg[(size_t)b*TT*NN + idx] = acc;
  }
}

// ---------------- g2[b,n,f,t] = sum_s relu(theta_f·tmp[.,b,n,s]) * E2[b,s,t]  -> d_out (A of GEMM)
__global__ void k_g2(const float* __restrict__ tmp, const float* __restrict__ E2,
                     const float* __restrict__ theta, float* __restrict__ g2){
  __shared__ float E_s[TT*TT], th_s[192], tr[3*4*TT], g_s[4*CT];
  int b = blockIdx.y, n0 = blockIdx.x*4, tid = threadIdx.x;
  for (int i = tid; i < 576; i += 256) E_s[i] = E2[(size_t)b*576 + i];
  for (int i = tid; i < 192; i += 256) th_s[i] = theta[i];
  for (int i = tid; i < 288; i += 256){
    int k = i / 96, rem = i % 96, nn = rem / TT, s = rem % TT;
    tr[i] = tmp[((size_t)(k*BB + b)*NN + n0 + nn)*TT + s];
  }
  __syncthreads();
  for (int idx = tid; idx < 4*CT; idx += 256){
    int nn = idx / CT, rem = idx % CT, f = rem / TT, s = rem % TT;
    float v = th_s[f]*tr[nn*TT + s] + th_s[64 + f]*tr[96 + nn*TT + s] + th_s[128 + f]*tr[192 + nn*TT + s];
    g_s[idx] = fmaxf(v, 0.f);
  }
  __syncthreads();
  for (int idx = tid; idx < 4*CT; idx += 256){
    int nn = idx / CT, rem = idx % CT, f = rem / TT, t = rem % TT;
    float acc = 0.f;
    const float* gr = g_s + nn*CT + f*TT;
    for (int s = 0; s < TT; ++s) acc += gr[s]*E_s[s*TT + t];
    g2[(size_t)(b*NN + n0 + nn)*CT + rem] = acc;
  }
}

// ---------------- tlin = A(16384x1536) @ l1_w^T + l1_b   (128x128 tile, 8x8 micro)
__global__ __launch_bounds__(256) void k_gemm(const float* __restrict__ A, const float* __restrict__ W,
                      const float* __restrict__ bias, float* __restrict__ Cout){
  __shared__ float As[128][17], Bs[128][17];
  int o0 = blockIdx.x*128, i0 = blockIdx.y*128, tid = threadIdx.x;
  int trr = tid >> 4, tc = tid & 15;
  float acc[8][8];
  #pragma unroll
  for (int i = 0; i < 8; ++i)
    #pragma unroll
    for (int j = 0; j < 8; ++j) acc[i][j] = 0.f;
  for (int k0 = 0; k0 < CT; k0 += 16){
    for (int p = 0; p < 8; ++p){
      int idx = tid + p*256;
      int r = idx >> 4, cc = idx & 15;
      As[r][cc] = A[(size_t)(i0 + r)*CT + k0 + cc];
      Bs[r][cc] = W[(size_t)(o0 + r)*CT + k0 + cc];
    }
    __syncthreads();
    #pragma unroll
    for (int kk = 0; kk < 16; ++kk){
      float a[8], bv[8];
      #pragma unroll
      for (int ii = 0; ii < 8; ++ii) a[ii] = As[trr*8 + ii][kk];
      #pragma unroll
      for (int jj = 0; jj < 8; ++jj) bv[jj] = Bs[tc*8 + jj][kk];
      #pragma unroll
      for (int ii = 0; ii < 8; ++ii)
        #pragma unroll
        for (int jj = 0; jj < 8; ++jj) acc[ii][jj] += a[ii]*bv[jj];
    }
    __syncthreads();
  }
  for (int ii = 0; ii < 8; ++ii){
    int i = i0 + trr*8 + ii;
    for (int jj = 0; jj < 8; ++jj){
      int o = o0 + tc*8 + jj;
      Cout[(size_t)i*CT + o] = acc[ii][jj] + bias[o];
    }
  }
}

// ---------------- scrambled reshape + residual + relu + LayerNorm
__global__ __launch_bounds__(256) void k_final(const float* __restrict__ tlin, const float* __restrict__ x,
                      const float* __restrict__ res_w, const float* __restrict__ res_b,
                      const float* __restrict__ ln_g, const float* __restrict__ ln_b,
                      float* __restrict__ out){
  int idx = blockIdx.x*256 + threadIdx.x;   // over B*N*T
  int b = idx / (NN*TT);
  int p = idx % (NN*TT);
  int np = p / TT, tp = p % TT;
  int dlt = p / CT;
  int o = p % CT;
  float xv = x[(size_t)(b*NN + np)*TT + tp];
  const float* tb = tlin + (size_t)b*NN*CT;
  float z[CC];
  float sum = 0.f, sq = 0.f;
  #pragma unroll
  for (int c = 0; c < CC; ++c){
    float v = tb[(size_t)(c*8 + dlt)*CT + o] + xv*res_w[c] + res_b[c];
    v = fmaxf(v, 0.f);
    z[c] = v;
    sum += v; sq += v*v;
  }
  float mu = sum*(1.f/64.f);
  float var = sq*(1.f/64.f) - mu*mu;
  float rstd = rsqrtf(var + 1e-5f);
  float* ob = out + (size_t)(b*NN + np)*CC*TT + tp;
  #pragma unroll
  for (int c = 0; c < CC; ++c){
    ob[c*TT] = (z[c] - mu)*rstd*ln_g[c] + ln_b[c];
  }
}

extern "C" void kernel_launch(void* const* d_in, const int* in_sizes, int n_in,
                              void* d_out, int out_size, void* d_ws, size_t ws_size,
                              hipStream_t stream){
  const float* x    = (const float*)d_in[0];
  const float* y    = (const float*)d_in[1];
  const float* tl_w = (const float*)d_in[2];
  const float* tl_b = (const float*)d_in[3];
  const float* u0_w = (const float*)d_in[4];
  const float* u0_b = (const float*)d_in[5];
  const float* u1a  = (const float*)d_in[6];
  const float* u2a  = (const float*)d_in[7];
  const float* u3a  = (const float*)d_in[8];
  const float* be_a = (const float*)d_in[9];
  const float* ve_a = (const float*)d_in[10];
  const float* u1b  = (const float*)d_in[11];
  const float* u2b  = (const float*)d_in[12];
  const float* u3b  = (const float*)d_in[13];
  const float* be_b = (const float*)d_in[14];
  const float* ve_b = (const float*)d_in[15];
  const float* sw1  = (const float*)d_in[16];
  const float* sw2  = (const float*)d_in[17];
  const float* sw3  = (const float*)d_in[18];
  const float* s_bs = (const float*)d_in[19];
  const float* s_vs = (const float*)d_in[20];
  const float* cheb = (const float*)d_in[21];
  const float* theta= (const float*)d_in[22];
  const float* l1_w = (const float*)d_in[23];
  const float* l1_b = (const float*)d_in[24];
  const float* res_w= (const float*)d_in[25];
  const float* res_b= (const float*)d_in[26];
  const float* ln_g = (const float*)d_in[27];
  const float* ln_b = (const float*)d_in[28];
  float* out = (float*)d_out;
  float* ws  = (float*)d_ws;

  // ws layout (floats). S region aliased under tlin: S dead before k_gemm writes tlin.
  float* dt   = ws;               // 49152
  float* E1   = dt   + 49152;     // 18432
  float* E2   = E1   + 18432;     // 18432
  float* xtat = E2   + 18432;     // 393216
  float* lxp  = xtat + 393216;    // 16384
  float* r2p  = lxp  + 16384;     // 16384
  float* w0u3 = r2p  + 16384;     // 640 (576 used)
  float* b0u3 = w0u3 + 640;       // 64
  float* sums = b0u3 + 64;        // 64
  float* lhs1 = sums + 64;        // 393216
  float* rhs1 = lhs1 + 393216;    // 393216
  float* lhsg = rhs1 + 393216;    // 393216
  float* rhsg = lhsg + 393216;    // 393216
  float* tmp  = rhsg + 393216;    // 1179648
  float* big  = tmp  + 1179648;   // S: 8388608 floats, later tlin: 25165824 floats
  float* S    = big;
  float* tlin = big;
  float* g2   = (float*)d_out;    // scratch; fully rewritten by k_final at the end

  k_prep0<<<dim3(1), dim3(576), 0, stream>>>(u0_w, u0_b, u1a, u3a, u1b, w0u3, b0u3, sums);
  k_dt<<<dim3(1536), dim3(256), 0, stream>>>(y, tl_w, tl_b, dt);
  k_att1_pre<<<dim3(32), dim3(256), 0, stream>>>(x, dt, u0_w, u0_b, u1a, u2a, u3a, w0u3, b0u3, sums, lhs1, rhs1);
  k_att_post<<<dim3(32), dim3(576), 0, stream>>>(lhs1, rhs1, ve_a, be_a, E1);
  k_xtat<<<dim3(64), dim3(256), 0, stream>>>(x, E1, sw1, sw2, sw3, xtat, lxp, r2p);
  k_S0<<<dim3(4, 4, 32), dim3(256), 0, stream>>>(s_vs, s_bs, lxp, r2p, S);
  k_softmaxS<<<dim3(2, 32), dim3(256), 0, stream>>>(S);
  k_tmp<<<dim3(32, 32), dim3(384), 0, stream>>>(S, cheb, x, tmp);
  k_att2_pre<<<dim3(32), dim3(256), 0, stream>>>(tmp, dt, theta, u1b, u2b, u3b, sums, lhsg, rhsg);
  k_att_post<<<dim3(32), dim3(576), 0, stream>>>(lhsg, rhsg, ve_b, be_b, E2);
  k_g2<<<dim3(128, 32), dim3(256), 0, stream>>>(tmp, E2, theta, g2);
  k_gemm<<<dim3(12, 128), dim3(256), 0, stream>>>(g2, l1_w, l1_b, tlin);
  k_final<<<dim3(1536), dim3(256), 0, stream>>>(tlin, x, res_w, res_b, ln_g, ln_b, out);
}

// Round 2
// 1638.449 us; speedup vs baseline: 1.7797x; 1.7797x over previous
//
#include <hip/hip_runtime.h>
#include <hip/hip_bf16.h>
#include <math.h>

#define BB 32
#define NN 512
#define TT 24
#define CC 64
#define CT 1536   // CC*TT
#define YD 3624   // 151*TT

typedef __attribute__((ext_vector_type(4))) float f32x4;
typedef __attribute__((ext_vector_type(8))) short bf16x8;

// ---------------- small precompute
__global__ void k_prep0(const float* __restrict__ u0_w, const float* __restrict__ u0_b,
                        const float* __restrict__ u1a, const float* __restrict__ u3a,
                        const float* __restrict__ u1b,
                        float* __restrict__ w0u3, float* __restrict__ b0u3, float* __restrict__ sums){
  int tid = threadIdx.x;
  if (tid < 576){
    int tp = tid / TT, t = tid % TT;
    float acc = 0.f;
    for (int f = 0; f < CC; ++f) acc += u3a[f] * u0_w[(f*TT + tp)*TT + t];
    w0u3[tid] = acc;
  }
  if (tid < TT){
    float acc = 0.f;
    for (int f = 0; f < CC; ++f) acc += u3a[f] * u0_b[f*TT + tid];
    b0u3[tid] = acc;
  }
  if (tid == 0){ float s = 0.f; for (int n = 0; n < NN; ++n) s += u1a[n]; sums[0] = s; }
  if (tid == 1){ float s = 0.f; for (int n = 0; n < NN; ++n) s += u1b[n]; sums[1] = s; }
}

// ---------------- dt[b][o] = dot(y[b,:], tl_w[o,:]) + tl_b[o]
__global__ void k_dt(const float* __restrict__ y, const float* __restrict__ tl_w,
                     const float* __restrict__ tl_b, float* __restrict__ dt){
  __shared__ float row[YD];
  int o = blockIdx.x;
  for (int j = threadIdx.x; j < YD; j += 256) row[j] = tl_w[(size_t)o*YD + j];
  __syncthreads();
  int wv = threadIdx.x >> 6, ln = threadIdx.x & 63;
  float bias = tl_b[o];
  for (int b = wv; b < BB; b += 4){
    float acc = 0.f;
    const float* yb = y + (size_t)b*YD;
    for (int j = ln; j < YD; j += 64) acc += row[j]*yb[j];
    for (int off = 32; off; off >>= 1) acc += __shfl_down(acc, off);
    if (ln == 0) dt[b*CT + o] = acc + bias;
  }
}

// ---------------- temporal attention 1 reductions (x64 folded analytically)
__global__ void k_att1_pre(const float* __restrict__ x, const float* __restrict__ dt,
                           const float* __restrict__ u0_w, const float* __restrict__ u0_b,
                           const float* __restrict__ u1a, const float* __restrict__ u2a,
                           const float* __restrict__ u3a,
                           const float* __restrict__ w0u3, const float* __restrict__ b0u3,
                           const float* __restrict__ sums,
                           float* __restrict__ lhs1, float* __restrict__ rhs1){
  __shared__ float xu_s[TT], du3_s[TT], w1_s[CC*TT], w0u3_s[576], b0u3_s[TT], u1a_s[NN];
  int b = blockIdx.x, tid = threadIdx.x;
  for (int i = tid; i < 576; i += 256) w0u3_s[i] = w0u3[i];
  for (int i = tid; i < NN; i += 256) u1a_s[i] = u1a[i];
  if (tid < TT){
    b0u3_s[tid] = b0u3[tid];
    float acc = 0.f;
    for (int f = 0; f < CC; ++f) acc += u3a[f]*dt[b*CT + tid*CC + f];
    du3_s[tid] = acc;
  }
  __syncthreads();
  int wv = tid >> 6, ln = tid & 63;
  for (int t = wv; t < TT; t += 4){
    float acc = 0.f;
    for (int n = ln; n < NN; n += 64) acc += u1a_s[n]*x[(size_t)(b*NN + n)*TT + t];
    for (int off = 32; off; off >>= 1) acc += __shfl_down(acc, off);
    if (ln == 0) xu_s[t] = acc;
  }
  __syncthreads();
  float S1 = sums[0];
  for (int idx = tid; idx < CC*TT; idx += 256){
    int f = idx / TT, tp = idx % TT;
    float acc = 0.f;
    const float* wrow = u0_w + (f*TT + tp)*TT;
    for (int t = 0; t < TT; ++t) acc += wrow[t]*xu_s[t];
    w1_s[idx] = acc + S1*(u0_b[f*TT + tp] + dt[b*CT + tp*CC + f]);
  }
  __syncthreads();
  for (int idx = tid; idx < NN*TT; idx += 256){
    int n = idx / TT, tp = idx % TT;
    float acc = b0u3_s[tp] + du3_s[tp];
    const float* xr = x + (size_t)(b*NN + n)*TT;
    const float* wr = w0u3_s + tp*TT;
    for (int t = 0; t < TT; ++t) acc += wr[t]*xr[t];
    rhs1[(size_t)b*NN*TT + idx] = acc;
  }
  for (int idx = tid; idx < TT*NN; idx += 256){
    int t = idx / NN, m = idx % NN;
    float acc = 0.f;
    for (int f = 0; f < CC; ++f) acc += u2a[f*NN + m]*w1_s[f*TT + t];
    lhs1[(size_t)b*TT*NN + idx] = acc;
  }
}

// ---------------- shared attention tail: prod -> sigmoid -> ve -> softmax(axis t)
__global__ void k_att_post(const float* __restrict__ lhs, const float* __restrict__ rhs,
                           const float* __restrict__ ve, const float* __restrict__ be,
                           float* __restrict__ E){
  __shared__ float sig_s[TT*TT], E_s[TT*TT];
  int b = blockIdx.x, tid = threadIdx.x;
  if (tid < 576){
    int t = tid / TT, s = tid % TT;
    float acc = 0.f;
    const float* lr = lhs + (size_t)b*TT*NN + t*NN;
    const float* rr = rhs + (size_t)b*NN*TT + s;
    for (int n = 0; n < NN; ++n) acc += lr[n]*rr[n*TT];
    sig_s[tid] = 1.f/(1.f + expf(-(acc + be[tid])));
  }
  __syncthreads();
  if (tid < 576){
    int t = tid / TT, r = tid % TT;
    float acc = 0.f;
    for (int s = 0; s < TT; ++s) acc += ve[t*TT + s]*sig_s[s*TT + r];
    E_s[tid] = acc;
  }
  __syncthreads();
  if (tid < TT){
    int r = tid;
    float mx = -1e30f;
    for (int t = 0; t < TT; ++t) mx = fmaxf(mx, E_s[t*TT + r]);
    float sum = 0.f;
    for (int t = 0; t < TT; ++t) sum += expf(E_s[t*TT + r] - mx);
    float inv = 1.f/sum;
    for (int t = 0; t < TT; ++t) E[(size_t)b*TT*TT + t*TT + r] = expf(E_s[t*TT + r] - mx)*inv;
  }
}

// ---------------- lx/r2 for spatial attention (x_tat never materialized)
__global__ void k_xtat(const float* __restrict__ x, const float* __restrict__ E1,
                       const float* __restrict__ sw1, const float* __restrict__ sw2,
                       const float* __restrict__ sw3,
                       float* __restrict__ lx, float* __restrict__ r2){
  __shared__ float E_s[TT*TT], sw1_s[TT], sw2_s[TT];
  int b = blockIdx.x >> 1, half = blockIdx.x & 1, tid = threadIdx.x;
  for (int i = tid; i < 576; i += 256) E_s[i] = E1[(size_t)b*576 + i];
  if (tid < TT){ sw1_s[tid] = sw1[tid]; sw2_s[tid] = sw2[tid]; }
  __syncthreads();
  int n = half*256 + tid;
  float xr[TT];
  const float* xp = x + (size_t)(b*NN + n)*TT;
  for (int t = 0; t < TT; ++t) xr[t] = xp[t];
  float l = 0.f, r = 0.f;
  for (int s = 0; s < TT; ++s){
    float acc = 0.f;
    for (int t = 0; t < TT; ++t) acc += xr[t]*E_s[t*TT + s];
    l += acc*sw1_s[s];
    r += acc*sw2_s[s];
  }
  lx[b*NN + n] = l;
  r2[b*NN + n] = r*sw3[0];
}

// ---------------- S0[b] = s_vs @ sigmoid(lx[b]⊗r2[b] + s_bs)
__global__ __launch_bounds__(256) void k_S0(const float* __restrict__ s_vs, const float* __restrict__ s_bs,
                    const float* __restrict__ lx, const float* __restrict__ r2,
                    float* __restrict__ S0){
  __shared__ float As[128][17], Bs[128][17];
  int kt = blockIdx.x, nt = blockIdx.y, b = blockIdx.z;
  int n0 = nt*128, k0 = kt*128, tid = threadIdx.x;
  int tr = tid >> 4, tc = tid & 15;
  float acc[8][8];
  #pragma unroll
  for (int i = 0; i < 8; ++i)
    #pragma unroll
    for (int j = 0; j < 8; ++j) acc[i][j] = 0.f;
  const float* lxb = lx + b*NN;
  const float* r2b = r2 + b*NN;
  for (int m0 = 0; m0 < NN; m0 += 16){
    for (int p = 0; p < 8; ++p){
      int idx = tid + p*256;
      int r = idx >> 4, cc = idx & 15;
      As[r][cc] = s_vs[(size_t)(n0 + r)*NN + m0 + cc];
      int mm = idx >> 7, j = idx & 127;
      float v = lxb[m0 + mm]*r2b[k0 + j] + s_bs[(size_t)(m0 + mm)*NN + k0 + j];
      Bs[j][mm] = 1.f/(1.f + expf(-v));
    }
    __syncthreads();
    #pragma unroll
    for (int kk = 0; kk < 16; ++kk){
      float a[8], bv[8];
      #pragma unroll
      for (int ii = 0; ii < 8; ++ii) a[ii] = As[tr*8 + ii][kk];
      #pragma unroll
      for (int jj = 0; jj < 8; ++jj) bv[jj] = Bs[tc*8 + jj][kk];
      #pragma unroll
      for (int ii = 0; ii < 8; ++ii)
        #pragma unroll
        for (int jj = 0; jj < 8; ++jj) acc[ii][jj] += a[ii]*bv[jj];
    }
    __syncthreads();
  }
  for (int ii = 0; ii < 8; ++ii){
    int i = n0 + tr*8 + ii;
    for (int jj = 0; jj < 8; ++jj){
      S0[(size_t)b*NN*NN + (size_t)i*NN + k0 + tc*8 + jj] = acc[ii][jj];
    }
  }
}

// ---------------- column softmax over n (axis=1) in place
__global__ void k_softmaxS(float* __restrict__ S){
  int b = blockIdx.y;
  int k = blockIdx.x*256 + threadIdx.x;
  float* Sb = S + (size_t)b*NN*NN + k;
  float mx = -1e30f;
  for (int n = 0; n < NN; ++n) mx = fmaxf(mx, Sb[(size_t)n*NN]);
  float sum = 0.f;
  for (int n = 0; n < NN; ++n){ float e = expf(Sb[(size_t)n*NN] - mx); sum += e; Sb[(size_t)n*NN] = e; }
  float inv = 1.f/sum;
  for (int n = 0; n < NN; ++n) Sb[(size_t)n*NN] *= inv;
}

// ---------------- tmp_k[b,i,t] = sum_j cheb[k][j,i]*S[b,j,i]*x[b,j,t]
__global__ __launch_bounds__(384) void k_tmp(const float* __restrict__ S, const float* __restrict__ cheb,
                     const float* __restrict__ x, float* __restrict__ tmp){
  __shared__ float Ssub[NN*16];
  int i0 = blockIdx.x*16, b = blockIdx.y, tid = threadIdx.x;
  for (int idx = tid; idx < NN*16; idx += 384){
    int j = idx >> 4, ii = idx & 15;
    Ssub[idx] = S[(size_t)b*NN*NN + (size_t)j*NN + i0 + ii];
  }
  __syncthreads();
  int ii = tid / TT, t = tid % TT;
  const float* xb = x + (size_t)b*NN*TT;
  const float* c0 = cheb;
  const float* c1 = cheb + (size_t)NN*NN;
  const float* c2 = cheb + (size_t)2*NN*NN;
  float a0 = 0.f, a1 = 0.f, a2 = 0.f;
  for (int j = 0; j < NN; ++j){
    float sx = Ssub[j*16 + ii]*xb[j*TT + t];
    a0 += c0[(size_t)j*NN + i0 + ii]*sx;
    a1 += c1[(size_t)j*NN + i0 + ii]*sx;
    a2 += c2[(size_t)j*NN + i0 + ii]*sx;
  }
  tmp[((size_t)(0*BB + b)*NN + i0 + ii)*TT + t] = a0;
  tmp[((size_t)(1*BB + b)*NN + i0 + ii)*TT + t] = a1;
  tmp[((size_t)(2*BB + b)*NN + i0 + ii)*TT + t] = a2;
}

// ---------------- temporal attention 2 reductions on g (never materialized)
__global__ void k_att2_pre(const float* __restrict__ tmp, const float* __restrict__ dt,
                           const float* __restrict__ theta,
                           const float* __restrict__ u1b, const float* __restrict__ u2b,
                           const float* __restrict__ u3b, const float* __restrict__ sums,
                           float* __restrict__ lhsg, float* __restrict__ rhsg){
  __shared__ float th_s[192], u3b_s[CC], u1b_s[NN], du3b_s[TT], w1g_s[CC*TT];
  __shared__ float tile[3*128*TT];
  int b = blockIdx.x, tid = threadIdx.x;
  for (int i = tid; i < 192; i += 256) th_s[i] = theta[i];
  for (int i = tid; i < CC; i += 256) u3b_s[i] = u3b[i];
  for (int i = tid; i < NN; i += 256) u1b_s[i] = u1b[i];
  if (tid < TT){
    float acc = 0.f;
    for (int f = 0; f < CC; ++f) acc += u3b[f]*dt[b*CT + tid*CC + f];
    du3b_s[tid] = acc;
  }
  __syncthreads();
  float acc6[6];
  #pragma unroll
  for (int p = 0; p < 6; ++p) acc6[p] = 0.f;
  for (int nt = 0; nt < 4; ++nt){
    for (int idx = tid; idx < 3*128*TT; idx += 256){
      int k = idx / (128*TT), rem = idx % (128*TT);
      int r = rem / TT, t = rem % TT;
      tile[idx] = tmp[((size_t)(k*BB + b)*NN + nt*128 + r)*TT + t];
    }
    __syncthreads();
    #pragma unroll
    for (int p = 0; p < 6; ++p){
      int oidx = tid + p*256;
      int f = oidx / TT, t = oidx % TT;
      float a = 0.f;
      for (int n = 0; n < 128; ++n){
        float v = th_s[f]*tile[n*TT + t] + th_s[64 + f]*tile[128*TT + n*TT + t]
                + th_s[128 + f]*tile[2*128*TT + n*TT + t];
        a += u1b_s[nt*128 + n]*fmaxf(v, 0.f);
      }
      acc6[p] += a;
    }
    __syncthreads();
  }
  float S2 = sums[1];
  #pragma unroll
  for (int p = 0; p < 6; ++p){
    int oidx = tid + p*256;
    int f = oidx / TT, t = oidx % TT;
    w1g_s[oidx] = acc6[p] + S2*dt[b*CT + t*CC + f];
  }
  __syncthreads();
  const float* t0 = tmp + (size_t)(0*BB + b)*NN*TT;
  const float* t1 = tmp + (size_t)(1*BB + b)*NN*TT;
  const float* t2 = tmp + (size_t)(2*BB + b)*NN*TT;
  for (int idx = tid; idx < NN*TT; idx += 256){
    int t = idx % TT;
    float a0 = t0[idx], a1 = t1[idx], a2 = t2[idx];
    float acc = du3b_s[t];
    for (int f = 0; f < CC; ++f){
      float v = th_s[f]*a0 + th_s[64 + f]*a1 + th_s[128 + f]*a2;
      acc += u3b_s[f]*fmaxf(v, 0.f);
    }
    rhsg[(size_t)b*NN*TT + idx] = acc;
  }
  for (int idx = tid; idx < TT*NN; idx += 256){
    int t = idx / NN, m = idx % NN;
    float acc = 0.f;
    for (int f = 0; f < CC; ++f) acc += u2b[f*NN + m]*w1g_s[f*TT + t];
    lhsg[(size_t)b*TT*NN + idx] = acc;
  }
}

// ---------------- g2 (bf16) = relu(theta·tmp) @ E2  -> A-operand of the MFMA GEMM
__global__ void k_g2(const float* __restrict__ tmp, const float* __restrict__ E2,
                     const float* __restrict__ theta, __hip_bfloat16* __restrict__ g2){
  __shared__ float E_s[TT*TT], th_s[192], tr[3*4*TT], g_s[4*CT];
  int b = blockIdx.y, n0 = blockIdx.x*4, tid = threadIdx.x;
  for (int i = tid; i < 576; i += 256) E_s[i] = E2[(size_t)b*576 + i];
  for (int i = tid; i < 192; i += 256) th_s[i] = theta[i];
  for (int i = tid; i < 288; i += 256){
    int k = i / 96, rem = i % 96, nn = rem / TT, s = rem % TT;
    tr[i] = tmp[((size_t)(k*BB + b)*NN + n0 + nn)*TT + s];
  }
  __syncthreads();
  for (int idx = tid; idx < 4*CT; idx += 256){
    int nn = idx / CT, rem = idx % CT, f = rem / TT, s = rem % TT;
    float v = th_s[f]*tr[nn*TT + s] + th_s[64 + f]*tr[96 + nn*TT + s] + th_s[128 + f]*tr[192 + nn*TT + s];
    g_s[idx] = fmaxf(v, 0.f);
  }
  __syncthreads();
  for (int idx = tid; idx < 4*CT; idx += 256){
    int nn = idx / CT, rem = idx % CT, f = rem / TT, t = rem % TT;
    float acc = 0.f;
    const float* gr = g_s + nn*CT + f*TT;
    for (int s = 0; s < TT; ++s) acc += gr[s]*E_s[s*TT + t];
    g2[(size_t)(b*NN + n0 + nn)*CT + rem] = __float2bfloat16(acc);
  }
}

// ---------------- l1_w fp32 -> bf16
__global__ void k_convW(const float* __restrict__ W, __hip_bfloat16* __restrict__ Wb){
  int i = (blockIdx.x*256 + threadIdx.x)*4;
  float4 v = *(const float4*)(W + i);
  Wb[i+0] = __float2bfloat16(v.x);
  Wb[i+1] = __float2bfloat16(v.y);
  Wb[i+2] = __float2bfloat16(v.z);
  Wb[i+3] = __float2bfloat16(v.w);
}

// ---------------- tlin = A(16384x1536,bf16) @ W^T(bf16) + l1_b  — m97-style MFMA GEMM
__global__ __launch_bounds__(256) void k_gemm_bf16(const __hip_bfloat16* __restrict__ A,
                      const __hip_bfloat16* __restrict__ W,
                      const float* __restrict__ bias, float* __restrict__ Cout){
  __shared__ __align__(16) short lA[128*32];
  __shared__ __align__(16) short lB[128*32];
  int i0 = blockIdx.y*128, o0 = blockIdx.x*128;
  int tid = threadIdx.x;
  int w = tid >> 6, l = tid & 63;
  int wr = w >> 1, wc = w & 1;
  f32x4 acc[4][4];
  #pragma unroll
  for (int m = 0; m < 4; ++m)
    #pragma unroll
    for (int n = 0; n < 4; ++n) acc[m][n] = (f32x4){0.f,0.f,0.f,0.f};

  int lrow = l & 15, lk = (l >> 4);   // fragment lane decomposition
  for (int k0 = 0; k0 < CT; k0 += 32){
    #pragma unroll
    for (int p = 0; p < 2; ++p){
      int c = p*4 + w;               // chunk 0..7, 512 bf16 each
      int off = c*512 + l*8;
      int row = off >> 5, col = off & 31;
      __builtin_amdgcn_global_load_lds(
        (const __attribute__((address_space(1))) void*)(A + (size_t)(i0 + row)*CT + k0 + col),
        (__attribute__((address_space(3))) void*)(lA + c*512), 16, 0, 0);
      __builtin_amdgcn_global_load_lds(
        (const __attribute__((address_space(1))) void*)(W + (size_t)(o0 + row)*CT + k0 + col),
        (__attribute__((address_space(3))) void*)(lB + c*512), 16, 0, 0);
    }
    __syncthreads();
    bf16x8 a[4], bv[4];
    #pragma unroll
    for (int m = 0; m < 4; ++m){
      int row = wr*64 + m*16 + lrow;
      a[m] = *(const bf16x8*)(lA + row*32 + lk*8);
    }
    #pragma unroll
    for (int n = 0; n < 4; ++n){
      int row = wc*64 + n*16 + lrow;
      bv[n] = *(const bf16x8*)(lB + row*32 + lk*8);
    }
    #pragma unroll
    for (int m = 0; m < 4; ++m)
      #pragma unroll
      for (int n = 0; n < 4; ++n)
        acc[m][n] = __builtin_amdgcn_mfma_f32_16x16x32_bf16(a[m], bv[n], acc[m][n], 0, 0, 0);
    __syncthreads();
  }
  // C/D layout: col = lane&15, row = (lane>>4)*4 + reg
  #pragma unroll
  for (int m = 0; m < 4; ++m){
    #pragma unroll
    for (int n = 0; n < 4; ++n){
      int o = o0 + wc*64 + n*16 + lrow;
      float bo = bias[o];
      #pragma unroll
      for (int j = 0; j < 4; ++j){
        int i = i0 + wr*64 + m*16 + lk*4 + j;
        Cout[(size_t)i*CT + o] = acc[m][n][j] + bo;
      }
    }
  }
}

// ---------------- scrambled reshape + residual + relu + LayerNorm
__global__ __launch_bounds__(256) void k_final(const float* __restrict__ tlin, const float* __restrict__ x,
                      const float* __restrict__ res_w, const float* __restrict__ res_b,
                      const float* __restrict__ ln_g, const float* __restrict__ ln_b,
                      float* __restrict__ out){
  int idx = blockIdx.x*256 + threadIdx.x;
  int b = idx / (NN*TT);
  int p = idx % (NN*TT);
  int np = p / TT, tp = p % TT;
  int dlt = p / CT;
  int o = p % CT;
  float xv = x[(size_t)(b*NN + np)*TT + tp];
  const float* tb = tlin + (size_t)b*NN*CT;
  float z[CC];
  float sum = 0.f, sq = 0.f;
  #pragma unroll
  for (int c = 0; c < CC; ++c){
    float v = tb[(size_t)(c*8 + dlt)*CT + o] + xv*res_w[c] + res_b[c];
    v = fmaxf(v, 0.f);
    z[c] = v;
    sum += v; sq += v*v;
  }
  float mu = sum*(1.f/64.f);
  float var = sq*(1.f/64.f) - mu*mu;
  float rstd = rsqrtf(var + 1e-5f);
  float* ob = out + (size_t)(b*NN + np)*CC*TT + tp;
  #pragma unroll
  for (int c = 0; c < CC; ++c){
    ob[c*TT] = (z[c] - mu)*rstd*ln_g[c] + ln_b[c];
  }
}

extern "C" void kernel_launch(void* const* d_in, const int* in_sizes, int n_in,
                              void* d_out, int out_size, void* d_ws, size_t ws_size,
                              hipStream_t stream){
  const float* x    = (const float*)d_in[0];
  const float* y    = (const float*)d_in[1];
  const float* tl_w = (const float*)d_in[2];
  const float* tl_b = (const float*)d_in[3];
  const float* u0_w = (const float*)d_in[4];
  const float* u0_b = (const float*)d_in[5];
  const float* u1a  = (const float*)d_in[6];
  const float* u2a  = (const float*)d_in[7];
  const float* u3a  = (const float*)d_in[8];
  const float* be_a = (const float*)d_in[9];
  const float* ve_a = (const float*)d_in[10];
  const float* u1b  = (const float*)d_in[11];
  const float* u2b  = (const float*)d_in[12];
  const float* u3b  = (const float*)d_in[13];
  const float* be_b = (const float*)d_in[14];
  const float* ve_b = (const float*)d_in[15];
  const float* sw1  = (const float*)d_in[16];
  const float* sw2  = (const float*)d_in[17];
  const float* sw3  = (const float*)d_in[18];
  const float* s_bs = (const float*)d_in[19];
  const float* s_vs = (const float*)d_in[20];
  const float* cheb = (const float*)d_in[21];
  const float* theta= (const float*)d_in[22];
  const float* l1_w = (const float*)d_in[23];
  const float* l1_b = (const float*)d_in[24];
  const float* res_w= (const float*)d_in[25];
  const float* res_b= (const float*)d_in[26];
  const float* ln_g = (const float*)d_in[27];
  const float* ln_b = (const float*)d_in[28];
  float* out = (float*)d_out;
  float* ws  = (float*)d_ws;

  // ws layout (floats). Aliases:
  //  - Wbf16 (bf16, 1179648 floats worth) over lhs1+rhs1+lhsg (dead after E2)
  //  - tlin over S (S dead before k_gemm writes)
  float* dt   = ws;               // 49152
  float* E1   = dt   + 49152;     // 18432
  float* E2   = E1   + 18432;     // 18432
  float* lxp  = E2   + 18432;     // 16384
  float* r2p  = lxp  + 16384;     // 16384
  float* w0u3 = r2p  + 16384;     // 640
  float* b0u3 = w0u3 + 640;       // 64
  float* sums = b0u3 + 64;        // 64
  float* lhs1 = sums + 64;        // 393216
  float* rhs1 = lhs1 + 393216;    // 393216
  float* lhsg = rhs1 + 393216;    // 393216
  float* rhsg = lhsg + 393216;    // 393216
  float* tmp  = rhsg + 393216;    // 1179648
  float* big  = tmp  + 1179648;   // S: 8388608 floats, later tlin: 25165824 floats
  float* S    = big;
  float* tlin = big;
  __hip_bfloat16* Wb  = (__hip_bfloat16*)lhs1;   // 1536*1536 bf16 = 1179648 floats
  __hip_bfloat16* g2b = (__hip_bfloat16*)d_out;  // 16384*1536 bf16 = 50.3 MB, dead before k_final

  k_prep0<<<dim3(1), dim3(576), 0, stream>>>(u0_w, u0_b, u1a, u3a, u1b, w0u3, b0u3, sums);
  k_dt<<<dim3(1536), dim3(256), 0, stream>>>(y, tl_w, tl_b, dt);
  k_att1_pre<<<dim3(32), dim3(256), 0, stream>>>(x, dt, u0_w, u0_b, u1a, u2a, u3a, w0u3, b0u3, sums, lhs1, rhs1);
  k_att_post<<<dim3(32), dim3(576), 0, stream>>>(lhs1, rhs1, ve_a, be_a, E1);
  k_xtat<<<dim3(64), dim3(256), 0, stream>>>(x, E1, sw1, sw2, sw3, lxp, r2p);
  k_S0<<<dim3(4, 4, 32), dim3(256), 0, stream>>>(s_vs, s_bs, lxp, r2p, S);
  k_softmaxS<<<dim3(2, 32), dim3(256), 0, stream>>>(S);
  k_tmp<<<dim3(32, 32), dim3(384), 0, stream>>>(S, cheb, x, tmp);
  k_att2_pre<<<dim3(32), dim3(256), 0, stream>>>(tmp, dt, theta, u1b, u2b, u3b, sums, lhsg, rhsg);
  k_att_post<<<dim3(32), dim3(576), 0, stream>>>(lhsg, rhsg, ve_b, be_b, E2);
  k_convW<<<dim3(2304), dim3(256), 0, stream>>>(l1_w, Wb);
  k_g2<<<dim3(128, 32), dim3(256), 0, stream>>>(tmp, E2, theta, g2b);
  k_gemm_bf16<<<dim3(12, 128), dim3(256), 0, stream>>>(g2b, Wb, l1_b, tlin);
  k_final<<<dim3(1536), dim3(256), 0, stream>>>(tlin, x, res_w, res_b, ln_g, ln_b, out);
}

// Round 3
// 1034.261 us; speedup vs baseline: 2.8193x; 1.5842x over previous
//
#include <hip/hip_runtime.h>
#include <hip/hip_bf16.h>
#include <math.h>

#define BB 32
#define NN 512
#define TT 24
#define CC 64
#define CT 1536   // CC*TT
#define YD 3624   // 151*TT

typedef __attribute__((ext_vector_type(4))) float f32x4;
typedef __attribute__((ext_vector_type(8))) short bf16x8;

// ---------------- small precompute
__global__ void k_prep0(const float* __restrict__ u0_w, const float* __restrict__ u0_b,
                        const float* __restrict__ u1a, const float* __restrict__ u3a,
                        const float* __restrict__ u1b,
                        float* __restrict__ w0u3, float* __restrict__ b0u3, float* __restrict__ sums){
  int tid = threadIdx.x;
  if (tid < 576){
    int tp = tid / TT, t = tid % TT;
    float acc = 0.f;
    for (int f = 0; f < CC; ++f) acc += u3a[f] * u0_w[(f*TT + tp)*TT + t];
    w0u3[tid] = acc;
  }
  if (tid < TT){
    float acc = 0.f;
    for (int f = 0; f < CC; ++f) acc += u3a[f] * u0_b[f*TT + tid];
    b0u3[tid] = acc;
  }
  if (tid == 0){ float s = 0.f; for (int n = 0; n < NN; ++n) s += u1a[n]; sums[0] = s; }
  if (tid == 1){ float s = 0.f; for (int n = 0; n < NN; ++n) s += u1b[n]; sums[1] = s; }
}

// ---------------- dt[b][o] = dot(y[b,:], tl_w[o,:]) + tl_b[o]
__global__ void k_dt(const float* __restrict__ y, const float* __restrict__ tl_w,
                     const float* __restrict__ tl_b, float* __restrict__ dt){
  __shared__ float row[YD];
  int o = blockIdx.x;
  for (int j = threadIdx.x; j < YD; j += 256) row[j] = tl_w[(size_t)o*YD + j];
  __syncthreads();
  int wv = threadIdx.x >> 6, ln = threadIdx.x & 63;
  float bias = tl_b[o];
  for (int b = wv; b < BB; b += 4){
    float acc = 0.f;
    const float* yb = y + (size_t)b*YD;
    for (int j = ln; j < YD; j += 64) acc += row[j]*yb[j];
    for (int off = 32; off; off >>= 1) acc += __shfl_down(acc, off);
    if (ln == 0) dt[b*CT + o] = acc + bias;
  }
}

// ---------------- per-b small reductions: xu, du3a, du3b, w1a
__global__ void k_small(const float* __restrict__ x, const float* __restrict__ dt,
                        const float* __restrict__ u0_w, const float* __restrict__ u0_b,
                        const float* __restrict__ u1a, const float* __restrict__ u3a,
                        const float* __restrict__ u3b, const float* __restrict__ sums,
                        float* __restrict__ w1a, float* __restrict__ du3a, float* __restrict__ du3b){
  __shared__ float xu_s[TT], u1a_s[NN];
  int b = blockIdx.x, tid = threadIdx.x;
  for (int i = tid; i < NN; i += 256) u1a_s[i] = u1a[i];
  __syncthreads();
  int wv = tid >> 6, ln = tid & 63;
  for (int t = wv; t < TT; t += 4){
    float acc = 0.f;
    for (int n = ln; n < NN; n += 64) acc += u1a_s[n]*x[(size_t)(b*NN + n)*TT + t];
    for (int off = 32; off; off >>= 1) acc += __shfl_down(acc, off);
    if (ln == 0) xu_s[t] = acc;
  }
  if (tid < TT){
    float a = 0.f, c = 0.f;
    for (int f = 0; f < CC; ++f){
      float d = dt[b*CT + tid*CC + f];
      a += u3a[f]*d; c += u3b[f]*d;
    }
    du3a[b*TT + tid] = a;
    du3b[b*TT + tid] = c;
  }
  __syncthreads();
  float S1 = sums[0];
  for (int idx = tid; idx < CC*TT; idx += 256){
    int f = idx / TT, tp = idx % TT;
    float acc = 0.f;
    const float* wrow = u0_w + (f*TT + tp)*TT;
    for (int t = 0; t < TT; ++t) acc += wrow[t]*xu_s[t];
    w1a[b*CC*TT + idx] = acc + S1*(u0_b[f*TT + tp] + dt[b*CT + tp*CC + f]);
  }
}

// ---------------- rhs1[b][n][t'] = b0u3[t'] + du3a[b][t'] + sum_t w0u3[t'][t]*x[b,n,t]
__global__ __launch_bounds__(384) void k_rhs1(const float* __restrict__ x, const float* __restrict__ w0u3,
                      const float* __restrict__ b0u3, const float* __restrict__ du3a,
                      float* __restrict__ rhs1){
  __shared__ float xs[16*TT], w0_s[576], bd_s[TT];
  int b = blockIdx.y, n0 = blockIdx.x*16, tid = threadIdx.x;
  for (int i = tid; i < 576; i += 384) w0_s[i] = w0u3[i];
  if (tid < TT) bd_s[tid] = b0u3[tid] + du3a[b*TT + tid];
  xs[tid] = x[(size_t)(b*NN + n0)*TT + tid];
  __syncthreads();
  int nn = tid / TT, tp = tid % TT;
  float acc = bd_s[tp];
  const float* wr = w0_s + tp*TT;
  const float* xr = xs + nn*TT;
  for (int t = 0; t < TT; ++t) acc += wr[t]*xr[t];
  rhs1[(size_t)b*NN*TT + (n0 + nn)*TT + tp] = acc;
}

// ---------------- lhs[b][t][m] = sum_f u2[f,m]*w1[b][f][t]   (shared by att1/att2)
__global__ void k_lhs(const float* __restrict__ u2, const float* __restrict__ w1,
                      float* __restrict__ lhs){
  int b = blockIdx.y;
  int j = blockIdx.x*256 + threadIdx.x;   // 0..12287 over (t,m)
  int t = j >> 9, m = j & 511;
  const float* w = w1 + b*CC*TT;
  float acc = 0.f;
  #pragma unroll 8
  for (int f = 0; f < CC; ++f) acc += u2[f*NN + m]*w[f*TT + t];
  lhs[(size_t)b*TT*NN + j] = acc;
}

// ---------------- shared attention tail: prod -> sigmoid -> ve -> softmax(axis t)
__global__ void k_att_post(const float* __restrict__ lhs, const float* __restrict__ rhs,
                           const float* __restrict__ ve, const float* __restrict__ be,
                           float* __restrict__ E){
  __shared__ float sig_s[TT*TT], E_s[TT*TT];
  int b = blockIdx.x, tid = threadIdx.x;
  if (tid < 576){
    int t = tid / TT, s = tid % TT;
    float acc = 0.f;
    const float* lr = lhs + (size_t)b*TT*NN + t*NN;
    const float* rr = rhs + (size_t)b*NN*TT + s;
    for (int n = 0; n < NN; ++n) acc += lr[n]*rr[n*TT];
    sig_s[tid] = 1.f/(1.f + expf(-(acc + be[tid])));
  }
  __syncthreads();
  if (tid < 576){
    int t = tid / TT, r = tid % TT;
    float acc = 0.f;
    for (int s = 0; s < TT; ++s) acc += ve[t*TT + s]*sig_s[s*TT + r];
    E_s[tid] = acc;
  }
  __syncthreads();
  if (tid < TT){
    int r = tid;
    float mx = -1e30f;
    for (int t = 0; t < TT; ++t) mx = fmaxf(mx, E_s[t*TT + r]);
    float sum = 0.f;
    for (int t = 0; t < TT; ++t) sum += expf(E_s[t*TT + r] - mx);
    float inv = 1.f/sum;
    for (int t = 0; t < TT; ++t) E[(size_t)b*TT*TT + t*TT + r] = expf(E_s[t*TT + r] - mx)*inv;
  }
}

// ---------------- lx/r2 for spatial attention (x_tat never materialized)
__global__ void k_xtat(const float* __restrict__ x, const float* __restrict__ E1,
                       const float* __restrict__ sw1, const float* __restrict__ sw2,
                       const float* __restrict__ sw3,
                       float* __restrict__ lx, float* __restrict__ r2){
  __shared__ float E_s[TT*TT], sw1_s[TT], sw2_s[TT];
  int b = blockIdx.x >> 1, half = blockIdx.x & 1, tid = threadIdx.x;
  for (int i = tid; i < 576; i += 256) E_s[i] = E1[(size_t)b*576 + i];
  if (tid < TT){ sw1_s[tid] = sw1[tid]; sw2_s[tid] = sw2[tid]; }
  __syncthreads();
  int n = half*256 + tid;
  float xr[TT];
  const float* xp = x + (size_t)(b*NN + n)*TT;
  for (int t = 0; t < TT; ++t) xr[t] = xp[t];
  float l = 0.f, r = 0.f;
  for (int s = 0; s < TT; ++s){
    float acc = 0.f;
    for (int t = 0; t < TT; ++t) acc += xr[t]*E_s[t*TT + s];
    l += acc*sw1_s[s];
    r += acc*sw2_s[s];
  }
  lx[b*NN + n] = l;
  r2[b*NN + n] = r*sw3[0];
}

// ---------------- S0[b] = s_vs @ sigmoid(lx[b]⊗r2[b] + s_bs)
__global__ __launch_bounds__(256) void k_S0(const float* __restrict__ s_vs, const float* __restrict__ s_bs,
                    const float* __restrict__ lx, const float* __restrict__ r2,
                    float* __restrict__ S0){
  __shared__ float As[128][17], Bs[128][17];
  int kt = blockIdx.x, nt = blockIdx.y, b = blockIdx.z;
  int n0 = nt*128, k0 = kt*128, tid = threadIdx.x;
  int tr = tid >> 4, tc = tid & 15;
  float acc[8][8];
  #pragma unroll
  for (int i = 0; i < 8; ++i)
    #pragma unroll
    for (int j = 0; j < 8; ++j) acc[i][j] = 0.f;
  const float* lxb = lx + b*NN;
  const float* r2b = r2 + b*NN;
  for (int m0 = 0; m0 < NN; m0 += 16){
    for (int p = 0; p < 8; ++p){
      int idx = tid + p*256;
      int r = idx >> 4, cc = idx & 15;
      As[r][cc] = s_vs[(size_t)(n0 + r)*NN + m0 + cc];
      int mm = idx >> 7, j = idx & 127;
      float v = lxb[m0 + mm]*r2b[k0 + j] + s_bs[(size_t)(m0 + mm)*NN + k0 + j];
      Bs[j][mm] = 1.f/(1.f + expf(-v));
    }
    __syncthreads();
    #pragma unroll
    for (int kk = 0; kk < 16; ++kk){
      float a[8], bv[8];
      #pragma unroll
      for (int ii = 0; ii < 8; ++ii) a[ii] = As[tr*8 + ii][kk];
      #pragma unroll
      for (int jj = 0; jj < 8; ++jj) bv[jj] = Bs[tc*8 + jj][kk];
      #pragma unroll
      for (int ii = 0; ii < 8; ++ii)
        #pragma unroll
        for (int jj = 0; jj < 8; ++jj) acc[ii][jj] += a[ii]*bv[jj];
    }
    __syncthreads();
  }
  for (int ii = 0; ii < 8; ++ii){
    int i = n0 + tr*8 + ii;
    for (int jj = 0; jj < 8; ++jj){
      S0[(size_t)b*NN*NN + (size_t)i*NN + k0 + tc*8 + jj] = acc[ii][jj];
    }
  }
}

// ---------------- column softmax over n (axis=1) in place
__global__ void k_softmaxS(float* __restrict__ S){
  int b = blockIdx.y;
  int k = blockIdx.x*256 + threadIdx.x;
  float* Sb = S + (size_t)b*NN*NN + k;
  float mx = -1e30f;
  for (int n = 0; n < NN; ++n) mx = fmaxf(mx, Sb[(size_t)n*NN]);
  float sum = 0.f;
  for (int n = 0; n < NN; ++n){ float e = expf(Sb[(size_t)n*NN] - mx); sum += e; Sb[(size_t)n*NN] = e; }
  float inv = 1.f/sum;
  for (int n = 0; n < NN; ++n) Sb[(size_t)n*NN] *= inv;
}

// ---------------- tmp_k[b,i,t] = sum_j cheb[k][j,i]*S[b,j,i]*x[b,j,t]
__global__ __launch_bounds__(384) void k_tmp(const float* __restrict__ S, const float* __restrict__ cheb,
                     const float* __restrict__ x, float* __restrict__ tmp){
  __shared__ float Ssub[NN*16];
  int i0 = blockIdx.x*16, b = blockIdx.y, tid = threadIdx.x;
  for (int idx = tid; idx < NN*16; idx += 384){
    int j = idx >> 4, ii = idx & 15;
    Ssub[idx] = S[(size_t)b*NN*NN + (size_t)j*NN + i0 + ii];
  }
  __syncthreads();
  int ii = tid / TT, t = tid % TT;
  const float* xb = x + (size_t)b*NN*TT;
  const float* c0 = cheb;
  const float* c1 = cheb + (size_t)NN*NN;
  const float* c2 = cheb + (size_t)2*NN*NN;
  float a0 = 0.f, a1 = 0.f, a2 = 0.f;
  for (int j = 0; j < NN; ++j){
    float sx = Ssub[j*16 + ii]*xb[j*TT + t];
    a0 += c0[(size_t)j*NN + i0 + ii]*sx;
    a1 += c1[(size_t)j*NN + i0 + ii]*sx;
    a2 += c2[(size_t)j*NN + i0 + ii]*sx;
  }
  tmp[((size_t)(0*BB + b)*NN + i0 + ii)*TT + t] = a0;
  tmp[((size_t)(1*BB + b)*NN + i0 + ii)*TT + t] = a1;
  tmp[((size_t)(2*BB + b)*NN + i0 + ii)*TT + t] = a2;
}

// ---------------- att2: per-16-n-tile two-pass: rhsg + partial w1g
__global__ __launch_bounds__(384) void k_gsum(const float* __restrict__ tmp, const float* __restrict__ theta,
                      const float* __restrict__ u1b, const float* __restrict__ u3b,
                      const float* __restrict__ du3b,
                      float* __restrict__ rhsg, float* __restrict__ pw1g){
  __shared__ float A0[16*TT], A1[16*TT], A2[16*TT], th_s[192], u3_s[CC], u1_s[16], du_s[TT];
  int nt = blockIdx.x, b = blockIdx.y;
  int n0 = nt*16, tid = threadIdx.x;
  for (int i = tid; i < 192; i += 384) th_s[i] = theta[i];
  if (tid < CC) u3_s[tid] = u3b[tid];
  if (tid < 16) u1_s[tid] = u1b[n0 + tid];
  if (tid < TT) du_s[tid] = du3b[b*TT + tid];
  A0[tid] = tmp[((size_t)(0*BB + b)*NN + n0)*TT + tid];
  A1[tid] = tmp[((size_t)(1*BB + b)*NN + n0)*TT + tid];
  A2[tid] = tmp[((size_t)(2*BB + b)*NN + n0)*TT + tid];
  __syncthreads();
  // pass 1: rhsg (reduce over f)
  {
    int nn = tid / TT, t = tid % TT;
    float a0 = A0[nn*TT + t], a1 = A1[nn*TT + t], a2 = A2[nn*TT + t];
    float acc = du_s[t];
    #pragma unroll 8
    for (int f = 0; f < CC; ++f){
      float v = th_s[f]*a0 + th_s[64 + f]*a1 + th_s[128 + f]*a2;
      acc += u3_s[f]*fmaxf(v, 0.f);
    }
    rhsg[(size_t)b*NN*TT + (n0 + nn)*TT + t] = acc;
  }
  // pass 2: partial w1g (reduce over the 16 n of this tile)
  #pragma unroll
  for (int p = 0; p < 4; ++p){
    int o = tid + p*384;
    int f = o / TT, t = o % TT;
    float t0 = th_s[f], t1 = th_s[64 + f], t2 = th_s[128 + f];
    float acc = 0.f;
    #pragma unroll
    for (int m = 0; m < 16; ++m){
      float v = t0*A0[m*TT + t] + t1*A1[m*TT + t] + t2*A2[m*TT + t];
      acc += u1_s[m]*fmaxf(v, 0.f);
    }
    pw1g[((size_t)(b*32 + nt))*CC*TT + o] = acc;
  }
}

// ---------------- reduce partial w1g + S2*dt
__global__ void k_w1g_red(const float* __restrict__ pw1g, const float* __restrict__ dt,
                          const float* __restrict__ sums, float* __restrict__ w1g){
  int b = blockIdx.x, tid = threadIdx.x;
  float S2 = sums[1];
  for (int o = tid; o < CC*TT; o += 256){
    int f = o / TT, t = o % TT;
    float acc = 0.f;
    for (int nt = 0; nt < 32; ++nt) acc += pw1g[((size_t)(b*32 + nt))*CC*TT + o];
    w1g[b*CC*TT + o] = acc + S2*dt[b*CT + t*CC + f];
  }
}

// ---------------- g2 (bf16) = relu(theta·tmp) @ E2  -> A-operand of the MFMA GEMM
__global__ void k_g2(const float* __restrict__ tmp, const float* __restrict__ E2,
                     const float* __restrict__ theta, __hip_bfloat16* __restrict__ g2){
  __shared__ float E_s[TT*TT], th_s[192], tr[3*4*TT], g_s[4*CT];
  int b = blockIdx.y, n0 = blockIdx.x*4, tid = threadIdx.x;
  for (int i = tid; i < 576; i += 256) E_s[i] = E2[(size_t)b*576 + i];
  for (int i = tid; i < 192; i += 256) th_s[i] = theta[i];
  for (int i = tid; i < 288; i += 256){
    int k = i / 96, rem = i % 96, nn = rem / TT, s = rem % TT;
    tr[i] = tmp[((size_t)(k*BB + b)*NN + n0 + nn)*TT + s];
  }
  __syncthreads();
  for (int idx = tid; idx < 4*CT; idx += 256){
    int nn = idx / CT, rem = idx % CT, f = rem / TT, s = rem % TT;
    float v = th_s[f]*tr[nn*TT + s] + th_s[64 + f]*tr[96 + nn*TT + s] + th_s[128 + f]*tr[192 + nn*TT + s];
    g_s[idx] = fmaxf(v, 0.f);
  }
  __syncthreads();
  for (int idx = tid; idx < 4*CT; idx += 256){
    int nn = idx / CT, rem = idx % CT, f = rem / TT, t = rem % TT;
    float acc = 0.f;
    const float* gr = g_s + nn*CT + f*TT;
    for (int s = 0; s < TT; ++s) acc += gr[s]*E_s[s*TT + t];
    g2[(size_t)(b*NN + n0 + nn)*CT + rem] = __float2bfloat16(acc);
  }
}

// ---------------- l1_w fp32 -> bf16
__global__ void k_convW(const float* __restrict__ W, __hip_bfloat16* __restrict__ Wb){
  int i = (blockIdx.x*256 + threadIdx.x)*4;
  float4 v = *(const float4*)(W + i);
  Wb[i+0] = __float2bfloat16(v.x);
  Wb[i+1] = __float2bfloat16(v.y);
  Wb[i+2] = __float2bfloat16(v.z);
  Wb[i+3] = __float2bfloat16(v.w);
}

// ---------------- tlin = A(16384x1536,bf16) @ W^T(bf16) + l1_b  — m97-style MFMA GEMM
__global__ __launch_bounds__(256) void k_gemm_bf16(const __hip_bfloat16* __restrict__ A,
                      const __hip_bfloat16* __restrict__ W,
                      const float* __restrict__ bias, float* __restrict__ Cout){
  __shared__ __align__(16) short lA[128*32];
  __shared__ __align__(16) short lB[128*32];
  int i0 = blockIdx.y*128, o0 = blockIdx.x*128;
  int tid = threadIdx.x;
  int w = tid >> 6, l = tid & 63;
  int wr = w >> 1, wc = w & 1;
  f32x4 acc[4][4];
  #pragma unroll
  for (int m = 0; m < 4; ++m)
    #pragma unroll
    for (int n = 0; n < 4; ++n) acc[m][n] = (f32x4){0.f,0.f,0.f,0.f};

  int lrow = l & 15, lk = (l >> 4);
  for (int k0 = 0; k0 < CT; k0 += 32){
    #pragma unroll
    for (int p = 0; p < 2; ++p){
      int c = p*4 + w;
      int off = c*512 + l*8;
      int row = off >> 5, col = off & 31;
      __builtin_amdgcn_global_load_lds(
        (const __attribute__((address_space(1))) void*)(A + (size_t)(i0 + row)*CT + k0 + col),
        (__attribute__((address_space(3))) void*)(lA + c*512), 16, 0, 0);
      __builtin_amdgcn_global_load_lds(
        (const __attribute__((address_space(1))) void*)(W + (size_t)(o0 + row)*CT + k0 + col),
        (__attribute__((address_space(3))) void*)(lB + c*512), 16, 0, 0);
    }
    __syncthreads();
    bf16x8 a[4], bv[4];
    #pragma unroll
    for (int m = 0; m < 4; ++m){
      int row = wr*64 + m*16 + lrow;
      a[m] = *(const bf16x8*)(lA + row*32 + lk*8);
    }
    #pragma unroll
    for (int n = 0; n < 4; ++n){
      int row = wc*64 + n*16 + lrow;
      bv[n] = *(const bf16x8*)(lB + row*32 + lk*8);
    }
    #pragma unroll
    for (int m = 0; m < 4; ++m)
      #pragma unroll
      for (int n = 0; n < 4; ++n)
        acc[m][n] = __builtin_amdgcn_mfma_f32_16x16x32_bf16(a[m], bv[n], acc[m][n], 0, 0, 0);
    __syncthreads();
  }
  #pragma unroll
  for (int m = 0; m < 4; ++m){
    #pragma unroll
    for (int n = 0; n < 4; ++n){
      int o = o0 + wc*64 + n*16 + lrow;
      float bo = bias[o];
      #pragma unroll
      for (int j = 0; j < 4; ++j){
        int i = i0 + wr*64 + m*16 + lk*4 + j;
        Cout[(size_t)i*CT + o] = acc[m][n][j] + bo;
      }
    }
  }
}

// ---------------- scrambled reshape + residual + relu + LayerNorm
__global__ __launch_bounds__(256) void k_final(const float* __restrict__ tlin, const float* __restrict__ x,
                      const float* __restrict__ res_w, const float* __restrict__ res_b,
                      const float* __restrict__ ln_g, const float* __restrict__ ln_b,
                      float* __restrict__ out){
  int idx = blockIdx.x*256 + threadIdx.x;
  int b = idx / (NN*TT);
  int p = idx % (NN*TT);
  int np = p / TT, tp = p % TT;
  int dlt = p / CT;
  int o = p % CT;
  float xv = x[(size_t)(b*NN + np)*TT + tp];
  const float* tb = tlin + (size_t)b*NN*CT;
  float z[CC];
  float sum = 0.f, sq = 0.f;
  #pragma unroll
  for (int c = 0; c < CC; ++c){
    float v = tb[(size_t)(c*8 + dlt)*CT + o] + xv*res_w[c] + res_b[c];
    v = fmaxf(v, 0.f);
    z[c] = v;
    sum += v; sq += v*v;
  }
  float mu = sum*(1.f/64.f);
  float var = sq*(1.f/64.f) - mu*mu;
  float rstd = rsqrtf(var + 1e-5f);
  float* ob = out + (size_t)(b*NN + np)*CC*TT + tp;
  #pragma unroll
  for (int c = 0; c < CC; ++c){
    ob[c*TT] = (z[c] - mu)*rstd*ln_g[c] + ln_b[c];
  }
}

extern "C" void kernel_launch(void* const* d_in, const int* in_sizes, int n_in,
                              void* d_out, int out_size, void* d_ws, size_t ws_size,
                              hipStream_t stream){
  const float* x    = (const float*)d_in[0];
  const float* y    = (const float*)d_in[1];
  const float* tl_w = (const float*)d_in[2];
  const float* tl_b = (const float*)d_in[3];
  const float* u0_w = (const float*)d_in[4];
  const float* u0_b = (const float*)d_in[5];
  const float* u1a  = (const float*)d_in[6];
  const float* u2a  = (const float*)d_in[7];
  const float* u3a  = (const float*)d_in[8];
  const float* be_a = (const float*)d_in[9];
  const float* ve_a = (const float*)d_in[10];
  const float* u1b  = (const float*)d_in[11];
  const float* u2b  = (const float*)d_in[12];
  const float* u3b  = (const float*)d_in[13];
  const float* be_b = (const float*)d_in[14];
  const float* ve_b = (const float*)d_in[15];
  const float* sw1  = (const float*)d_in[16];
  const float* sw2  = (const float*)d_in[17];
  const float* sw3  = (const float*)d_in[18];
  const float* s_bs = (const float*)d_in[19];
  const float* s_vs = (const float*)d_in[20];
  const float* cheb = (const float*)d_in[21];
  const float* theta= (const float*)d_in[22];
  const float* l1_w = (const float*)d_in[23];
  const float* l1_b = (const float*)d_in[24];
  const float* res_w= (const float*)d_in[25];
  const float* res_b= (const float*)d_in[26];
  const float* ln_g = (const float*)d_in[27];
  const float* ln_b = (const float*)d_in[28];
  float* out = (float*)d_out;
  float* ws  = (float*)d_ws;

  // ws layout (floats). Aliases:
  //  - Wb (bf16) over lhs1+rhs1 (dead after E1)
  //  - pw1g over big/S (S dead after k_tmp); tlin over big (pw1g dead before k_gemm)
  float* dt   = ws;               // 49152
  float* E1   = dt   + 49152;     // 18432
  float* E2   = E1   + 18432;     // 18432
  float* lxp  = E2   + 18432;     // 16384
  float* r2p  = lxp  + 16384;     // 16384
  float* w0u3 = r2p  + 16384;     // 640
  float* b0u3 = w0u3 + 640;       // 64
  float* sums = b0u3 + 64;        // 64
  float* du3a = sums + 64;        // 768
  float* du3b = du3a + 768;       // 768
  float* w1a  = du3b + 768;       // 49152
  float* w1g  = w1a  + 49152;     // 49152
  float* lhs1 = w1g  + 49152;     // 393216
  float* rhs1 = lhs1 + 393216;    // 393216
  float* lhsg = rhs1 + 393216;    // 393216
  float* rhsg = lhsg + 393216;    // 393216
  float* tmp  = rhsg + 393216;    // 1179648
  float* big  = tmp  + 1179648;   // S: 8388608 / pw1g: 1572864 / tlin: 25165824
  float* S    = big;
  float* pw1g = big;
  float* tlin = big;
  __hip_bfloat16* Wb  = (__hip_bfloat16*)lhs1;
  __hip_bfloat16* g2b = (__hip_bfloat16*)d_out;

  k_prep0<<<dim3(1), dim3(576), 0, stream>>>(u0_w, u0_b, u1a, u3a, u1b, w0u3, b0u3, sums);
  k_dt<<<dim3(1536), dim3(256), 0, stream>>>(y, tl_w, tl_b, dt);
  k_small<<<dim3(32), dim3(256), 0, stream>>>(x, dt, u0_w, u0_b, u1a, u3a, u3b, sums, w1a, du3a, du3b);
  k_rhs1<<<dim3(32, 32), dim3(384), 0, stream>>>(x, w0u3, b0u3, du3a, rhs1);
  k_lhs<<<dim3(48, 32), dim3(256), 0, stream>>>(u2a, w1a, lhs1);
  k_att_post<<<dim3(32), dim3(576), 0, stream>>>(lhs1, rhs1, ve_a, be_a, E1);
  k_xtat<<<dim3(64), dim3(256), 0, stream>>>(x, E1, sw1, sw2, sw3, lxp, r2p);
  k_S0<<<dim3(4, 4, 32), dim3(256), 0, stream>>>(s_vs, s_bs, lxp, r2p, S);
  k_softmaxS<<<dim3(2, 32), dim3(256), 0, stream>>>(S);
  k_tmp<<<dim3(32, 32), dim3(384), 0, stream>>>(S, cheb, x, tmp);
  k_gsum<<<dim3(32, 32), dim3(384), 0, stream>>>(tmp, theta, u1b, u3b, du3b, rhsg, pw1g);
  k_w1g_red<<<dim3(32), dim3(256), 0, stream>>>(pw1g, dt, sums, w1g);
  k_lhs<<<dim3(48, 32), dim3(256), 0, stream>>>(u2b, w1g, lhsg);
  k_att_post<<<dim3(32), dim3(576), 0, stream>>>(lhsg, rhsg, ve_b, be_b, E2);
  k_convW<<<dim3(2304), dim3(256), 0, stream>>>(l1_w, Wb);
  k_g2<<<dim3(128, 32), dim3(256), 0, stream>>>(tmp, E2, theta, g2b);
  k_gemm_bf16<<<dim3(12, 128), dim3(256), 0, stream>>>(g2b, Wb, l1_b, tlin);
  k_final<<<dim3(1536), dim3(256), 0, stream>>>(tlin, x, res_w, res_b, ln_g, ln_b, out);
}

// Round 5
// 645.898 us; speedup vs baseline: 4.5145x; 1.6013x over previous
//
#include <hip/hip_runtime.h>
#include <hip/hip_bf16.h>
#include <math.h>

#define BB 32
#define NN 512
#define TT 24
#define CC 64
#define CT 1536   // CC*TT
#define YD 3624   // 151*TT

typedef __attribute__((ext_vector_type(4))) float f32x4;
typedef __attribute__((ext_vector_type(8))) short bf16x8;

static __device__ __forceinline__ short f2bf(float f){
  union { float f; unsigned u; } v; v.f = f;
  unsigned r = (v.u + 0x7FFF + ((v.u >> 16) & 1)) >> 16;
  return (short)r;
}

// ---------------- small precompute
__global__ void k_prep0(const float* __restrict__ u0_w, const float* __restrict__ u0_b,
                        const float* __restrict__ u1a, const float* __restrict__ u3a,
                        const float* __restrict__ u1b,
                        float* __restrict__ w0u3, float* __restrict__ b0u3, float* __restrict__ sums){
  int tid = threadIdx.x;
  if (tid < 576){
    int tp = tid / TT, t = tid % TT;
    float acc = 0.f;
    for (int f = 0; f < CC; ++f) acc += u3a[f] * u0_w[(f*TT + tp)*TT + t];
    w0u3[tid] = acc;
  }
  if (tid < TT){
    float acc = 0.f;
    for (int f = 0; f < CC; ++f) acc += u3a[f] * u0_b[f*TT + tid];
    b0u3[tid] = acc;
  }
  if (tid == 0){ float s = 0.f; for (int n = 0; n < NN; ++n) s += u1a[n]; sums[0] = s; }
  if (tid == 1){ float s = 0.f; for (int n = 0; n < NN; ++n) s += u1b[n]; sums[1] = s; }
}

// ---------------- dt[b][o] = dot(y[b,:], tl_w[o,:]) + tl_b[o]
__global__ void k_dt(const float* __restrict__ y, const float* __restrict__ tl_w,
                     const float* __restrict__ tl_b, float* __restrict__ dt){
  __shared__ float row[YD];
  int o = blockIdx.x;
  for (int j = threadIdx.x; j < YD; j += 256) row[j] = tl_w[(size_t)o*YD + j];
  __syncthreads();
  int wv = threadIdx.x >> 6, ln = threadIdx.x & 63;
  float bias = tl_b[o];
  for (int b = wv; b < BB; b += 4){
    float acc = 0.f;
    const float* yb = y + (size_t)b*YD;
    for (int j = ln; j < YD; j += 64) acc += row[j]*yb[j];
    for (int off = 32; off; off >>= 1) acc += __shfl_down(acc, off);
    if (ln == 0) dt[b*CT + o] = acc + bias;
  }
}

// ---------------- per-b small reductions: xu, du3a, du3b, w1a
__global__ void k_small(const float* __restrict__ x, const float* __restrict__ dt,
                        const float* __restrict__ u0_w, const float* __restrict__ u0_b,
                        const float* __restrict__ u1a, const float* __restrict__ u3a,
                        const float* __restrict__ u3b, const float* __restrict__ sums,
                        float* __restrict__ w1a, float* __restrict__ du3a, float* __restrict__ du3b){
  __shared__ float xu_s[TT], u1a_s[NN];
  int b = blockIdx.x, tid = threadIdx.x;
  for (int i = tid; i < NN; i += 256) u1a_s[i] = u1a[i];
  __syncthreads();
  int wv = tid >> 6, ln = tid & 63;
  for (int t = wv; t < TT; t += 4){
    float acc = 0.f;
    for (int n = ln; n < NN; n += 64) acc += u1a_s[n]*x[(size_t)(b*NN + n)*TT + t];
    for (int off = 32; off; off >>= 1) acc += __shfl_down(acc, off);
    if (ln == 0) xu_s[t] = acc;
  }
  if (tid < TT){
    float a = 0.f, c = 0.f;
    for (int f = 0; f < CC; ++f){
      float d = dt[b*CT + tid*CC + f];
      a += u3a[f]*d; c += u3b[f]*d;
    }
    du3a[b*TT + tid] = a;
    du3b[b*TT + tid] = c;
  }
  __syncthreads();
  float S1 = sums[0];
  for (int idx = tid; idx < CC*TT; idx += 256){
    int f = idx / TT, tp = idx % TT;
    float acc = 0.f;
    const float* wrow = u0_w + (f*TT + tp)*TT;
    for (int t = 0; t < TT; ++t) acc += wrow[t]*xu_s[t];
    w1a[b*CC*TT + idx] = acc + S1*(u0_b[f*TT + tp] + dt[b*CT + tp*CC + f]);
  }
}

// ---------------- rhs1[b][n][t'] = b0u3[t'] + du3a[b][t'] + sum_t w0u3[t'][t]*x[b,n,t]
__global__ __launch_bounds__(384) void k_rhs1(const float* __restrict__ x, const float* __restrict__ w0u3,
                      const float* __restrict__ b0u3, const float* __restrict__ du3a,
                      float* __restrict__ rhs1){
  __shared__ float xs[16*TT], w0_s[576], bd_s[TT];
  int b = blockIdx.y, n0 = blockIdx.x*16, tid = threadIdx.x;
  for (int i = tid; i < 576; i += 384) w0_s[i] = w0u3[i];
  if (tid < TT) bd_s[tid] = b0u3[tid] + du3a[b*TT + tid];
  xs[tid] = x[(size_t)(b*NN + n0)*TT + tid];
  __syncthreads();
  int nn = tid / TT, tp = tid % TT;
  float acc = bd_s[tp];
  const float* wr = w0_s + tp*TT;
  const float* xr = xs + nn*TT;
  for (int t = 0; t < TT; ++t) acc += wr[t]*xr[t];
  rhs1[(size_t)b*NN*TT + (n0 + nn)*TT + tp] = acc;
}

// ---------------- lhs[b][t][m] = sum_f u2[f,m]*w1[b][f][t]   (shared by att1/att2)
__global__ void k_lhs(const float* __restrict__ u2, const float* __restrict__ w1,
                      float* __restrict__ lhs){
  int b = blockIdx.y;
  int j = blockIdx.x*256 + threadIdx.x;
  int t = j >> 9, m = j & 511;
  const float* w = w1 + b*CC*TT;
  float acc = 0.f;
  #pragma unroll 8
  for (int f = 0; f < CC; ++f) acc += u2[f*NN + m]*w[f*TT + t];
  lhs[(size_t)b*TT*NN + j] = acc;
}

// ---------------- partial prod: pprod[b][ns][t*24+s] = sum_{n in slice} lhs[b,t,n]*rhs[b,n,s]
__global__ __launch_bounds__(576) void k_prod(const float* __restrict__ lhs, const float* __restrict__ rhs,
                      float* __restrict__ pprod){
  __shared__ float lh[TT][64], rh[64][TT];
  int ns = blockIdx.x, b = blockIdx.y;
  int n0 = ns*64, tid = threadIdx.x;
  for (int i = tid; i < 1536; i += 576){ int t = i >> 6, n = i & 63; lh[t][n] = lhs[(size_t)b*TT*NN + t*NN + n0 + n]; }
  for (int i = tid; i < 1536; i += 576){ ((float*)rh)[i] = rhs[(size_t)b*NN*TT + n0*TT + i]; }
  __syncthreads();
  int t = tid / TT, s = tid % TT;
  float acc = 0.f;
  #pragma unroll 4
  for (int n = 0; n < 64; ++n) acc += lh[t][n]*rh[n][s];
  pprod[((size_t)(b*8 + ns))*576 + tid] = acc;
}

// ---------------- attention tail: sum partials -> sigmoid -> ve -> softmax(axis t)
__global__ void k_att_post2(const float* __restrict__ pprod, const float* __restrict__ ve,
                            const float* __restrict__ be, float* __restrict__ E){
  __shared__ float sig_s[TT*TT], E_s[TT*TT];
  int b = blockIdx.x, tid = threadIdx.x;
  float acc = 0.f;
  #pragma unroll
  for (int p = 0; p < 8; ++p) acc += pprod[((size_t)(b*8 + p))*576 + tid];
  sig_s[tid] = 1.f/(1.f + expf(-(acc + be[tid])));
  __syncthreads();
  {
    int t = tid / TT, r = tid % TT;
    float a = 0.f;
    for (int s = 0; s < TT; ++s) a += ve[t*TT + s]*sig_s[s*TT + r];
    E_s[tid] = a;
  }
  __syncthreads();
  if (tid < TT){
    int r = tid;
    float mx = -1e30f;
    for (int t = 0; t < TT; ++t) mx = fmaxf(mx, E_s[t*TT + r]);
    float sum = 0.f;
    for (int t = 0; t < TT; ++t) sum += expf(E_s[t*TT + r] - mx);
    float inv = 1.f/sum;
    for (int t = 0; t < TT; ++t) E[(size_t)b*TT*TT + t*TT + r] = expf(E_s[t*TT + r] - mx)*inv;
  }
}

// ---------------- lx/r2 for spatial attention
__global__ void k_xtat(const float* __restrict__ x, const float* __restrict__ E1,
                       const float* __restrict__ sw1, const float* __restrict__ sw2,
                       const float* __restrict__ sw3,
                       float* __restrict__ lx, float* __restrict__ r2){
  __shared__ float E_s[TT*TT], sw1_s[TT], sw2_s[TT];
  int b = blockIdx.x >> 1, half = blockIdx.x & 1, tid = threadIdx.x;
  for (int i = tid; i < 576; i += 256) E_s[i] = E1[(size_t)b*576 + i];
  if (tid < TT){ sw1_s[tid] = sw1[tid]; sw2_s[tid] = sw2[tid]; }
  __syncthreads();
  int n = half*256 + tid;
  float xr[TT];
  const float* xp = x + (size_t)(b*NN + n)*TT;
  for (int t = 0; t < TT; ++t) xr[t] = xp[t];
  float l = 0.f, r = 0.f;
  for (int s = 0; s < TT; ++s){
    float acc = 0.f;
    for (int t = 0; t < TT; ++t) acc += xr[t]*E_s[t*TT + s];
    l += acc*sw1_s[s];
    r += acc*sw2_s[s];
  }
  lx[b*NN + n] = l;
  r2[b*NN + n] = r*sw3[0];
}

// ---------------- s_vs fp32 -> bf16
__global__ void k_convS(const float* __restrict__ S, __hip_bfloat16* __restrict__ Sb){
  int i = (blockIdx.x*256 + threadIdx.x)*4;
  float4 v = *(const float4*)(S + i);
  Sb[i+0] = __float2bfloat16(v.x);
  Sb[i+1] = __float2bfloat16(v.y);
  Sb[i+2] = __float2bfloat16(v.z);
  Sb[i+3] = __float2bfloat16(v.w);
}

// ---------------- ST[b][k][n] = sum_m s_vs[n][m]*sigmoid(lx[m]*r2[k]+s_bs[m][k])  (MFMA)
__global__ __launch_bounds__(256) void k_S0(const __hip_bfloat16* __restrict__ svB,
                    const float* __restrict__ s_bs,
                    const float* __restrict__ lx, const float* __restrict__ r2,
                    float* __restrict__ ST){
  __shared__ __align__(16) short lA[128*32];
  __shared__ __align__(16) short lQ[128*32];
  __shared__ float sb_s[32][132];
  __shared__ float lx_s[32];
  int kt = blockIdx.x, nt = blockIdx.y, b = blockIdx.z;
  int n0 = nt*128, k0 = kt*128;
  int tid = threadIdx.x;
  int w = tid >> 6, l = tid & 63;
  int wr = w >> 1, wc = w & 1;
  int lrow = l & 15, lk = l >> 4;
  f32x4 acc[4][4];
  #pragma unroll
  for (int m = 0; m < 4; ++m)
    #pragma unroll
    for (int n = 0; n < 4; ++n) acc[m][n] = (f32x4){0.f,0.f,0.f,0.f};
  const float* lxb = lx + b*NN;
  int kq = tid >> 1;
  float r2q = r2[b*NN + k0 + kq];
  for (int m0 = 0; m0 < NN; m0 += 32){
    if (tid < 32) lx_s[tid] = lxb[m0 + tid];
    #pragma unroll
    for (int p = 0; p < 2; ++p){
      int c = p*4 + w;
      int off = c*512 + l*8;
      int row = off >> 5, col = off & 31;
      __builtin_amdgcn_global_load_lds(
        (const __attribute__((address_space(1))) void*)(svB + (size_t)(n0 + row)*NN + m0 + col),
        (__attribute__((address_space(3))) void*)(lA + c*512), 16, 0, 0);
    }
    #pragma unroll
    for (int q = 0; q < 4; ++q){
      int idx = tid + q*256;          // 1024 float4 units
      int mm = idx >> 5, k4 = idx & 31;
      float4 v = *(const float4*)(s_bs + (size_t)(mm)*NN + (size_t)m0*NN + k0 + k4*4);
      *(float4*)(&sb_s[mm][k4*4]) = v;
    }
    __syncthreads();
    // Q^T tile: lQ[k][m] bf16, each entry computed once
    #pragma unroll
    for (int c2 = 0; c2 < 2; ++c2){
      int mc = (tid & 1)*2 + c2;
      bf16x8 pk;
      #pragma unroll
      for (int j = 0; j < 8; ++j){
        int m = mc*8 + j;
        float v = lx_s[m]*r2q + sb_s[m][kq];
        float sg = 1.f/(1.f + __expf(-v));
        pk[j] = f2bf(sg);
      }
      *(bf16x8*)(lQ + kq*32 + mc*8) = pk;
    }
    __syncthreads();
    bf16x8 a[4], bv[4];
    #pragma unroll
    for (int m = 0; m < 4; ++m) a[m] = *(const bf16x8*)(lA + (wr*64 + m*16 + lrow)*32 + lk*8);
    #pragma unroll
    for (int n = 0; n < 4; ++n) bv[n] = *(const bf16x8*)(lQ + (wc*64 + n*16 + lrow)*32 + lk*8);
    #pragma unroll
    for (int m = 0; m < 4; ++m)
      #pragma unroll
      for (int n = 0; n < 4; ++n)
        acc[m][n] = __builtin_amdgcn_mfma_f32_16x16x32_bf16(a[m], bv[n], acc[m][n], 0, 0, 0);
    __syncthreads();
  }
  #pragma unroll
  for (int m = 0; m < 4; ++m){
    #pragma unroll
    for (int n = 0; n < 4; ++n){
      int col = k0 + wc*64 + n*16 + lrow;     // k index (ST row)
      int row = n0 + wr*64 + m*16 + lk*4;     // n index (ST col)
      float4 v; v.x = acc[m][n][0]; v.y = acc[m][n][1]; v.z = acc[m][n][2]; v.w = acc[m][n][3];
      *(float4*)(ST + (size_t)b*NN*NN + (size_t)col*NN + row) = v;
    }
  }
}

// ---------------- row softmax on ST (over n, contiguous)
__global__ __launch_bounds__(256) void k_softST(float* __restrict__ ST){
  int b = blockIdx.y;
  int row = blockIdx.x*4 + (threadIdx.x >> 6);
  int l = threadIdx.x & 63;
  float* R = ST + (size_t)b*NN*NN + (size_t)row*NN;
  float4 v0 = *(float4*)(R + l*8);
  float4 v1 = *(float4*)(R + l*8 + 4);
  float mx = fmaxf(fmaxf(fmaxf(v0.x,v0.y),fmaxf(v0.z,v0.w)),
                   fmaxf(fmaxf(v1.x,v1.y),fmaxf(v1.z,v1.w)));
  for (int off = 32; off; off >>= 1) mx = fmaxf(mx, __shfl_xor(mx, off));
  v0.x = expf(v0.x-mx); v0.y = expf(v0.y-mx); v0.z = expf(v0.z-mx); v0.w = expf(v0.w-mx);
  v1.x = expf(v1.x-mx); v1.y = expf(v1.y-mx); v1.z = expf(v1.z-mx); v1.w = expf(v1.w-mx);
  float s = v0.x+v0.y+v0.z+v0.w+v1.x+v1.y+v1.z+v1.w;
  for (int off = 32; off; off >>= 1) s += __shfl_xor(s, off);
  float inv = 1.f/s;
  v0.x*=inv; v0.y*=inv; v0.z*=inv; v0.w*=inv;
  v1.x*=inv; v1.y*=inv; v1.z*=inv; v1.w*=inv;
  *(float4*)(R + l*8) = v0;
  *(float4*)(R + l*8 + 4) = v1;
}

// ---------------- tmp_k[b,i,t] = sum_j cheb[k][j,i]*ST[b,i,j]*x[b,j,t]
__global__ __launch_bounds__(384) void k_tmp(const float* __restrict__ ST, const float* __restrict__ cheb,
                     const float* __restrict__ x, float* __restrict__ tmp){
  __shared__ float Ss[16*NN];
  int i0 = blockIdx.x*16, b = blockIdx.y, tid = threadIdx.x;
  for (int idx = tid; idx < 16*NN; idx += 384)
    Ss[idx] = ST[(size_t)b*NN*NN + (size_t)i0*NN + idx];
  __syncthreads();
  int ii = tid / TT, t = tid % TT;
  const float* xb = x + (size_t)b*NN*TT;
  const float* Sr = Ss + ii*NN;
  const float* c0 = cheb;
  const float* c1 = cheb + (size_t)NN*NN;
  const float* c2 = cheb + (size_t)2*NN*NN;
  float a0 = 0.f, a1 = 0.f, a2 = 0.f;
  for (int j = 0; j < NN; ++j){
    float sx = Sr[j]*xb[j*TT + t];
    a0 += c0[(size_t)j*NN + i0 + ii]*sx;
    a1 += c1[(size_t)j*NN + i0 + ii]*sx;
    a2 += c2[(size_t)j*NN + i0 + ii]*sx;
  }
  tmp[((size_t)(0*BB + b)*NN + i0 + ii)*TT + t] = a0;
  tmp[((size_t)(1*BB + b)*NN + i0 + ii)*TT + t] = a1;
  tmp[((size_t)(2*BB + b)*NN + i0 + ii)*TT + t] = a2;
}

// ---------------- att2: per-16-n-tile two-pass: rhsg + partial w1g
__global__ __launch_bounds__(384) void k_gsum(const float* __restrict__ tmp, const float* __restrict__ theta,
                      const float* __restrict__ u1b, const float* __restrict__ u3b,
                      const float* __restrict__ du3b,
                      float* __restrict__ rhsg, float* __restrict__ pw1g){
  __shared__ float A0[16*TT], A1[16*TT], A2[16*TT], th_s[192], u3_s[CC], u1_s[16], du_s[TT];
  int nt = blockIdx.x, b = blockIdx.y;
  int n0 = nt*16, tid = threadIdx.x;
  for (int i = tid; i < 192; i += 384) th_s[i] = theta[i];
  if (tid < CC) u3_s[tid] = u3b[tid];
  if (tid < 16) u1_s[tid] = u1b[n0 + tid];
  if (tid < TT) du_s[tid] = du3b[b*TT + tid];
  A0[tid] = tmp[((size_t)(0*BB + b)*NN + n0)*TT + tid];
  A1[tid] = tmp[((size_t)(1*BB + b)*NN + n0)*TT + tid];
  A2[tid] = tmp[((size_t)(2*BB + b)*NN + n0)*TT + tid];
  __syncthreads();
  {
    int nn = tid / TT, t = tid % TT;
    float a0 = A0[nn*TT + t], a1 = A1[nn*TT + t], a2 = A2[nn*TT + t];
    float acc = du_s[t];
    #pragma unroll 8
    for (int f = 0; f < CC; ++f){
      float v = th_s[f]*a0 + th_s[64 + f]*a1 + th_s[128 + f]*a2;
      acc += u3_s[f]*fmaxf(v, 0.f);
    }
    rhsg[(size_t)b*NN*TT + (n0 + nn)*TT + t] = acc;
  }
  #pragma unroll
  for (int p = 0; p < 4; ++p){
    int o = tid + p*384;
    int f = o / TT, t = o % TT;
    float t0 = th_s[f], t1 = th_s[64 + f], t2 = th_s[128 + f];
    float acc = 0.f;
    #pragma unroll
    for (int m = 0; m < 16; ++m){
      float v = t0*A0[m*TT + t] + t1*A1[m*TT + t] + t2*A2[m*TT + t];
      acc += u1_s[m]*fmaxf(v, 0.f);
    }
    pw1g[((size_t)(b*32 + nt))*CC*TT + o] = acc;
  }
}

// ---------------- reduce partial w1g + S2*dt
__global__ void k_w1g_red(const float* __restrict__ pw1g, const float* __restrict__ dt,
                          const float* __restrict__ sums, float* __restrict__ w1g){
  int b = blockIdx.x, tid = threadIdx.x;
  float S2 = sums[1];
  for (int o = tid; o < CC*TT; o += 256){
    int f = o / TT, t = o % TT;
    float acc = 0.f;
    for (int nt = 0; nt < 32; ++nt) acc += pw1g[((size_t)(b*32 + nt))*CC*TT + o];
    w1g[b*CC*TT + o] = acc + S2*dt[b*CT + t*CC + f];
  }
}

// ---------------- g2 (bf16) = relu(theta·tmp) @ E2
__global__ void k_g2(const float* __restrict__ tmp, const float* __restrict__ E2,
                     const float* __restrict__ theta, __hip_bfloat16* __restrict__ g2){
  __shared__ float E_s[TT*TT], th_s[192], tr[3*4*TT], g_s[4*CT];
  int b = blockIdx.y, n0 = blockIdx.x*4, tid = threadIdx.x;
  for (int i = tid; i < 576; i += 256) E_s[i] = E2[(size_t)b*576 + i];
  for (int i = tid; i < 192; i += 256) th_s[i] = theta[i];
  for (int i = tid; i < 288; i += 256){
    int k = i / 96, rem = i % 96, nn = rem / TT, s = rem % TT;
    tr[i] = tmp[((size_t)(k*BB + b)*NN + n0 + nn)*TT + s];
  }
  __syncthreads();
  for (int idx = tid; idx < 4*CT; idx += 256){
    int nn = idx / CT, rem = idx % CT, f = rem / TT, s = rem % TT;
    float v = th_s[f]*tr[nn*TT + s] + th_s[64 + f]*tr[96 + nn*TT + s] + th_s[128 + f]*tr[192 + nn*TT + s];
    g_s[idx] = fmaxf(v, 0.f);
  }
  __syncthreads();
  for (int idx = tid; idx < 4*CT; idx += 256){
    int nn = idx / CT, rem = idx % CT, f = rem / TT, t = rem % TT;
    float acc = 0.f;
    const float* gr = g_s + nn*CT + f*TT;
    for (int s = 0; s < TT; ++s) acc += gr[s]*E_s[s*TT + t];
    g2[(size_t)(b*NN + n0 + nn)*CT + rem] = __float2bfloat16(acc);
  }
}

// ---------------- l1_w fp32 -> bf16
__global__ void k_convW(const float* __restrict__ W, __hip_bfloat16* __restrict__ Wb){
  int i = (blockIdx.x*256 + threadIdx.x)*4;
  float4 v = *(const float4*)(W + i);
  Wb[i+0] = __float2bfloat16(v.x);
  Wb[i+1] = __float2bfloat16(v.y);
  Wb[i+2] = __float2bfloat16(v.z);
  Wb[i+3] = __float2bfloat16(v.w);
}

// ---------------- tlin = A(16384x1536,bf16) @ W^T(bf16) + l1_b
__global__ __launch_bounds__(256) void k_gemm_bf16(const __hip_bfloat16* __restrict__ A,
                      const __hip_bfloat16* __restrict__ W,
                      const float* __restrict__ bias, float* __restrict__ Cout){
  __shared__ __align__(16) short lA[128*32];
  __shared__ __align__(16) short lB[128*32];
  int i0 = blockIdx.y*128, o0 = blockIdx.x*128;
  int tid = threadIdx.x;
  int w = tid >> 6, l = tid & 63;
  int wr = w >> 1, wc = w & 1;
  f32x4 acc[4][4];
  #pragma unroll
  for (int m = 0; m < 4; ++m)
    #pragma unroll
    for (int n = 0; n < 4; ++n) acc[m][n] = (f32x4){0.f,0.f,0.f,0.f};
  int lrow = l & 15, lk = (l >> 4);
  for (int k0 = 0; k0 < CT; k0 += 32){
    #pragma unroll
    for (int p = 0; p < 2; ++p){
      int c = p*4 + w;
      int off = c*512 + l*8;
      int row = off >> 5, col = off & 31;
      __builtin_amdgcn_global_load_lds(
        (const __attribute__((address_space(1))) void*)(A + (size_t)(i0 + row)*CT + k0 + col),
        (__attribute__((address_space(3))) void*)(lA + c*512), 16, 0, 0);
      __builtin_amdgcn_global_load_lds(
        (const __attribute__((address_space(1))) void*)(W + (size_t)(o0 + row)*CT + k0 + col),
        (__attribute__((address_space(3))) void*)(lB + c*512), 16, 0, 0);
    }
    __syncthreads();
    bf16x8 a[4], bv[4];
    #pragma unroll
    for (int m = 0; m < 4; ++m) a[m] = *(const bf16x8*)(lA + (wr*64 + m*16 + lrow)*32 + lk*8);
    #pragma unroll
    for (int n = 0; n < 4; ++n) bv[n] = *(const bf16x8*)(lB + (wc*64 + n*16 + lrow)*32 + lk*8);
    #pragma unroll
    for (int m = 0; m < 4; ++m)
      #pragma unroll
      for (int n = 0; n < 4; ++n)
        acc[m][n] = __builtin_amdgcn_mfma_f32_16x16x32_bf16(a[m], bv[n], acc[m][n], 0, 0, 0);
    __syncthreads();
  }
  #pragma unroll
  for (int m = 0; m < 4; ++m){
    #pragma unroll
    for (int n = 0; n < 4; ++n){
      int o = o0 + wc*64 + n*16 + lrow;
      float bo = bias[o];
      #pragma unroll
      for (int j = 0; j < 4; ++j){
        int i = i0 + wr*64 + m*16 + lk*4 + j;
        Cout[(size_t)i*CT + o] = acc[m][n][j] + bo;
      }
    }
  }
}

// ---------------- reshape + residual + relu + LayerNorm (LDS-staged)
__global__ __launch_bounds__(128) void k_final(const float* __restrict__ tlin, const float* __restrict__ x,
                      const float* __restrict__ res_w, const float* __restrict__ res_b,
                      const float* __restrict__ ln_g, const float* __restrict__ ln_b,
                      float* __restrict__ out){
  __shared__ float Ls[64][132];
  __shared__ float rw_s[64], rb_s[64], lg_s[64], lb_s[64];
  int ot = blockIdx.x, dlt = blockIdx.y, b = blockIdx.z;
  int o0 = ot*128, tid = threadIdx.x;
  if (tid < 64){ rw_s[tid]=res_w[tid]; rb_s[tid]=res_b[tid]; lg_s[tid]=ln_g[tid]; lb_s[tid]=ln_b[tid]; }
  const float* tb = tlin + (size_t)b*NN*CT;
  #pragma unroll 4
  for (int c = 0; c < 64; ++c)
    Ls[c][tid] = tb[(size_t)(c*8 + dlt)*CT + o0 + tid];
  __syncthreads();
  int p = dlt*CT + o0 + tid;
  int np = p / TT, tp = p % TT;
  float xv = x[(size_t)(b*NN + np)*TT + tp];
  float z[CC];
  float sum = 0.f, sq = 0.f;
  #pragma unroll
  for (int c = 0; c < CC; ++c){
    float v = Ls[c][tid] + xv*rw_s[c] + rb_s[c];
    v = fmaxf(v, 0.f);
    z[c] = v; sum += v; sq += v*v;
  }
  float mu = sum*(1.f/64.f);
  float var = sq*(1.f/64.f) - mu*mu;
  float rstd = rsqrtf(var + 1e-5f);
  float* ob = out + (size_t)(b*NN + np)*CC*TT + tp;
  #pragma unroll
  for (int c = 0; c < CC; ++c)
    ob[c*TT] = (z[c] - mu)*rstd*lg_s[c] + lb_s[c];
}

extern "C" void kernel_launch(void* const* d_in, const int* in_sizes, int n_in,
                              void* d_out, int out_size, void* d_ws, size_t ws_size,
                              hipStream_t stream){
  const float* x    = (const float*)d_in[0];
  const float* y    = (const float*)d_in[1];
  const float* tl_w = (const float*)d_in[2];
  const float* tl_b = (const float*)d_in[3];
  const float* u0_w = (const float*)d_in[4];
  const float* u0_b = (const float*)d_in[5];
  const float* u1a  = (const float*)d_in[6];
  const float* u2a  = (const float*)d_in[7];
  const float* u3a  = (const float*)d_in[8];
  const float* be_a = (const float*)d_in[9];
  const float* ve_a = (const float*)d_in[10];
  const float* u1b  = (const float*)d_in[11];
  const float* u2b  = (const float*)d_in[12];
  const float* u3b  = (const float*)d_in[13];
  const float* be_b = (const float*)d_in[14];
  const float* ve_b = (const float*)d_in[15];
  const float* sw1  = (const float*)d_in[16];
  const float* sw2  = (const float*)d_in[17];
  const float* sw3  = (const float*)d_in[18];
  const float* s_bs = (const float*)d_in[19];
  const float* s_vs = (const float*)d_in[20];
  const float* cheb = (const float*)d_in[21];
  const float* theta= (const float*)d_in[22];
  const float* l1_w = (const float*)d_in[23];
  const float* l1_b = (const float*)d_in[24];
  const float* res_w= (const float*)d_in[25];
  const float* res_b= (const float*)d_in[26];
  const float* ln_g = (const float*)d_in[27];
  const float* ln_b = (const float*)d_in[28];
  float* out = (float*)d_out;
  float* ws  = (float*)d_ws;

  // ws layout (floats). Alias lifetimes (serial stream order):
  //  - Wb (bf16, spans lhs1+rhs1+lhsg = 4,718,592 B exactly): k_convW may run
  //    ONLY after E2 (second k_att_post2) when lhs1/rhs1/lhsg are all dead.  [R4 bug]
  //  - ST/pw1g/tlin share `big`: ST dead after k_tmp; pw1g dead after k_w1g_red.
  //  - g2b lives in d_out: dead once k_gemm_bf16 consumed it; k_final rewrites d_out.
  float* dt   = ws;               // 49152
  float* E    = dt   + 49152;     // 18432 (E1 then E2)
  float* lxp  = E    + 18432;     // 16384
  float* r2p  = lxp  + 16384;     // 16384
  float* w0u3 = r2p  + 16384;     // 640
  float* b0u3 = w0u3 + 640;       // 64
  float* sums = b0u3 + 64;        // 64
  float* du3a = sums + 64;        // 768
  float* du3b = du3a + 768;       // 768
  float* w1a  = du3b + 768;       // 49152
  float* w1g  = w1a  + 49152;     // 49152
  float* lhs1 = w1g  + 49152;     // 393216
  float* rhs1 = lhs1 + 393216;    // 393216
  float* lhsg = rhs1 + 393216;    // 393216
  float* rhsg = lhsg + 393216;    // 393216
  float* svBf = rhsg + 393216;    // 131072 (bf16 512x512)
  float* ppr  = svBf + 131072;    // 147456
  float* tmp  = ppr  + 147456;    // 1179648
  float* big  = tmp  + 1179648;   // ST: 8388608 / pw1g: 1572864 / tlin: 25165824
  float* ST   = big;
  float* pw1g = big;
  float* tlin = big;
  __hip_bfloat16* svB = (__hip_bfloat16*)svBf;
  __hip_bfloat16* Wb  = (__hip_bfloat16*)lhs1;   // valid only after E2 (see above)
  __hip_bfloat16* g2b = (__hip_bfloat16*)d_out;

  k_prep0<<<dim3(1), dim3(576), 0, stream>>>(u0_w, u0_b, u1a, u3a, u1b, w0u3, b0u3, sums);
  k_convS<<<dim3(256), dim3(256), 0, stream>>>(s_vs, svB);
  k_dt<<<dim3(1536), dim3(256), 0, stream>>>(y, tl_w, tl_b, dt);
  k_small<<<dim3(32), dim3(256), 0, stream>>>(x, dt, u0_w, u0_b, u1a, u3a, u3b, sums, w1a, du3a, du3b);
  k_rhs1<<<dim3(32, 32), dim3(384), 0, stream>>>(x, w0u3, b0u3, du3a, rhs1);
  k_lhs<<<dim3(48, 32), dim3(256), 0, stream>>>(u2a, w1a, lhs1);
  k_prod<<<dim3(8, 32), dim3(576), 0, stream>>>(lhs1, rhs1, ppr);
  k_att_post2<<<dim3(32), dim3(576), 0, stream>>>(ppr, ve_a, be_a, E);
  k_xtat<<<dim3(64), dim3(256), 0, stream>>>(x, E, sw1, sw2, sw3, lxp, r2p);
  k_S0<<<dim3(4, 4, 32), dim3(256), 0, stream>>>(svB, s_bs, lxp, r2p, ST);
  k_softST<<<dim3(128, 32), dim3(256), 0, stream>>>(ST);
  k_tmp<<<dim3(32, 32), dim3(384), 0, stream>>>(ST, cheb, x, tmp);
  k_gsum<<<dim3(32, 32), dim3(384), 0, stream>>>(tmp, theta, u1b, u3b, du3b, rhsg, pw1g);
  k_w1g_red<<<dim3(32), dim3(256), 0, stream>>>(pw1g, dt, sums, w1g);
  k_lhs<<<dim3(48, 32), dim3(256), 0, stream>>>(u2b, w1g, lhsg);
  k_prod<<<dim3(8, 32), dim3(576), 0, stream>>>(lhsg, rhsg, ppr);
  k_att_post2<<<dim3(32), dim3(576), 0, stream>>>(ppr, ve_b, be_b, E);
  k_convW<<<dim3(2304), dim3(256), 0, stream>>>(l1_w, Wb);   // after E2: lhs1/rhs1/lhsg dead
  k_g2<<<dim3(128, 32), dim3(256), 0, stream>>>(tmp, E, theta, g2b);
  k_gemm_bf16<<<dim3(12, 128), dim3(256), 0, stream>>>(g2b, Wb, l1_b, tlin);
  k_final<<<dim3(12, 8, 32), dim3(128), 0, stream>>>(tlin, x, res_w, res_b, ln_g, ln_b, out);
}

// Round 6
// 532.695 us; speedup vs baseline: 5.4739x; 1.2125x over previous
//
#include <hip/hip_runtime.h>
#include <hip/hip_bf16.h>
#include <math.h>

#define BB 32
#define NN 512
#define TT 24
#define CC 64
#define CT 1536   // CC*TT
#define YD 3624   // 151*TT
#define YP 3648   // YD padded to 114*32

typedef __attribute__((ext_vector_type(4))) float f32x4;
typedef __attribute__((ext_vector_type(8))) short bf16x8;

static __device__ __forceinline__ short f2bf(float f){
  union { float f; unsigned u; } v; v.f = f;
  unsigned r = (v.u + 0x7FFF + ((v.u >> 16) & 1)) >> 16;
  return (short)r;
}

// ---------------- small precompute
__global__ void k_prep0(const float* __restrict__ u0_w, const float* __restrict__ u0_b,
                        const float* __restrict__ u1a, const float* __restrict__ u3a,
                        const float* __restrict__ u1b,
                        float* __restrict__ w0u3, float* __restrict__ b0u3, float* __restrict__ sums){
  int tid = threadIdx.x;
  if (tid < 576){
    int tp = tid / TT, t = tid % TT;
    float acc = 0.f;
    for (int f = 0; f < CC; ++f) acc += u3a[f] * u0_w[(f*TT + tp)*TT + t];
    w0u3[tid] = acc;
  }
  if (tid < TT){
    float acc = 0.f;
    for (int f = 0; f < CC; ++f) acc += u3a[f] * u0_b[f*TT + tid];
    b0u3[tid] = acc;
  }
  if (tid == 0){ float s = 0.f; for (int n = 0; n < NN; ++n) s += u1a[n]; sums[0] = s; }
  if (tid == 1){ float s = 0.f; for (int n = 0; n < NN; ++n) s += u1b[n]; sums[1] = s; }
}

// ---------------- fp32 [rows][3624] -> bf16 [rows][3648] zero-padded
__global__ void k_convPad(const float* __restrict__ src, __hip_bfloat16* __restrict__ dst, int rows){
  int gid = blockIdx.x*256 + threadIdx.x;
  int r = gid / (YP/8), c8 = (gid % (YP/8))*8;
  if (r >= rows) return;
  bf16x8 o;
  if (c8 < YD){
    float4 a = *(const float4*)(src + (size_t)r*YD + c8);
    float4 b = *(const float4*)(src + (size_t)r*YD + c8 + 4);
    o[0]=f2bf(a.x); o[1]=f2bf(a.y); o[2]=f2bf(a.z); o[3]=f2bf(a.w);
    o[4]=f2bf(b.x); o[5]=f2bf(b.y); o[6]=f2bf(b.z); o[7]=f2bf(b.w);
  } else {
    for (int j = 0; j < 8; ++j) o[j] = 0;
  }
  *(bf16x8*)((short*)dst + (size_t)r*YP + c8) = o;
}

// ---------------- pdt[ks][32][1536] = y-slice @ tl_w-slice^T  (MFMA, M=32)
__global__ __launch_bounds__(256) void k_dtgemm(const __hip_bfloat16* __restrict__ yB,
                       const __hip_bfloat16* __restrict__ WB, float* __restrict__ pdt){
  __shared__ __align__(16) short lA[32*32];
  __shared__ __align__(16) short lB[256*32];
  int nt = blockIdx.x, ks = blockIdx.y;
  int o0 = nt*256;
  int tid = threadIdx.x;
  int w = tid >> 6, l = tid & 63;
  int lrow = l & 15, lk = l >> 4;
  f32x4 acc[2][4];
  #pragma unroll
  for (int m = 0; m < 2; ++m)
    #pragma unroll
    for (int n = 0; n < 4; ++n) acc[m][n] = (f32x4){0.f,0.f,0.f,0.f};
  for (int step = 0; step < 6; ++step){
    int k0 = (ks*6 + step)*32;
    // stage B: 256 rows x 32 cols bf16 = 16 chunks of 512 shorts
    #pragma unroll
    for (int p = 0; p < 4; ++p){
      int c = p*4 + w;
      int off = c*512 + l*8;
      int row = off >> 5, col = off & 31;
      __builtin_amdgcn_global_load_lds(
        (const __attribute__((address_space(1))) void*)((const short*)WB + (size_t)(o0 + row)*YP + k0 + col),
        (__attribute__((address_space(3))) void*)(lB + c*512), 16, 0, 0);
    }
    // stage A: 32 rows x 32 cols = 2 chunks (waves 0,1)
    if (w < 2){
      int off = w*512 + l*8;
      int row = off >> 5, col = off & 31;
      __builtin_amdgcn_global_load_lds(
        (const __attribute__((address_space(1))) void*)((const short*)yB + (size_t)row*YP + k0 + col),
        (__attribute__((address_space(3))) void*)(lA + w*512), 16, 0, 0);
    }
    __syncthreads();
    bf16x8 a[2], bv[4];
    #pragma unroll
    for (int m = 0; m < 2; ++m) a[m] = *(const bf16x8*)(lA + (m*16 + lrow)*32 + lk*8);
    #pragma unroll
    for (int n = 0; n < 4; ++n) bv[n] = *(const bf16x8*)(lB + (w*64 + n*16 + lrow)*32 + lk*8);
    #pragma unroll
    for (int m = 0; m < 2; ++m)
      #pragma unroll
      for (int n = 0; n < 4; ++n)
        acc[m][n] = __builtin_amdgcn_mfma_f32_16x16x32_bf16(a[m], bv[n], acc[m][n], 0, 0, 0);
    __syncthreads();
  }
  #pragma unroll
  for (int m = 0; m < 2; ++m){
    #pragma unroll
    for (int n = 0; n < 4; ++n){
      int o = o0 + w*64 + n*16 + lrow;
      #pragma unroll
      for (int j = 0; j < 4; ++j){
        int b = m*16 + lk*4 + j;
        pdt[((size_t)(ks*32 + b))*CT + o] = acc[m][n][j];
      }
    }
  }
}

// ---------------- dt = sum_ks pdt + tl_b
__global__ void k_dtred(const float* __restrict__ pdt, const float* __restrict__ tl_b,
                        float* __restrict__ dt){
  int gid = blockIdx.x*256 + threadIdx.x;   // 49152
  int b = gid / CT, o = gid % CT;
  float acc = tl_b[o];
  #pragma unroll
  for (int ks = 0; ks < 19; ++ks) acc += pdt[((size_t)(ks*32 + b))*CT + o];
  dt[gid] = acc;
}

// ---------------- per-b small reductions: xu, du3a, du3b, w1a
__global__ void k_small(const float* __restrict__ x, const float* __restrict__ dt,
                        const float* __restrict__ u0_w, const float* __restrict__ u0_b,
                        const float* __restrict__ u1a, const float* __restrict__ u3a,
                        const float* __restrict__ u3b, const float* __restrict__ sums,
                        float* __restrict__ w1a, float* __restrict__ du3a, float* __restrict__ du3b){
  __shared__ float xu_s[TT], u1a_s[NN];
  int b = blockIdx.x, tid = threadIdx.x;
  for (int i = tid; i < NN; i += 256) u1a_s[i] = u1a[i];
  __syncthreads();
  int wv = tid >> 6, ln = tid & 63;
  for (int t = wv; t < TT; t += 4){
    float acc = 0.f;
    for (int n = ln; n < NN; n += 64) acc += u1a_s[n]*x[(size_t)(b*NN + n)*TT + t];
    for (int off = 32; off; off >>= 1) acc += __shfl_down(acc, off);
    if (ln == 0) xu_s[t] = acc;
  }
  if (tid < TT){
    float a = 0.f, c = 0.f;
    for (int f = 0; f < CC; ++f){
      float d = dt[b*CT + tid*CC + f];
      a += u3a[f]*d; c += u3b[f]*d;
    }
    du3a[b*TT + tid] = a;
    du3b[b*TT + tid] = c;
  }
  __syncthreads();
  float S1 = sums[0];
  for (int idx = tid; idx < CC*TT; idx += 256){
    int f = idx / TT, tp = idx % TT;
    float acc = 0.f;
    const float* wrow = u0_w + (f*TT + tp)*TT;
    for (int t = 0; t < TT; ++t) acc += wrow[t]*xu_s[t];
    w1a[b*CC*TT + idx] = acc + S1*(u0_b[f*TT + tp] + dt[b*CT + tp*CC + f]);
  }
}

// ---------------- rhs1[b][n][t'] = b0u3[t'] + du3a[b][t'] + sum_t w0u3[t'][t]*x[b,n,t]
__global__ __launch_bounds__(384) void k_rhs1(const float* __restrict__ x, const float* __restrict__ w0u3,
                      const float* __restrict__ b0u3, const float* __restrict__ du3a,
                      float* __restrict__ rhs1){
  __shared__ float xs[16*TT], w0_s[576], bd_s[TT];
  int b = blockIdx.y, n0 = blockIdx.x*16, tid = threadIdx.x;
  for (int i = tid; i < 576; i += 384) w0_s[i] = w0u3[i];
  if (tid < TT) bd_s[tid] = b0u3[tid] + du3a[b*TT + tid];
  xs[tid] = x[(size_t)(b*NN + n0)*TT + tid];
  __syncthreads();
  int nn = tid / TT, tp = tid % TT;
  float acc = bd_s[tp];
  const float* wr = w0_s + tp*TT;
  const float* xr = xs + nn*TT;
  for (int t = 0; t < TT; ++t) acc += wr[t]*xr[t];
  rhs1[(size_t)b*NN*TT + (n0 + nn)*TT + tp] = acc;
}

// ---------------- lhs[b][t][m] = sum_f u2[f,m]*w1[b][f][t]
__global__ void k_lhs(const float* __restrict__ u2, const float* __restrict__ w1,
                      float* __restrict__ lhs){
  int b = blockIdx.y;
  int j = blockIdx.x*256 + threadIdx.x;
  int t = j >> 9, m = j & 511;
  const float* w = w1 + b*CC*TT;
  float acc = 0.f;
  #pragma unroll 8
  for (int f = 0; f < CC; ++f) acc += u2[f*NN + m]*w[f*TT + t];
  lhs[(size_t)b*TT*NN + j] = acc;
}

// ---------------- partial prod over 64-n slices
__global__ __launch_bounds__(576) void k_prod(const float* __restrict__ lhs, const float* __restrict__ rhs,
                      float* __restrict__ pprod){
  __shared__ float lh[TT][64], rh[64][TT];
  int ns = blockIdx.x, b = blockIdx.y;
  int n0 = ns*64, tid = threadIdx.x;
  for (int i = tid; i < 1536; i += 576){ int t = i >> 6, n = i & 63; lh[t][n] = lhs[(size_t)b*TT*NN + t*NN + n0 + n]; }
  for (int i = tid; i < 1536; i += 576){ ((float*)rh)[i] = rhs[(size_t)b*NN*TT + n0*TT + i]; }
  __syncthreads();
  int t = tid / TT, s = tid % TT;
  float acc = 0.f;
  #pragma unroll 4
  for (int n = 0; n < 64; ++n) acc += lh[t][n]*rh[n][s];
  pprod[((size_t)(b*8 + ns))*576 + tid] = acc;
}

// ---------------- attention tail: sum partials -> sigmoid -> ve -> softmax(axis t)
__global__ void k_att_post2(const float* __restrict__ pprod, const float* __restrict__ ve,
                            const float* __restrict__ be, float* __restrict__ E){
  __shared__ float sig_s[TT*TT], E_s[TT*TT];
  int b = blockIdx.x, tid = threadIdx.x;
  float acc = 0.f;
  #pragma unroll
  for (int p = 0; p < 8; ++p) acc += pprod[((size_t)(b*8 + p))*576 + tid];
  sig_s[tid] = 1.f/(1.f + expf(-(acc + be[tid])));
  __syncthreads();
  {
    int t = tid / TT, r = tid % TT;
    float a = 0.f;
    for (int s = 0; s < TT; ++s) a += ve[t*TT + s]*sig_s[s*TT + r];
    E_s[tid] = a;
  }
  __syncthreads();
  if (tid < TT){
    int r = tid;
    float mx = -1e30f;
    for (int t = 0; t < TT; ++t) mx = fmaxf(mx, E_s[t*TT + r]);
    float sum = 0.f;
    for (int t = 0; t < TT; ++t) sum += expf(E_s[t*TT + r] - mx);
    float inv = 1.f/sum;
    for (int t = 0; t < TT; ++t) E[(size_t)b*TT*TT + t*TT + r] = expf(E_s[t*TT + r] - mx)*inv;
  }
}

// ---------------- lx/r2 for spatial attention
__global__ void k_xtat(const float* __restrict__ x, const float* __restrict__ E1,
                       const float* __restrict__ sw1, const float* __restrict__ sw2,
                       const float* __restrict__ sw3,
                       float* __restrict__ lx, float* __restrict__ r2){
  __shared__ float E_s[TT*TT], sw1_s[TT], sw2_s[TT];
  int b = blockIdx.x >> 1, half = blockIdx.x & 1, tid = threadIdx.x;
  for (int i = tid; i < 576; i += 256) E_s[i] = E1[(size_t)b*576 + i];
  if (tid < TT){ sw1_s[tid] = sw1[tid]; sw2_s[tid] = sw2[tid]; }
  __syncthreads();
  int n = half*256 + tid;
  float xr[TT];
  const float* xp = x + (size_t)(b*NN + n)*TT;
  for (int t = 0; t < TT; ++t) xr[t] = xp[t];
  float l = 0.f, r = 0.f;
  for (int s = 0; s < TT; ++s){
    float acc = 0.f;
    for (int t = 0; t < TT; ++t) acc += xr[t]*E_s[t*TT + s];
    l += acc*sw1_s[s];
    r += acc*sw2_s[s];
  }
  lx[b*NN + n] = l;
  r2[b*NN + n] = r*sw3[0];
}

// ---------------- s_vs fp32 -> bf16
__global__ void k_convS(const float* __restrict__ S, __hip_bfloat16* __restrict__ Sb){
  int i = (blockIdx.x*256 + threadIdx.x)*4;
  float4 v = *(const float4*)(S + i);
  Sb[i+0] = __float2bfloat16(v.x);
  Sb[i+1] = __float2bfloat16(v.y);
  Sb[i+2] = __float2bfloat16(v.z);
  Sb[i+3] = __float2bfloat16(v.w);
}

// ---------------- ST[b][k][n] = sum_m s_vs[n][m]*sigmoid(lx[m]*r2[k]+s_bs[m][k])  (MFMA)
__global__ __launch_bounds__(256) void k_S0(const __hip_bfloat16* __restrict__ svB,
                    const float* __restrict__ s_bs,
                    const float* __restrict__ lx, const float* __restrict__ r2,
                    float* __restrict__ ST){
  __shared__ __align__(16) short lA[128*32];
  __shared__ __align__(16) short lQ[128*32];
  __shared__ float sb_s[32][132];
  __shared__ float lx_s[32];
  int kt = blockIdx.x, nt = blockIdx.y, b = blockIdx.z;
  int n0 = nt*128, k0 = kt*128;
  int tid = threadIdx.x;
  int w = tid >> 6, l = tid & 63;
  int wr = w >> 1, wc = w & 1;
  int lrow = l & 15, lk = l >> 4;
  f32x4 acc[4][4];
  #pragma unroll
  for (int m = 0; m < 4; ++m)
    #pragma unroll
    for (int n = 0; n < 4; ++n) acc[m][n] = (f32x4){0.f,0.f,0.f,0.f};
  const float* lxb = lx + b*NN;
  int kq = tid >> 1;
  float r2q = r2[b*NN + k0 + kq];
  for (int m0 = 0; m0 < NN; m0 += 32){
    if (tid < 32) lx_s[tid] = lxb[m0 + tid];
    #pragma unroll
    for (int p = 0; p < 2; ++p){
      int c = p*4 + w;
      int off = c*512 + l*8;
      int row = off >> 5, col = off & 31;
      __builtin_amdgcn_global_load_lds(
        (const __attribute__((address_space(1))) void*)(svB + (size_t)(n0 + row)*NN + m0 + col),
        (__attribute__((address_space(3))) void*)(lA + c*512), 16, 0, 0);
    }
    #pragma unroll
    for (int q = 0; q < 4; ++q){
      int idx = tid + q*256;
      int mm = idx >> 5, k4 = idx & 31;
      float4 v = *(const float4*)(s_bs + (size_t)(mm)*NN + (size_t)m0*NN + k0 + k4*4);
      *(float4*)(&sb_s[mm][k4*4]) = v;
    }
    __syncthreads();
    #pragma unroll
    for (int c2 = 0; c2 < 2; ++c2){
      int mc = (tid & 1)*2 + c2;
      bf16x8 pk;
      #pragma unroll
      for (int j = 0; j < 8; ++j){
        int m = mc*8 + j;
        float v = lx_s[m]*r2q + sb_s[m][kq];
        float sg = 1.f/(1.f + __expf(-v));
        pk[j] = f2bf(sg);
      }
      *(bf16x8*)(lQ + kq*32 + mc*8) = pk;
    }
    __syncthreads();
    bf16x8 a[4], bv[4];
    #pragma unroll
    for (int m = 0; m < 4; ++m) a[m] = *(const bf16x8*)(lA + (wr*64 + m*16 + lrow)*32 + lk*8);
    #pragma unroll
    for (int n = 0; n < 4; ++n) bv[n] = *(const bf16x8*)(lQ + (wc*64 + n*16 + lrow)*32 + lk*8);
    #pragma unroll
    for (int m = 0; m < 4; ++m)
      #pragma unroll
      for (int n = 0; n < 4; ++n)
        acc[m][n] = __builtin_amdgcn_mfma_f32_16x16x32_bf16(a[m], bv[n], acc[m][n], 0, 0, 0);
    __syncthreads();
  }
  #pragma unroll
  for (int m = 0; m < 4; ++m){
    #pragma unroll
    for (int n = 0; n < 4; ++n){
      int col = k0 + wc*64 + n*16 + lrow;
      int row = n0 + wr*64 + m*16 + lk*4;
      float4 v; v.x = acc[m][n][0]; v.y = acc[m][n][1]; v.z = acc[m][n][2]; v.w = acc[m][n][3];
      *(float4*)(ST + (size_t)b*NN*NN + (size_t)col*NN + row) = v;
    }
  }
}

// ---------------- row softmax on ST (over n, contiguous)
__global__ __launch_bounds__(256) void k_softST(float* __restrict__ ST){
  int b = blockIdx.y;
  int row = blockIdx.x*4 + (threadIdx.x >> 6);
  int l = threadIdx.x & 63;
  float* R = ST + (size_t)b*NN*NN + (size_t)row*NN;
  float4 v0 = *(float4*)(R + l*8);
  float4 v1 = *(float4*)(R + l*8 + 4);
  float mx = fmaxf(fmaxf(fmaxf(v0.x,v0.y),fmaxf(v0.z,v0.w)),
                   fmaxf(fmaxf(v1.x,v1.y),fmaxf(v1.z,v1.w)));
  for (int off = 32; off; off >>= 1) mx = fmaxf(mx, __shfl_xor(mx, off));
  v0.x = expf(v0.x-mx); v0.y = expf(v0.y-mx); v0.z = expf(v0.z-mx); v0.w = expf(v0.w-mx);
  v1.x = expf(v1.x-mx); v1.y = expf(v1.y-mx); v1.z = expf(v1.z-mx); v1.w = expf(v1.w-mx);
  float s = v0.x+v0.y+v0.z+v0.w+v1.x+v1.y+v1.z+v1.w;
  for (int off = 32; off; off >>= 1) s += __shfl_xor(s, off);
  float inv = 1.f/s;
  v0.x*=inv; v0.y*=inv; v0.z*=inv; v0.w*=inv;
  v1.x*=inv; v1.y*=inv; v1.z*=inv; v1.w*=inv;
  *(float4*)(R + l*8) = v0;
  *(float4*)(R + l*8 + 4) = v1;
}

// ---------------- tmp_k[b,i,t] = sum_j cheb[k][j,i]*ST[b,i,j]*x[b,j,t]
__global__ __launch_bounds__(384) void k_tmp(const float* __restrict__ ST, const float* __restrict__ cheb,
                     const float* __restrict__ x, float* __restrict__ tmp){
  __shared__ float Ss[16*NN];
  int i0 = blockIdx.x*16, b = blockIdx.y, tid = threadIdx.x;
  for (int idx = tid; idx < 16*NN; idx += 384)
    Ss[idx] = ST[(size_t)b*NN*NN + (size_t)i0*NN + idx];
  __syncthreads();
  int ii = tid / TT, t = tid % TT;
  const float* xb = x + (size_t)b*NN*TT;
  const float* Sr = Ss + ii*NN;
  const float* c0 = cheb;
  const float* c1 = cheb + (size_t)NN*NN;
  const float* c2 = cheb + (size_t)2*NN*NN;
  float a0 = 0.f, a1 = 0.f, a2 = 0.f;
  for (int j = 0; j < NN; ++j){
    float sx = Sr[j]*xb[j*TT + t];
    a0 += c0[(size_t)j*NN + i0 + ii]*sx;
    a1 += c1[(size_t)j*NN + i0 + ii]*sx;
    a2 += c2[(size_t)j*NN + i0 + ii]*sx;
  }
  tmp[((size_t)(0*BB + b)*NN + i0 + ii)*TT + t] = a0;
  tmp[((size_t)(1*BB + b)*NN + i0 + ii)*TT + t] = a1;
  tmp[((size_t)(2*BB + b)*NN + i0 + ii)*TT + t] = a2;
}

// ---------------- att2: per-16-n-tile two-pass: rhsg + partial w1g
__global__ __launch_bounds__(384) void k_gsum(const float* __restrict__ tmp, const float* __restrict__ theta,
                      const float* __restrict__ u1b, const float* __restrict__ u3b,
                      const float* __restrict__ du3b,
                      float* __restrict__ rhsg, float* __restrict__ pw1g){
  __shared__ float A0[16*TT], A1[16*TT], A2[16*TT], th_s[192], u3_s[CC], u1_s[16], du_s[TT];
  int nt = blockIdx.x, b = blockIdx.y;
  int n0 = nt*16, tid = threadIdx.x;
  for (int i = tid; i < 192; i += 384) th_s[i] = theta[i];
  if (tid < CC) u3_s[tid] = u3b[tid];
  if (tid < 16) u1_s[tid] = u1b[n0 + tid];
  if (tid < TT) du_s[tid] = du3b[b*TT + tid];
  A0[tid] = tmp[((size_t)(0*BB + b)*NN + n0)*TT + tid];
  A1[tid] = tmp[((size_t)(1*BB + b)*NN + n0)*TT + tid];
  A2[tid] = tmp[((size_t)(2*BB + b)*NN + n0)*TT + tid];
  __syncthreads();
  {
    int nn = tid / TT, t = tid % TT;
    float a0 = A0[nn*TT + t], a1 = A1[nn*TT + t], a2 = A2[nn*TT + t];
    float acc = du_s[t];
    #pragma unroll 8
    for (int f = 0; f < CC; ++f){
      float v = th_s[f]*a0 + th_s[64 + f]*a1 + th_s[128 + f]*a2;
      acc += u3_s[f]*fmaxf(v, 0.f);
    }
    rhsg[(size_t)b*NN*TT + (n0 + nn)*TT + t] = acc;
  }
  #pragma unroll
  for (int p = 0; p < 4; ++p){
    int o = tid + p*384;
    int f = o / TT, t = o % TT;
    float t0 = th_s[f], t1 = th_s[64 + f], t2 = th_s[128 + f];
    float acc = 0.f;
    #pragma unroll
    for (int m = 0; m < 16; ++m){
      float v = t0*A0[m*TT + t] + t1*A1[m*TT + t] + t2*A2[m*TT + t];
      acc += u1_s[m]*fmaxf(v, 0.f);
    }
    pw1g[((size_t)(b*32 + nt))*CC*TT + o] = acc;
  }
}

// ---------------- reduce partial w1g + S2*dt
__global__ void k_w1g_red(const float* __restrict__ pw1g, const float* __restrict__ dt,
                          const float* __restrict__ sums, float* __restrict__ w1g){
  int b = blockIdx.x, tid = threadIdx.x;
  float S2 = sums[1];
  for (int o = tid; o < CC*TT; o += 256){
    int f = o / TT, t = o % TT;
    float acc = 0.f;
    for (int nt = 0; nt < 32; ++nt) acc += pw1g[((size_t)(b*32 + nt))*CC*TT + o];
    w1g[b*CC*TT + o] = acc + S2*dt[b*CT + t*CC + f];
  }
}

// ---------------- g2 (bf16) = relu(theta·tmp) @ E2
__global__ void k_g2(const float* __restrict__ tmp, const float* __restrict__ E2,
                     const float* __restrict__ theta, __hip_bfloat16* __restrict__ g2){
  __shared__ float E_s[TT*TT], th_s[192], tr[3*4*TT], g_s[4*CT];
  int b = blockIdx.y, n0 = blockIdx.x*4, tid = threadIdx.x;
  for (int i = tid; i < 576; i += 256) E_s[i] = E2[(size_t)b*576 + i];
  for (int i = tid; i < 192; i += 256) th_s[i] = theta[i];
  for (int i = tid; i < 288; i += 256){
    int k = i / 96, rem = i % 96, nn = rem / TT, s = rem % TT;
    tr[i] = tmp[((size_t)(k*BB + b)*NN + n0 + nn)*TT + s];
  }
  __syncthreads();
  for (int idx = tid; idx < 4*CT; idx += 256){
    int nn = idx / CT, rem = idx % CT, f = rem / TT, s = rem % TT;
    float v = th_s[f]*tr[nn*TT + s] + th_s[64 + f]*tr[96 + nn*TT + s] + th_s[128 + f]*tr[192 + nn*TT + s];
    g_s[idx] = fmaxf(v, 0.f);
  }
  __syncthreads();
  for (int idx = tid; idx < 4*CT; idx += 256){
    int nn = idx / CT, rem = idx % CT, f = rem / TT, t = rem % TT;
    float acc = 0.f;
    const float* gr = g_s + nn*CT + f*TT;
    for (int s = 0; s < TT; ++s) acc += gr[s]*E_s[s*TT + t];
    g2[(size_t)(b*NN + n0 + nn)*CT + rem] = __float2bfloat16(acc);
  }
}

// ---------------- l1_w fp32 -> bf16
__global__ void k_convW(const float* __restrict__ W, __hip_bfloat16* __restrict__ Wb){
  int i = (blockIdx.x*256 + threadIdx.x)*4;
  float4 v = *(const float4*)(W + i);
  Wb[i+0] = __float2bfloat16(v.x);
  Wb[i+1] = __float2bfloat16(v.y);
  Wb[i+2] = __float2bfloat16(v.z);
  Wb[i+3] = __float2bfloat16(v.w);
}

// ---------------- tlin = A(16384x1536,bf16) @ W^T(bf16) + l1_b
__global__ __launch_bounds__(256) void k_gemm_bf16(const __hip_bfloat16* __restrict__ A,
                      const __hip_bfloat16* __restrict__ W,
                      const float* __restrict__ bias, float* __restrict__ Cout){
  __shared__ __align__(16) short lA[128*32];
  __shared__ __align__(16) short lB[128*32];
  int i0 = blockIdx.y*128, o0 = blockIdx.x*128;
  int tid = threadIdx.x;
  int w = tid >> 6, l = tid & 63;
  int wr = w >> 1, wc = w & 1;
  f32x4 acc[4][4];
  #pragma unroll
  for (int m = 0; m < 4; ++m)
    #pragma unroll
    for (int n = 0; n < 4; ++n) acc[m][n] = (f32x4){0.f,0.f,0.f,0.f};
  int lrow = l & 15, lk = (l >> 4);
  for (int k0 = 0; k0 < CT; k0 += 32){
    #pragma unroll
    for (int p = 0; p < 2; ++p){
      int c = p*4 + w;
      int off = c*512 + l*8;
      int row = off >> 5, col = off & 31;
      __builtin_amdgcn_global_load_lds(
        (const __attribute__((address_space(1))) void*)(A + (size_t)(i0 + row)*CT + k0 + col),
        (__attribute__((address_space(3))) void*)(lA + c*512), 16, 0, 0);
      __builtin_amdgcn_global_load_lds(
        (const __attribute__((address_space(1))) void*)(W + (size_t)(o0 + row)*CT + k0 + col),
        (__attribute__((address_space(3))) void*)(lB + c*512), 16, 0, 0);
    }
    __syncthreads();
    bf16x8 a[4], bv[4];
    #pragma unroll
    for (int m = 0; m < 4; ++m) a[m] = *(const bf16x8*)(lA + (wr*64 + m*16 + lrow)*32 + lk*8);
    #pragma unroll
    for (int n = 0; n < 4; ++n) bv[n] = *(const bf16x8*)(lB + (wc*64 + n*16 + lrow)*32 + lk*8);
    #pragma unroll
    for (int m = 0; m < 4; ++m)
      #pragma unroll
      for (int n = 0; n < 4; ++n)
        acc[m][n] = __builtin_amdgcn_mfma_f32_16x16x32_bf16(a[m], bv[n], acc[m][n], 0, 0, 0);
    __syncthreads();
  }
  #pragma unroll
  for (int m = 0; m < 4; ++m){
    #pragma unroll
    for (int n = 0; n < 4; ++n){
      int o = o0 + wc*64 + n*16 + lrow;
      float bo = bias[o];
      #pragma unroll
      for (int j = 0; j < 4; ++j){
        int i = i0 + wr*64 + m*16 + lk*4 + j;
        Cout[(size_t)i*CT + o] = acc[m][n][j] + bo;
      }
    }
  }
}

// ---------------- reshape + residual + relu + LayerNorm (LDS-staged)
__global__ __launch_bounds__(128) void k_final(const float* __restrict__ tlin, const float* __restrict__ x,
                      const float* __restrict__ res_w, const float* __restrict__ res_b,
                      const float* __restrict__ ln_g, const float* __restrict__ ln_b,
                      float* __restrict__ out){
  __shared__ float Ls[64][132];
  __shared__ float rw_s[64], rb_s[64], lg_s[64], lb_s[64];
  int ot = blockIdx.x, dlt = blockIdx.y, b = blockIdx.z;
  int o0 = ot*128, tid = threadIdx.x;
  if (tid < 64){ rw_s[tid]=res_w[tid]; rb_s[tid]=res_b[tid]; lg_s[tid]=ln_g[tid]; lb_s[tid]=ln_b[tid]; }
  const float* tb = tlin + (size_t)b*NN*CT;
  #pragma unroll 4
  for (int c = 0; c < 64; ++c)
    Ls[c][tid] = tb[(size_t)(c*8 + dlt)*CT + o0 + tid];
  __syncthreads();
  int p = dlt*CT + o0 + tid;
  int np = p / TT, tp = p % TT;
  float xv = x[(size_t)(b*NN + np)*TT + tp];
  float z[CC];
  float sum = 0.f, sq = 0.f;
  #pragma unroll
  for (int c = 0; c < CC; ++c){
    float v = Ls[c][tid] + xv*rw_s[c] + rb_s[c];
    v = fmaxf(v, 0.f);
    z[c] = v; sum += v; sq += v*v;
  }
  float mu = sum*(1.f/64.f);
  float var = sq*(1.f/64.f) - mu*mu;
  float rstd = rsqrtf(var + 1e-5f);
  float* ob = out + (size_t)(b*NN + np)*CC*TT + tp;
  #pragma unroll
  for (int c = 0; c < CC; ++c)
    ob[c*TT] = (z[c] - mu)*rstd*lg_s[c] + lb_s[c];
}

extern "C" void kernel_launch(void* const* d_in, const int* in_sizes, int n_in,
                              void* d_out, int out_size, void* d_ws, size_t ws_size,
                              hipStream_t stream){
  const float* x    = (const float*)d_in[0];
  const float* y    = (const float*)d_in[1];
  const float* tl_w = (const float*)d_in[2];
  const float* tl_b = (const float*)d_in[3];
  const float* u0_w = (const float*)d_in[4];
  const float* u0_b = (const float*)d_in[5];
  const float* u1a  = (const float*)d_in[6];
  const float* u2a  = (const float*)d_in[7];
  const float* u3a  = (const float*)d_in[8];
  const float* be_a = (const float*)d_in[9];
  const float* ve_a = (const float*)d_in[10];
  const float* u1b  = (const float*)d_in[11];
  const float* u2b  = (const float*)d_in[12];
  const float* u3b  = (const float*)d_in[13];
  const float* be_b = (const float*)d_in[14];
  const float* ve_b = (const float*)d_in[15];
  const float* sw1  = (const float*)d_in[16];
  const float* sw2  = (const float*)d_in[17];
  const float* sw3  = (const float*)d_in[18];
  const float* s_bs = (const float*)d_in[19];
  const float* s_vs = (const float*)d_in[20];
  const float* cheb = (const float*)d_in[21];
  const float* theta= (const float*)d_in[22];
  const float* l1_w = (const float*)d_in[23];
  const float* l1_b = (const float*)d_in[24];
  const float* res_w= (const float*)d_in[25];
  const float* res_b= (const float*)d_in[26];
  const float* ln_g = (const float*)d_in[27];
  const float* ln_b = (const float*)d_in[28];
  float* out = (float*)d_out;
  float* ws  = (float*)d_ws;

  // ws layout (floats). Alias lifetimes (serial stream order):
  //  - WB/yB/pdt (dt pipeline) live in `big` BEFORE k_S0 writes ST there.
  //  - Wb (bf16, spans lhs1+rhs1+lhsg): k_convW only after E2 (2nd k_att_post2).
  //  - ST/pw1g/tlin share `big`: ST dead after k_tmp; pw1g dead after k_w1g_red.
  //  - g2b lives in d_out: dead once k_gemm_bf16 consumed it; k_final rewrites d_out.
  float* dt   = ws;               // 49152
  float* E    = dt   + 49152;     // 18432 (E1 then E2)
  float* lxp  = E    + 18432;     // 16384
  float* r2p  = lxp  + 16384;     // 16384
  float* w0u3 = r2p  + 16384;     // 640
  float* b0u3 = w0u3 + 640;       // 64
  float* sums = b0u3 + 64;        // 64
  float* du3a = sums + 64;        // 768
  float* du3b = du3a + 768;       // 768
  float* w1a  = du3b + 768;       // 49152
  float* w1g  = w1a  + 49152;     // 49152
  float* lhs1 = w1g  + 49152;     // 393216
  float* rhs1 = lhs1 + 393216;    // 393216
  float* lhsg = rhs1 + 393216;    // 393216
  float* rhsg = lhsg + 393216;    // 393216
  float* svBf = rhsg + 393216;    // 131072 (bf16 512x512)
  float* ppr  = svBf + 131072;    // 147456
  float* tmp  = ppr  + 147456;    // 1179648
  float* big  = tmp  + 1179648;   // ST: 8388608 / pw1g: 1572864 / tlin: 25165824
  float* ST   = big;
  float* pw1g = big;
  float* tlin = big;
  // dt-pipeline scratch inside big (dead before k_S0):
  __hip_bfloat16* WB = (__hip_bfloat16*)big;                 // 1536*3648 bf16 = 2801664 floats
  __hip_bfloat16* yB = (__hip_bfloat16*)(big + 2801664);     // 32*3648 bf16 = 58368 floats
  float* pdt = big + 2801664 + 58368;                        // 19*32*1536 = 933888 floats
  __hip_bfloat16* svB = (__hip_bfloat16*)svBf;
  __hip_bfloat16* Wb  = (__hip_bfloat16*)lhs1;   // valid only after E2
  __hip_bfloat16* g2b = (__hip_bfloat16*)d_out;

  k_prep0<<<dim3(1), dim3(576), 0, stream>>>(u0_w, u0_b, u1a, u3a, u1b, w0u3, b0u3, sums);
  k_convS<<<dim3(256), dim3(256), 0, stream>>>(s_vs, svB);
  // dt = y @ tl_w^T + tl_b  (MFMA path)
  k_convPad<<<dim3((32*(YP/8) + 255)/256), dim3(256), 0, stream>>>(y, yB, 32);
  k_convPad<<<dim3((1536*(YP/8) + 255)/256), dim3(256), 0, stream>>>(tl_w, WB, 1536);
  k_dtgemm<<<dim3(6, 19), dim3(256), 0, stream>>>(yB, WB, pdt);
  k_dtred<<<dim3(192), dim3(256), 0, stream>>>(pdt, tl_b, dt);
  k_small<<<dim3(32), dim3(256), 0, stream>>>(x, dt, u0_w, u0_b, u1a, u3a, u3b, sums, w1a, du3a, du3b);
  k_rhs1<<<dim3(32, 32), dim3(384), 0, stream>>>(x, w0u3, b0u3, du3a, rhs1);
  k_lhs<<<dim3(48, 32), dim3(256), 0, stream>>>(u2a, w1a, lhs1);
  k_prod<<<dim3(8, 32), dim3(576), 0, stream>>>(lhs1, rhs1, ppr);
  k_att_post2<<<dim3(32), dim3(576), 0, stream>>>(ppr, ve_a, be_a, E);
  k_xtat<<<dim3(64), dim3(256), 0, stream>>>(x, E, sw1, sw2, sw3, lxp, r2p);
  k_S0<<<dim3(4, 4, 32), dim3(256), 0, stream>>>(svB, s_bs, lxp, r2p, ST);
  k_softST<<<dim3(128, 32), dim3(256), 0, stream>>>(ST);
  k_tmp<<<dim3(32, 32), dim3(384), 0, stream>>>(ST, cheb, x, tmp);
  k_gsum<<<dim3(32, 32), dim3(384), 0, stream>>>(tmp, theta, u1b, u3b, du3b, rhsg, pw1g);
  k_w1g_red<<<dim3(32), dim3(256), 0, stream>>>(pw1g, dt, sums, w1g);
  k_lhs<<<dim3(48, 32), dim3(256), 0, stream>>>(u2b, w1g, lhsg);
  k_prod<<<dim3(8, 32), dim3(576), 0, stream>>>(lhsg, rhsg, ppr);
  k_att_post2<<<dim3(32), dim3(576), 0, stream>>>(ppr, ve_b, be_b, E);
  k_convW<<<dim3(2304), dim3(256), 0, stream>>>(l1_w, Wb);   // after E2: lhs1/rhs1/lhsg dead
  k_g2<<<dim3(128, 32), dim3(256), 0, stream>>>(tmp, E, theta, g2b);
  k_gemm_bf16<<<dim3(12, 128), dim3(256), 0, stream>>>(g2b, Wb, l1_b, tlin);
  k_final<<<dim3(12, 8, 32), dim3(128), 0, stream>>>(tlin, x, res_w, res_b, ln_g, ln_b, out);
}

// Round 7
// 520.422 us; speedup vs baseline: 5.6029x; 1.0236x over previous
//
#include <hip/hip_runtime.h>
#include <hip/hip_bf16.h>
#include <math.h>

#define BB 32
#define NN 512
#define TT 24
#define CC 64
#define CT 1536   // CC*TT
#define YD 3624   // 151*TT
#define YP 3648   // YD padded to 114*32

typedef __attribute__((ext_vector_type(4))) float f32x4;
typedef __attribute__((ext_vector_type(8))) short bf16x8;

static __device__ __forceinline__ short f2bf(float f){
  union { float f; unsigned u; } v; v.f = f;
  unsigned r = (v.u + 0x7FFF + ((v.u >> 16) & 1)) >> 16;
  return (short)r;
}

// ---------------- small precompute
__global__ void k_prep0(const float* __restrict__ u0_w, const float* __restrict__ u0_b,
                        const float* __restrict__ u1a, const float* __restrict__ u3a,
                        const float* __restrict__ u1b,
                        float* __restrict__ w0u3, float* __restrict__ b0u3, float* __restrict__ sums){
  int tid = threadIdx.x;
  if (tid < 576){
    int tp = tid / TT, t = tid % TT;
    float acc = 0.f;
    for (int f = 0; f < CC; ++f) acc += u3a[f] * u0_w[(f*TT + tp)*TT + t];
    w0u3[tid] = acc;
  }
  if (tid < TT){
    float acc = 0.f;
    for (int f = 0; f < CC; ++f) acc += u3a[f] * u0_b[f*TT + tid];
    b0u3[tid] = acc;
  }
  if (tid == 0){ float s = 0.f; for (int n = 0; n < NN; ++n) s += u1a[n]; sums[0] = s; }
  if (tid == 1){ float s = 0.f; for (int n = 0; n < NN; ++n) s += u1b[n]; sums[1] = s; }
}

// ---------------- fp32 [rows][3624] -> bf16 [rows][3648] zero-padded
__global__ void k_convPad(const float* __restrict__ src, __hip_bfloat16* __restrict__ dst, int rows){
  int gid = blockIdx.x*256 + threadIdx.x;
  int r = gid / (YP/8), c8 = (gid % (YP/8))*8;
  if (r >= rows) return;
  bf16x8 o;
  if (c8 < YD){
    float4 a = *(const float4*)(src + (size_t)r*YD + c8);
    float4 b = *(const float4*)(src + (size_t)r*YD + c8 + 4);
    o[0]=f2bf(a.x); o[1]=f2bf(a.y); o[2]=f2bf(a.z); o[3]=f2bf(a.w);
    o[4]=f2bf(b.x); o[5]=f2bf(b.y); o[6]=f2bf(b.z); o[7]=f2bf(b.w);
  } else {
    for (int j = 0; j < 8; ++j) o[j] = 0;
  }
  *(bf16x8*)((short*)dst + (size_t)r*YP + c8) = o;
}

// ---------------- pdt[ks][32][1536] = y-slice @ tl_w-slice^T  (MFMA, M=32)
__global__ __launch_bounds__(256) void k_dtgemm(const __hip_bfloat16* __restrict__ yB,
                       const __hip_bfloat16* __restrict__ WB, float* __restrict__ pdt){
  __shared__ __align__(16) short lA[32*32];
  __shared__ __align__(16) short lB[256*32];
  int nt = blockIdx.x, ks = blockIdx.y;
  int o0 = nt*256;
  int tid = threadIdx.x;
  int w = tid >> 6, l = tid & 63;
  int lrow = l & 15, lk = l >> 4;
  f32x4 acc[2][4];
  #pragma unroll
  for (int m = 0; m < 2; ++m)
    #pragma unroll
    for (int n = 0; n < 4; ++n) acc[m][n] = (f32x4){0.f,0.f,0.f,0.f};
  for (int step = 0; step < 6; ++step){
    int k0 = (ks*6 + step)*32;
    #pragma unroll
    for (int p = 0; p < 4; ++p){
      int c = p*4 + w;
      int off = c*512 + l*8;
      int row = off >> 5, col = off & 31;
      __builtin_amdgcn_global_load_lds(
        (const __attribute__((address_space(1))) void*)((const short*)WB + (size_t)(o0 + row)*YP + k0 + col),
        (__attribute__((address_space(3))) void*)(lB + c*512), 16, 0, 0);
    }
    if (w < 2){
      int off = w*512 + l*8;
      int row = off >> 5, col = off & 31;
      __builtin_amdgcn_global_load_lds(
        (const __attribute__((address_space(1))) void*)((const short*)yB + (size_t)row*YP + k0 + col),
        (__attribute__((address_space(3))) void*)(lA + w*512), 16, 0, 0);
    }
    __syncthreads();
    bf16x8 a[2], bv[4];
    #pragma unroll
    for (int m = 0; m < 2; ++m) a[m] = *(const bf16x8*)(lA + (m*16 + lrow)*32 + lk*8);
    #pragma unroll
    for (int n = 0; n < 4; ++n) bv[n] = *(const bf16x8*)(lB + (w*64 + n*16 + lrow)*32 + lk*8);
    #pragma unroll
    for (int m = 0; m < 2; ++m)
      #pragma unroll
      for (int n = 0; n < 4; ++n)
        acc[m][n] = __builtin_amdgcn_mfma_f32_16x16x32_bf16(a[m], bv[n], acc[m][n], 0, 0, 0);
    __syncthreads();
  }
  #pragma unroll
  for (int m = 0; m < 2; ++m){
    #pragma unroll
    for (int n = 0; n < 4; ++n){
      int o = o0 + w*64 + n*16 + lrow;
      #pragma unroll
      for (int j = 0; j < 4; ++j){
        int b = m*16 + lk*4 + j;
        pdt[((size_t)(ks*32 + b))*CT + o] = acc[m][n][j];
      }
    }
  }
}

// ---------------- dt = sum_ks pdt + tl_b
__global__ void k_dtred(const float* __restrict__ pdt, const float* __restrict__ tl_b,
                        float* __restrict__ dt){
  int gid = blockIdx.x*256 + threadIdx.x;
  int b = gid / CT, o = gid % CT;
  float acc = tl_b[o];
  #pragma unroll
  for (int ks = 0; ks < 19; ++ks) acc += pdt[((size_t)(ks*32 + b))*CT + o];
  dt[gid] = acc;
}

// ---------------- per-b small reductions: xu, du3a, du3b, w1a
__global__ void k_small(const float* __restrict__ x, const float* __restrict__ dt,
                        const float* __restrict__ u0_w, const float* __restrict__ u0_b,
                        const float* __restrict__ u1a, const float* __restrict__ u3a,
                        const float* __restrict__ u3b, const float* __restrict__ sums,
                        float* __restrict__ w1a, float* __restrict__ du3a, float* __restrict__ du3b){
  __shared__ float xu_s[TT], u1a_s[NN];
  int b = blockIdx.x, tid = threadIdx.x;
  for (int i = tid; i < NN; i += 256) u1a_s[i] = u1a[i];
  __syncthreads();
  int wv = tid >> 6, ln = tid & 63;
  for (int t = wv; t < TT; t += 4){
    float acc = 0.f;
    for (int n = ln; n < NN; n += 64) acc += u1a_s[n]*x[(size_t)(b*NN + n)*TT + t];
    for (int off = 32; off; off >>= 1) acc += __shfl_down(acc, off);
    if (ln == 0) xu_s[t] = acc;
  }
  if (tid < TT){
    float a = 0.f, c = 0.f;
    for (int f = 0; f < CC; ++f){
      float d = dt[b*CT + tid*CC + f];
      a += u3a[f]*d; c += u3b[f]*d;
    }
    du3a[b*TT + tid] = a;
    du3b[b*TT + tid] = c;
  }
  __syncthreads();
  float S1 = sums[0];
  for (int idx = tid; idx < CC*TT; idx += 256){
    int f = idx / TT, tp = idx % TT;
    float acc = 0.f;
    const float* wrow = u0_w + (f*TT + tp)*TT;
    for (int t = 0; t < TT; ++t) acc += wrow[t]*xu_s[t];
    w1a[b*CC*TT + idx] = acc + S1*(u0_b[f*TT + tp] + dt[b*CT + tp*CC + f]);
  }
}

// ---------------- rhs1[b][n][t'] = b0u3[t'] + du3a[b][t'] + sum_t w0u3[t'][t]*x[b,n,t]
__global__ __launch_bounds__(384) void k_rhs1(const float* __restrict__ x, const float* __restrict__ w0u3,
                      const float* __restrict__ b0u3, const float* __restrict__ du3a,
                      float* __restrict__ rhs1){
  __shared__ float xs[16*TT], w0_s[576], bd_s[TT];
  int b = blockIdx.y, n0 = blockIdx.x*16, tid = threadIdx.x;
  for (int i = tid; i < 576; i += 384) w0_s[i] = w0u3[i];
  if (tid < TT) bd_s[tid] = b0u3[tid] + du3a[b*TT + tid];
  xs[tid] = x[(size_t)(b*NN + n0)*TT + tid];
  __syncthreads();
  int nn = tid / TT, tp = tid % TT;
  float acc = bd_s[tp];
  const float* wr = w0_s + tp*TT;
  const float* xr = xs + nn*TT;
  for (int t = 0; t < TT; ++t) acc += wr[t]*xr[t];
  rhs1[(size_t)b*NN*TT + (n0 + nn)*TT + tp] = acc;
}

// ---------------- lhs[b][t][m] = sum_f u2[f,m]*w1[b][f][t]
__global__ void k_lhs(const float* __restrict__ u2, const float* __restrict__ w1,
                      float* __restrict__ lhs){
  int b = blockIdx.y;
  int j = blockIdx.x*256 + threadIdx.x;
  int t = j >> 9, m = j & 511;
  const float* w = w1 + b*CC*TT;
  float acc = 0.f;
  #pragma unroll 8
  for (int f = 0; f < CC; ++f) acc += u2[f*NN + m]*w[f*TT + t];
  lhs[(size_t)b*TT*NN + j] = acc;
}

// ---------------- partial prod over 64-n slices
__global__ __launch_bounds__(576) void k_prod(const float* __restrict__ lhs, const float* __restrict__ rhs,
                      float* __restrict__ pprod){
  __shared__ float lh[TT][64], rh[64][TT];
  int ns = blockIdx.x, b = blockIdx.y;
  int n0 = ns*64, tid = threadIdx.x;
  for (int i = tid; i < 1536; i += 576){ int t = i >> 6, n = i & 63; lh[t][n] = lhs[(size_t)b*TT*NN + t*NN + n0 + n]; }
  for (int i = tid; i < 1536; i += 576){ ((float*)rh)[i] = rhs[(size_t)b*NN*TT + n0*TT + i]; }
  __syncthreads();
  int t = tid / TT, s = tid % TT;
  float acc = 0.f;
  #pragma unroll 4
  for (int n = 0; n < 64; ++n) acc += lh[t][n]*rh[n][s];
  pprod[((size_t)(b*8 + ns))*576 + tid] = acc;
}

// ---------------- attention tail: sum partials -> sigmoid -> ve -> softmax(axis t)
__global__ void k_att_post2(const float* __restrict__ pprod, const float* __restrict__ ve,
                            const float* __restrict__ be, float* __restrict__ E){
  __shared__ float sig_s[TT*TT], E_s[TT*TT];
  int b = blockIdx.x, tid = threadIdx.x;
  float acc = 0.f;
  #pragma unroll
  for (int p = 0; p < 8; ++p) acc += pprod[((size_t)(b*8 + p))*576 + tid];
  sig_s[tid] = 1.f/(1.f + expf(-(acc + be[tid])));
  __syncthreads();
  {
    int t = tid / TT, r = tid % TT;
    float a = 0.f;
    for (int s = 0; s < TT; ++s) a += ve[t*TT + s]*sig_s[s*TT + r];
    E_s[tid] = a;
  }
  __syncthreads();
  if (tid < TT){
    int r = tid;
    float mx = -1e30f;
    for (int t = 0; t < TT; ++t) mx = fmaxf(mx, E_s[t*TT + r]);
    float sum = 0.f;
    for (int t = 0; t < TT; ++t) sum += expf(E_s[t*TT + r] - mx);
    float inv = 1.f/sum;
    for (int t = 0; t < TT; ++t) E[(size_t)b*TT*TT + t*TT + r] = expf(E_s[t*TT + r] - mx)*inv;
  }
}

// ---------------- lx/r2 for spatial attention
__global__ void k_xtat(const float* __restrict__ x, const float* __restrict__ E1,
                       const float* __restrict__ sw1, const float* __restrict__ sw2,
                       const float* __restrict__ sw3,
                       float* __restrict__ lx, float* __restrict__ r2){
  __shared__ float E_s[TT*TT], sw1_s[TT], sw2_s[TT];
  int b = blockIdx.x >> 1, half = blockIdx.x & 1, tid = threadIdx.x;
  for (int i = tid; i < 576; i += 256) E_s[i] = E1[(size_t)b*576 + i];
  if (tid < TT){ sw1_s[tid] = sw1[tid]; sw2_s[tid] = sw2[tid]; }
  __syncthreads();
  int n = half*256 + tid;
  float xr[TT];
  const float* xp = x + (size_t)(b*NN + n)*TT;
  for (int t = 0; t < TT; ++t) xr[t] = xp[t];
  float l = 0.f, r = 0.f;
  for (int s = 0; s < TT; ++s){
    float acc = 0.f;
    for (int t = 0; t < TT; ++t) acc += xr[t]*E_s[t*TT + s];
    l += acc*sw1_s[s];
    r += acc*sw2_s[s];
  }
  lx[b*NN + n] = l;
  r2[b*NN + n] = r*sw3[0];
}

// ---------------- s_vs fp32 -> bf16
__global__ void k_convS(const float* __restrict__ S, __hip_bfloat16* __restrict__ Sb){
  int i = (blockIdx.x*256 + threadIdx.x)*4;
  float4 v = *(const float4*)(S + i);
  Sb[i+0] = __float2bfloat16(v.x);
  Sb[i+1] = __float2bfloat16(v.y);
  Sb[i+2] = __float2bfloat16(v.z);
  Sb[i+3] = __float2bfloat16(v.w);
}

// ---------------- ST[b][k][n] = sum_m s_vs[n][m]*sigmoid(lx[m]*r2[k]+s_bs[m][k])  (MFMA)
__global__ __launch_bounds__(256) void k_S0(const __hip_bfloat16* __restrict__ svB,
                    const float* __restrict__ s_bs,
                    const float* __restrict__ lx, const float* __restrict__ r2,
                    float* __restrict__ ST){
  __shared__ __align__(16) short lA[128*32];
  __shared__ __align__(16) short lQ[128*32];
  __shared__ float sb_s[32][132];
  __shared__ float lx_s[32];
  int kt = blockIdx.x, nt = blockIdx.y, b = blockIdx.z;
  int n0 = nt*128, k0 = kt*128;
  int tid = threadIdx.x;
  int w = tid >> 6, l = tid & 63;
  int wr = w >> 1, wc = w & 1;
  int lrow = l & 15, lk = l >> 4;
  f32x4 acc[4][4];
  #pragma unroll
  for (int m = 0; m < 4; ++m)
    #pragma unroll
    for (int n = 0; n < 4; ++n) acc[m][n] = (f32x4){0.f,0.f,0.f,0.f};
  const float* lxb = lx + b*NN;
  int kq = tid >> 1;
  float r2q = r2[b*NN + k0 + kq];
  for (int m0 = 0; m0 < NN; m0 += 32){
    if (tid < 32) lx_s[tid] = lxb[m0 + tid];
    #pragma unroll
    for (int p = 0; p < 2; ++p){
      int c = p*4 + w;
      int off = c*512 + l*8;
      int row = off >> 5, col = off & 31;
      __builtin_amdgcn_global_load_lds(
        (const __attribute__((address_space(1))) void*)(svB + (size_t)(n0 + row)*NN + m0 + col),
        (__attribute__((address_space(3))) void*)(lA + c*512), 16, 0, 0);
    }
    #pragma unroll
    for (int q = 0; q < 4; ++q){
      int idx = tid + q*256;
      int mm = idx >> 5, k4 = idx & 31;
      float4 v = *(const float4*)(s_bs + (size_t)(mm)*NN + (size_t)m0*NN + k0 + k4*4);
      *(float4*)(&sb_s[mm][k4*4]) = v;
    }
    __syncthreads();
    #pragma unroll
    for (int c2 = 0; c2 < 2; ++c2){
      int mc = (tid & 1)*2 + c2;
      bf16x8 pk;
      #pragma unroll
      for (int j = 0; j < 8; ++j){
        int m = mc*8 + j;
        float v = lx_s[m]*r2q + sb_s[m][kq];
        float sg = 1.f/(1.f + __expf(-v));
        pk[j] = f2bf(sg);
      }
      *(bf16x8*)(lQ + kq*32 + mc*8) = pk;
    }
    __syncthreads();
    bf16x8 a[4], bv[4];
    #pragma unroll
    for (int m = 0; m < 4; ++m) a[m] = *(const bf16x8*)(lA + (wr*64 + m*16 + lrow)*32 + lk*8);
    #pragma unroll
    for (int n = 0; n < 4; ++n) bv[n] = *(const bf16x8*)(lQ + (wc*64 + n*16 + lrow)*32 + lk*8);
    #pragma unroll
    for (int m = 0; m < 4; ++m)
      #pragma unroll
      for (int n = 0; n < 4; ++n)
        acc[m][n] = __builtin_amdgcn_mfma_f32_16x16x32_bf16(a[m], bv[n], acc[m][n], 0, 0, 0);
    __syncthreads();
  }
  #pragma unroll
  for (int m = 0; m < 4; ++m){
    #pragma unroll
    for (int n = 0; n < 4; ++n){
      int col = k0 + wc*64 + n*16 + lrow;
      int row = n0 + wr*64 + m*16 + lk*4;
      float4 v; v.x = acc[m][n][0]; v.y = acc[m][n][1]; v.z = acc[m][n][2]; v.w = acc[m][n][3];
      *(float4*)(ST + (size_t)b*NN*NN + (size_t)col*NN + row) = v;
    }
  }
}

// ---------------- fused: row-softmax(ST) + tmp_k[b,i,t] = sum_j cheb[k][j,i]*P[b,i,j]*x[b,j,t]
// Ss stride 513 -> bank (ii+j)%32, conflict-free. Softmax folded: exp in LDS, 1/Z at epilogue.
__global__ __launch_bounds__(384) void k_tmp(const float* __restrict__ ST, const float* __restrict__ cheb,
                     const float* __restrict__ x, float* __restrict__ tmp){
  __shared__ float Ss[16*513];
  __shared__ float red[16][17];
  __shared__ float invZ[16];
  int i0 = blockIdx.x*16, b = blockIdx.y, tid = threadIdx.x;
  for (int idx = tid; idx < 16*NN; idx += 384){
    int ii = idx >> 9, j = idx & 511;
    Ss[ii*513 + j] = ST[(size_t)b*NN*NN + (size_t)i0*NN + idx];
  }
  __syncthreads();
  // row max (strided segments j = seg + 16*q to spread banks)
  if (tid < 256){
    int ii = tid >> 4, seg = tid & 15;
    const float* r = Ss + ii*513;
    float m = -1e30f;
    #pragma unroll
    for (int q = 0; q < 32; ++q) m = fmaxf(m, r[seg + q*16]);
    red[ii][seg] = m;
  }
  __syncthreads();
  if (tid < 16){
    float m = red[tid][0];
    #pragma unroll
    for (int q = 1; q < 16; ++q) m = fmaxf(m, red[tid][q]);
    red[tid][16] = m;
  }
  __syncthreads();
  for (int idx = tid; idx < 16*NN; idx += 384){
    int ii = idx >> 9, j = idx & 511;
    Ss[ii*513 + j] = __expf(Ss[ii*513 + j] - red[ii][16]);
  }
  __syncthreads();
  if (tid < 256){
    int ii = tid >> 4, seg = tid & 15;
    const float* r = Ss + ii*513;
    float s = 0.f;
    #pragma unroll
    for (int q = 0; q < 32; ++q) s += r[seg + q*16];
    red[ii][seg] = s;
  }
  __syncthreads();
  if (tid < 16){
    float s = 0.f;
    #pragma unroll
    for (int q = 0; q < 16; ++q) s += red[tid][q];
    invZ[tid] = 1.f/s;
  }
  __syncthreads();
  int ii = tid / TT, t = tid % TT;
  const float* xb = x + (size_t)b*NN*TT;
  const float* Sr = Ss + ii*513;
  const float* c0 = cheb;
  const float* c1 = cheb + (size_t)NN*NN;
  const float* c2 = cheb + (size_t)2*NN*NN;
  float a0 = 0.f, a1 = 0.f, a2 = 0.f;
  #pragma unroll 4
  for (int j = 0; j < NN; ++j){
    float sx = Sr[j]*xb[j*TT + t];
    a0 += c0[(size_t)j*NN + i0 + ii]*sx;
    a1 += c1[(size_t)j*NN + i0 + ii]*sx;
    a2 += c2[(size_t)j*NN + i0 + ii]*sx;
  }
  float iz = invZ[ii];
  tmp[((size_t)(0*BB + b)*NN + i0 + ii)*TT + t] = a0*iz;
  tmp[((size_t)(1*BB + b)*NN + i0 + ii)*TT + t] = a1*iz;
  tmp[((size_t)(2*BB + b)*NN + i0 + ii)*TT + t] = a2*iz;
}

// ---------------- att2: per-16-n-tile two-pass: rhsg + partial w1g
__global__ __launch_bounds__(384) void k_gsum(const float* __restrict__ tmp, const float* __restrict__ theta,
                      const float* __restrict__ u1b, const float* __restrict__ u3b,
                      const float* __restrict__ du3b,
                      float* __restrict__ rhsg, float* __restrict__ pw1g){
  __shared__ float A0[16*TT], A1[16*TT], A2[16*TT], th_s[192], u3_s[CC], u1_s[16], du_s[TT];
  int nt = blockIdx.x, b = blockIdx.y;
  int n0 = nt*16, tid = threadIdx.x;
  for (int i = tid; i < 192; i += 384) th_s[i] = theta[i];
  if (tid < CC) u3_s[tid] = u3b[tid];
  if (tid < 16) u1_s[tid] = u1b[n0 + tid];
  if (tid < TT) du_s[tid] = du3b[b*TT + tid];
  A0[tid] = tmp[((size_t)(0*BB + b)*NN + n0)*TT + tid];
  A1[tid] = tmp[((size_t)(1*BB + b)*NN + n0)*TT + tid];
  A2[tid] = tmp[((size_t)(2*BB + b)*NN + n0)*TT + tid];
  __syncthreads();
  {
    int nn = tid / TT, t = tid % TT;
    float a0 = A0[nn*TT + t], a1 = A1[nn*TT + t], a2 = A2[nn*TT + t];
    float acc = du_s[t];
    #pragma unroll 8
    for (int f = 0; f < CC; ++f){
      float v = th_s[f]*a0 + th_s[64 + f]*a1 + th_s[128 + f]*a2;
      acc += u3_s[f]*fmaxf(v, 0.f);
    }
    rhsg[(size_t)b*NN*TT + (n0 + nn)*TT + t] = acc;
  }
  #pragma unroll
  for (int p = 0; p < 4; ++p){
    int o = tid + p*384;
    int f = o / TT, t = o % TT;
    float t0 = th_s[f], t1 = th_s[64 + f], t2 = th_s[128 + f];
    float acc = 0.f;
    #pragma unroll
    for (int m = 0; m < 16; ++m){
      float v = t0*A0[m*TT + t] + t1*A1[m*TT + t] + t2*A2[m*TT + t];
      acc += u1_s[m]*fmaxf(v, 0.f);
    }
    pw1g[((size_t)(b*32 + nt))*CC*TT + o] = acc;
  }
}

// ---------------- reduce partial w1g + S2*dt
__global__ void k_w1g_red(const float* __restrict__ pw1g, const float* __restrict__ dt,
                          const float* __restrict__ sums, float* __restrict__ w1g){
  int b = blockIdx.x, tid = threadIdx.x;
  float S2 = sums[1];
  for (int o = tid; o < CC*TT; o += 256){
    int f = o / TT, t = o % TT;
    float acc = 0.f;
    for (int nt = 0; nt < 32; ++nt) acc += pw1g[((size_t)(b*32 + nt))*CC*TT + o];
    w1g[b*CC*TT + o] = acc + S2*dt[b*CT + t*CC + f];
  }
}

// ---------------- g2 (bf16) = relu(theta·tmp) @ E2
__global__ void k_g2(const float* __restrict__ tmp, const float* __restrict__ E2,
                     const float* __restrict__ theta, __hip_bfloat16* __restrict__ g2){
  __shared__ float E_s[TT*TT], th_s[192], tr[3*4*TT], g_s[4*CT];
  int b = blockIdx.y, n0 = blockIdx.x*4, tid = threadIdx.x;
  for (int i = tid; i < 576; i += 256) E_s[i] = E2[(size_t)b*576 + i];
  for (int i = tid; i < 192; i += 256) th_s[i] = theta[i];
  for (int i = tid; i < 288; i += 256){
    int k = i / 96, rem = i % 96, nn = rem / TT, s = rem % TT;
    tr[i] = tmp[((size_t)(k*BB + b)*NN + n0 + nn)*TT + s];
  }
  __syncthreads();
  for (int idx = tid; idx < 4*CT; idx += 256){
    int nn = idx / CT, rem = idx % CT, f = rem / TT, s = rem % TT;
    float v = th_s[f]*tr[nn*TT + s] + th_s[64 + f]*tr[96 + nn*TT + s] + th_s[128 + f]*tr[192 + nn*TT + s];
    g_s[idx] = fmaxf(v, 0.f);
  }
  __syncthreads();
  for (int idx = tid; idx < 4*CT; idx += 256){
    int nn = idx / CT, rem = idx % CT, f = rem / TT, t = rem % TT;
    float acc = 0.f;
    const float* gr = g_s + nn*CT + f*TT;
    for (int s = 0; s < TT; ++s) acc += gr[s]*E_s[s*TT + t];
    g2[(size_t)(b*NN + n0 + nn)*CT + rem] = __float2bfloat16(acc);
  }
}

// ---------------- l1_w fp32 -> bf16
__global__ void k_convW(const float* __restrict__ W, __hip_bfloat16* __restrict__ Wb){
  int i = (blockIdx.x*256 + threadIdx.x)*4;
  float4 v = *(const float4*)(W + i);
  Wb[i+0] = __float2bfloat16(v.x);
  Wb[i+1] = __float2bfloat16(v.y);
  Wb[i+2] = __float2bfloat16(v.z);
  Wb[i+3] = __float2bfloat16(v.w);
}

// ---------------- tlin = A(16384x1536,bf16) @ W^T(bf16) + l1_b
__global__ __launch_bounds__(256) void k_gemm_bf16(const __hip_bfloat16* __restrict__ A,
                      const __hip_bfloat16* __restrict__ W,
                      const float* __restrict__ bias, float* __restrict__ Cout){
  __shared__ __align__(16) short lA[128*32];
  __shared__ __align__(16) short lB[128*32];
  int i0 = blockIdx.y*128, o0 = blockIdx.x*128;
  int tid = threadIdx.x;
  int w = tid >> 6, l = tid & 63;
  int wr = w >> 1, wc = w & 1;
  f32x4 acc[4][4];
  #pragma unroll
  for (int m = 0; m < 4; ++m)
    #pragma unroll
    for (int n = 0; n < 4; ++n) acc[m][n] = (f32x4){0.f,0.f,0.f,0.f};
  int lrow = l & 15, lk = (l >> 4);
  for (int k0 = 0; k0 < CT; k0 += 32){
    #pragma unroll
    for (int p = 0; p < 2; ++p){
      int c = p*4 + w;
      int off = c*512 + l*8;
      int row = off >> 5, col = off & 31;
      __builtin_amdgcn_global_load_lds(
        (const __attribute__((address_space(1))) void*)(A + (size_t)(i0 + row)*CT + k0 + col),
        (__attribute__((address_space(3))) void*)(lA + c*512), 16, 0, 0);
      __builtin_amdgcn_global_load_lds(
        (const __attribute__((address_space(1))) void*)(W + (size_t)(o0 + row)*CT + k0 + col),
        (__attribute__((address_space(3))) void*)(lB + c*512), 16, 0, 0);
    }
    __syncthreads();
    bf16x8 a[4], bv[4];
    #pragma unroll
    for (int m = 0; m < 4; ++m) a[m] = *(const bf16x8*)(lA + (wr*64 + m*16 + lrow)*32 + lk*8);
    #pragma unroll
    for (int n = 0; n < 4; ++n) bv[n] = *(const bf16x8*)(lB + (wc*64 + n*16 + lrow)*32 + lk*8);
    #pragma unroll
    for (int m = 0; m < 4; ++m)
      #pragma unroll
      for (int n = 0; n < 4; ++n)
        acc[m][n] = __builtin_amdgcn_mfma_f32_16x16x32_bf16(a[m], bv[n], acc[m][n], 0, 0, 0);
    __syncthreads();
  }
  #pragma unroll
  for (int m = 0; m < 4; ++m){
    #pragma unroll
    for (int n = 0; n < 4; ++n){
      int o = o0 + wc*64 + n*16 + lrow;
      float bo = bias[o];
      #pragma unroll
      for (int j = 0; j < 4; ++j){
        int i = i0 + wr*64 + m*16 + lk*4 + j;
        Cout[(size_t)i*CT + o] = acc[m][n][j] + bo;
      }
    }
  }
}

// ---------------- reshape + residual + relu + LayerNorm (LDS-staged)
__global__ __launch_bounds__(128) void k_final(const float* __restrict__ tlin, const float* __restrict__ x,
                      const float* __restrict__ res_w, const float* __restrict__ res_b,
                      const float* __restrict__ ln_g, const float* __restrict__ ln_b,
                      float* __restrict__ out){
  __shared__ float Ls[64][132];
  __shared__ float rw_s[64], rb_s[64], lg_s[64], lb_s[64];
  int ot = blockIdx.x, dlt = blockIdx.y, b = blockIdx.z;
  int o0 = ot*128, tid = threadIdx.x;
  if (tid < 64){ rw_s[tid]=res_w[tid]; rb_s[tid]=res_b[tid]; lg_s[tid]=ln_g[tid]; lb_s[tid]=ln_b[tid]; }
  const float* tb = tlin + (size_t)b*NN*CT;
  #pragma unroll 4
  for (int c = 0; c < 64; ++c)
    Ls[c][tid] = tb[(size_t)(c*8 + dlt)*CT + o0 + tid];
  __syncthreads();
  int p = dlt*CT + o0 + tid;
  int np = p / TT, tp = p % TT;
  float xv = x[(size_t)(b*NN + np)*TT + tp];
  float z[CC];
  float sum = 0.f, sq = 0.f;
  #pragma unroll
  for (int c = 0; c < CC; ++c){
    float v = Ls[c][tid] + xv*rw_s[c] + rb_s[c];
    v = fmaxf(v, 0.f);
    z[c] = v; sum += v; sq += v*v;
  }
  float mu = sum*(1.f/64.f);
  float var = sq*(1.f/64.f) - mu*mu;
  float rstd = rsqrtf(var + 1e-5f);
  float* ob = out + (size_t)(b*NN + np)*CC*TT + tp;
  #pragma unroll
  for (int c = 0; c < CC; ++c)
    ob[c*TT] = (z[c] - mu)*rstd*lg_s[c] + lb_s[c];
}

extern "C" void kernel_launch(void* const* d_in, const int* in_sizes, int n_in,
                              void* d_out, int out_size, void* d_ws, size_t ws_size,
                              hipStream_t stream){
  const float* x    = (const float*)d_in[0];
  const float* y    = (const float*)d_in[1];
  const float* tl_w = (const float*)d_in[2];
  const float* tl_b = (const float*)d_in[3];
  const float* u0_w = (const float*)d_in[4];
  const float* u0_b = (const float*)d_in[5];
  const float* u1a  = (const float*)d_in[6];
  const float* u2a  = (const float*)d_in[7];
  const float* u3a  = (const float*)d_in[8];
  const float* be_a = (const float*)d_in[9];
  const float* ve_a = (const float*)d_in[10];
  const float* u1b  = (const float*)d_in[11];
  const float* u2b  = (const float*)d_in[12];
  const float* u3b  = (const float*)d_in[13];
  const float* be_b = (const float*)d_in[14];
  const float* ve_b = (const float*)d_in[15];
  const float* sw1  = (const float*)d_in[16];
  const float* sw2  = (const float*)d_in[17];
  const float* sw3  = (const float*)d_in[18];
  const float* s_bs = (const float*)d_in[19];
  const float* s_vs = (const float*)d_in[20];
  const float* cheb = (const float*)d_in[21];
  const float* theta= (const float*)d_in[22];
  const float* l1_w = (const float*)d_in[23];
  const float* l1_b = (const float*)d_in[24];
  const float* res_w= (const float*)d_in[25];
  const float* res_b= (const float*)d_in[26];
  const float* ln_g = (const float*)d_in[27];
  const float* ln_b = (const float*)d_in[28];
  float* out = (float*)d_out;
  float* ws  = (float*)d_ws;

  // ws layout (floats). Alias lifetimes (serial stream order):
  //  - WB/yB/pdt (dt pipeline) live in `big` BEFORE k_S0 writes ST there.
  //  - Wb (bf16, spans lhs1+rhs1+lhsg): k_convW only after E2 (2nd k_att_post2).
  //  - ST/pw1g/tlin share `big`: ST dead after k_tmp; pw1g dead after k_w1g_red.
  //  - g2b lives in d_out: dead once k_gemm_bf16 consumed it; k_final rewrites d_out.
  float* dt   = ws;               // 49152
  float* E    = dt   + 49152;     // 18432 (E1 then E2)
  float* lxp  = E    + 18432;     // 16384
  float* r2p  = lxp  + 16384;     // 16384
  float* w0u3 = r2p  + 16384;     // 640
  float* b0u3 = w0u3 + 640;       // 64
  float* sums = b0u3 + 64;        // 64
  float* du3a = sums + 64;        // 768
  float* du3b = du3a + 768;       // 768
  float* w1a  = du3b + 768;       // 49152
  float* w1g  = w1a  + 49152;     // 49152
  float* lhs1 = w1g  + 49152;     // 393216
  float* rhs1 = lhs1 + 393216;    // 393216
  float* lhsg = rhs1 + 393216;    // 393216
  float* rhsg = lhsg + 393216;    // 393216
  float* svBf = rhsg + 393216;    // 131072 (bf16 512x512)
  float* ppr  = svBf + 131072;    // 147456
  float* tmp  = ppr  + 147456;    // 1179648
  float* big  = tmp  + 1179648;   // ST: 8388608 / pw1g: 1572864 / tlin: 25165824
  float* ST   = big;
  float* pw1g = big;
  float* tlin = big;
  __hip_bfloat16* WB = (__hip_bfloat16*)big;                 // 1536*3648 bf16
  __hip_bfloat16* yB = (__hip_bfloat16*)(big + 2801664);     // 32*3648 bf16
  float* pdt = big + 2801664 + 58368;                        // 19*32*1536
  __hip_bfloat16* svB = (__hip_bfloat16*)svBf;
  __hip_bfloat16* Wb  = (__hip_bfloat16*)lhs1;   // valid only after E2
  __hip_bfloat16* g2b = (__hip_bfloat16*)d_out;

  k_prep0<<<dim3(1), dim3(576), 0, stream>>>(u0_w, u0_b, u1a, u3a, u1b, w0u3, b0u3, sums);
  k_convS<<<dim3(256), dim3(256), 0, stream>>>(s_vs, svB);
  k_convPad<<<dim3((32*(YP/8) + 255)/256), dim3(256), 0, stream>>>(y, yB, 32);
  k_convPad<<<dim3((1536*(YP/8) + 255)/256), dim3(256), 0, stream>>>(tl_w, WB, 1536);
  k_dtgemm<<<dim3(6, 19), dim3(256), 0, stream>>>(yB, WB, pdt);
  k_dtred<<<dim3(192), dim3(256), 0, stream>>>(pdt, tl_b, dt);
  k_small<<<dim3(32), dim3(256), 0, stream>>>(x, dt, u0_w, u0_b, u1a, u3a, u3b, sums, w1a, du3a, du3b);
  k_rhs1<<<dim3(32, 32), dim3(384), 0, stream>>>(x, w0u3, b0u3, du3a, rhs1);
  k_lhs<<<dim3(48, 32), dim3(256), 0, stream>>>(u2a, w1a, lhs1);
  k_prod<<<dim3(8, 32), dim3(576), 0, stream>>>(lhs1, rhs1, ppr);
  k_att_post2<<<dim3(32), dim3(576), 0, stream>>>(ppr, ve_a, be_a, E);
  k_xtat<<<dim3(64), dim3(256), 0, stream>>>(x, E, sw1, sw2, sw3, lxp, r2p);
  k_S0<<<dim3(4, 4, 32), dim3(256), 0, stream>>>(svB, s_bs, lxp, r2p, ST);
  k_tmp<<<dim3(32, 32), dim3(384), 0, stream>>>(ST, cheb, x, tmp);   // softmax fused
  k_gsum<<<dim3(32, 32), dim3(384), 0, stream>>>(tmp, theta, u1b, u3b, du3b, rhsg, pw1g);
  k_w1g_red<<<dim3(32), dim3(256), 0, stream>>>(pw1g, dt, sums, w1g);
  k_lhs<<<dim3(48, 32), dim3(256), 0, stream>>>(u2b, w1g, lhsg);
  k_prod<<<dim3(8, 32), dim3(576), 0, stream>>>(lhsg, rhsg, ppr);
  k_att_post2<<<dim3(32), dim3(576), 0, stream>>>(ppr, ve_b, be_b, E);
  k_convW<<<dim3(2304), dim3(256), 0, stream>>>(l1_w, Wb);   // after E2: lhs1/rhs1/lhsg dead
  k_g2<<<dim3(128, 32), dim3(256), 0, stream>>>(tmp, E, theta, g2b);
  k_gemm_bf16<<<dim3(12, 128), dim3(256), 0, stream>>>(g2b, Wb, l1_b, tlin);
  k_final<<<dim3(12, 8, 32), dim3(128), 0, stream>>>(tlin, x, res_w, res_b, ln_g, ln_b, out);
}

// Round 8
// 445.496 us; speedup vs baseline: 6.5453x; 1.1682x over previous
//
#include <hip/hip_runtime.h>
#include <hip/hip_bf16.h>
#include <math.h>

#define BB 32
#define NN 512
#define TT 24
#define CC 64
#define CT 1536   // CC*TT
#define YD 3624   // 151*TT
#define YP 3648   // YD padded to 114*32

typedef __attribute__((ext_vector_type(4))) float f32x4;
typedef __attribute__((ext_vector_type(8))) short bf16x8;

static __device__ __forceinline__ short f2bf(float f){
  union { float f; unsigned u; } v; v.f = f;
  unsigned r = (v.u + 0x7FFF + ((v.u >> 16) & 1)) >> 16;
  return (short)r;
}
static __device__ __forceinline__ float bf2f(short s){
  union { unsigned u; float f; } v; v.u = ((unsigned)(unsigned short)s) << 16;
  return v.f;
}

// ---------------- small precompute
__global__ void k_prep0(const float* __restrict__ u0_w, const float* __restrict__ u0_b,
                        const float* __restrict__ u1a, const float* __restrict__ u3a,
                        const float* __restrict__ u1b,
                        float* __restrict__ w0u3, float* __restrict__ b0u3, float* __restrict__ sums){
  int tid = threadIdx.x;
  if (tid < 576){
    int tp = tid / TT, t = tid % TT;
    float acc = 0.f;
    for (int f = 0; f < CC; ++f) acc += u3a[f] * u0_w[(f*TT + tp)*TT + t];
    w0u3[tid] = acc;
  }
  if (tid < TT){
    float acc = 0.f;
    for (int f = 0; f < CC; ++f) acc += u3a[f] * u0_b[f*TT + tid];
    b0u3[tid] = acc;
  }
  if (tid == 0){ float s = 0.f; for (int n = 0; n < NN; ++n) s += u1a[n]; sums[0] = s; }
  if (tid == 1){ float s = 0.f; for (int n = 0; n < NN; ++n) s += u1b[n]; sums[1] = s; }
}

// ---------------- fp32 [rows][3624] -> bf16 [rows][3648] zero-padded
__global__ void k_convPad(const float* __restrict__ src, __hip_bfloat16* __restrict__ dst, int rows){
  int gid = blockIdx.x*256 + threadIdx.x;
  int r = gid / (YP/8), c8 = (gid % (YP/8))*8;
  if (r >= rows) return;
  bf16x8 o;
  if (c8 < YD){
    float4 a = *(const float4*)(src + (size_t)r*YD + c8);
    float4 b = *(const float4*)(src + (size_t)r*YD + c8 + 4);
    o[0]=f2bf(a.x); o[1]=f2bf(a.y); o[2]=f2bf(a.z); o[3]=f2bf(a.w);
    o[4]=f2bf(b.x); o[5]=f2bf(b.y); o[6]=f2bf(b.z); o[7]=f2bf(b.w);
  } else {
    for (int j = 0; j < 8; ++j) o[j] = 0;
  }
  *(bf16x8*)((short*)dst + (size_t)r*YP + c8) = o;
}

// ---------------- pdt[ks][32][1536] = y-slice @ tl_w-slice^T  (MFMA, M=32)
__global__ __launch_bounds__(256) void k_dtgemm(const __hip_bfloat16* __restrict__ yB,
                       const __hip_bfloat16* __restrict__ WB, float* __restrict__ pdt){
  __shared__ __align__(16) short lA[32*32];
  __shared__ __align__(16) short lB[256*32];
  int nt = blockIdx.x, ks = blockIdx.y;
  int o0 = nt*256;
  int tid = threadIdx.x;
  int w = tid >> 6, l = tid & 63;
  int lrow = l & 15, lk = l >> 4;
  f32x4 acc[2][4];
  #pragma unroll
  for (int m = 0; m < 2; ++m)
    #pragma unroll
    for (int n = 0; n < 4; ++n) acc[m][n] = (f32x4){0.f,0.f,0.f,0.f};
  for (int step = 0; step < 6; ++step){
    int k0 = (ks*6 + step)*32;
    #pragma unroll
    for (int p = 0; p < 4; ++p){
      int c = p*4 + w;
      int off = c*512 + l*8;
      int row = off >> 5, col = off & 31;
      __builtin_amdgcn_global_load_lds(
        (const __attribute__((address_space(1))) void*)((const short*)WB + (size_t)(o0 + row)*YP + k0 + col),
        (__attribute__((address_space(3))) void*)(lB + c*512), 16, 0, 0);
    }
    if (w < 2){
      int off = w*512 + l*8;
      int row = off >> 5, col = off & 31;
      __builtin_amdgcn_global_load_lds(
        (const __attribute__((address_space(1))) void*)((const short*)yB + (size_t)row*YP + k0 + col),
        (__attribute__((address_space(3))) void*)(lA + w*512), 16, 0, 0);
    }
    __syncthreads();
    bf16x8 a[2], bv[4];
    #pragma unroll
    for (int m = 0; m < 2; ++m) a[m] = *(const bf16x8*)(lA + (m*16 + lrow)*32 + lk*8);
    #pragma unroll
    for (int n = 0; n < 4; ++n) bv[n] = *(const bf16x8*)(lB + (w*64 + n*16 + lrow)*32 + lk*8);
    #pragma unroll
    for (int m = 0; m < 2; ++m)
      #pragma unroll
      for (int n = 0; n < 4; ++n)
        acc[m][n] = __builtin_amdgcn_mfma_f32_16x16x32_bf16(a[m], bv[n], acc[m][n], 0, 0, 0);
    __syncthreads();
  }
  #pragma unroll
  for (int m = 0; m < 2; ++m){
    #pragma unroll
    for (int n = 0; n < 4; ++n){
      int o = o0 + w*64 + n*16 + lrow;
      #pragma unroll
      for (int j = 0; j < 4; ++j){
        int b = m*16 + lk*4 + j;
        pdt[((size_t)(ks*32 + b))*CT + o] = acc[m][n][j];
      }
    }
  }
}

// ---------------- dt = sum_ks pdt + tl_b
__global__ void k_dtred(const float* __restrict__ pdt, const float* __restrict__ tl_b,
                        float* __restrict__ dt){
  int gid = blockIdx.x*256 + threadIdx.x;
  int b = gid / CT, o = gid % CT;
  float acc = tl_b[o];
  #pragma unroll
  for (int ks = 0; ks < 19; ++ks) acc += pdt[((size_t)(ks*32 + b))*CT + o];
  dt[gid] = acc;
}

// ---------------- per-b small reductions: xu, du3a, du3b, w1a
__global__ void k_small(const float* __restrict__ x, const float* __restrict__ dt,
                        const float* __restrict__ u0_w, const float* __restrict__ u0_b,
                        const float* __restrict__ u1a, const float* __restrict__ u3a,
                        const float* __restrict__ u3b, const float* __restrict__ sums,
                        float* __restrict__ w1a, float* __restrict__ du3a, float* __restrict__ du3b){
  __shared__ float xu_s[TT], u1a_s[NN];
  int b = blockIdx.x, tid = threadIdx.x;
  for (int i = tid; i < NN; i += 256) u1a_s[i] = u1a[i];
  __syncthreads();
  int wv = tid >> 6, ln = tid & 63;
  for (int t = wv; t < TT; t += 4){
    float acc = 0.f;
    for (int n = ln; n < NN; n += 64) acc += u1a_s[n]*x[(size_t)(b*NN + n)*TT + t];
    for (int off = 32; off; off >>= 1) acc += __shfl_down(acc, off);
    if (ln == 0) xu_s[t] = acc;
  }
  if (tid < TT){
    float a = 0.f, c = 0.f;
    for (int f = 0; f < CC; ++f){
      float d = dt[b*CT + tid*CC + f];
      a += u3a[f]*d; c += u3b[f]*d;
    }
    du3a[b*TT + tid] = a;
    du3b[b*TT + tid] = c;
  }
  __syncthreads();
  float S1 = sums[0];
  for (int idx = tid; idx < CC*TT; idx += 256){
    int f = idx / TT, tp = idx % TT;
    float acc = 0.f;
    const float* wrow = u0_w + (f*TT + tp)*TT;
    for (int t = 0; t < TT; ++t) acc += wrow[t]*xu_s[t];
    w1a[b*CC*TT + idx] = acc + S1*(u0_b[f*TT + tp] + dt[b*CT + tp*CC + f]);
  }
}

// ---------------- rhs1[b][n][t'] = b0u3[t'] + du3a[b][t'] + sum_t w0u3[t'][t]*x[b,n,t]
__global__ __launch_bounds__(384) void k_rhs1(const float* __restrict__ x, const float* __restrict__ w0u3,
                      const float* __restrict__ b0u3, const float* __restrict__ du3a,
                      float* __restrict__ rhs1){
  __shared__ float xs[16*TT], w0_s[576], bd_s[TT];
  int b = blockIdx.y, n0 = blockIdx.x*16, tid = threadIdx.x;
  for (int i = tid; i < 576; i += 384) w0_s[i] = w0u3[i];
  if (tid < TT) bd_s[tid] = b0u3[tid] + du3a[b*TT + tid];
  xs[tid] = x[(size_t)(b*NN + n0)*TT + tid];
  __syncthreads();
  int nn = tid / TT, tp = tid % TT;
  float acc = bd_s[tp];
  const float* wr = w0_s + tp*TT;
  const float* xr = xs + nn*TT;
  for (int t = 0; t < TT; ++t) acc += wr[t]*xr[t];
  rhs1[(size_t)b*NN*TT + (n0 + nn)*TT + tp] = acc;
}

// ---------------- lhs[b][t][m] = sum_f u2[f,m]*w1[b][f][t]
__global__ void k_lhs(const float* __restrict__ u2, const float* __restrict__ w1,
                      float* __restrict__ lhs){
  int b = blockIdx.y;
  int j = blockIdx.x*256 + threadIdx.x;
  int t = j >> 9, m = j & 511;
  const float* w = w1 + b*CC*TT;
  float acc = 0.f;
  #pragma unroll 8
  for (int f = 0; f < CC; ++f) acc += u2[f*NN + m]*w[f*TT + t];
  lhs[(size_t)b*TT*NN + j] = acc;
}

// ---------------- partial prod over 64-n slices
__global__ __launch_bounds__(576) void k_prod(const float* __restrict__ lhs, const float* __restrict__ rhs,
                      float* __restrict__ pprod){
  __shared__ float lh[TT][64], rh[64][TT];
  int ns = blockIdx.x, b = blockIdx.y;
  int n0 = ns*64, tid = threadIdx.x;
  for (int i = tid; i < 1536; i += 576){ int t = i >> 6, n = i & 63; lh[t][n] = lhs[(size_t)b*TT*NN + t*NN + n0 + n]; }
  for (int i = tid; i < 1536; i += 576){ ((float*)rh)[i] = rhs[(size_t)b*NN*TT + n0*TT + i]; }
  __syncthreads();
  int t = tid / TT, s = tid % TT;
  float acc = 0.f;
  #pragma unroll 4
  for (int n = 0; n < 64; ++n) acc += lh[t][n]*rh[n][s];
  pprod[((size_t)(b*8 + ns))*576 + tid] = acc;
}

// ---------------- attention tail: sum partials -> sigmoid -> ve -> softmax(axis t)
__global__ void k_att_post2(const float* __restrict__ pprod, const float* __restrict__ ve,
                            const float* __restrict__ be, float* __restrict__ E){
  __shared__ float sig_s[TT*TT], E_s[TT*TT];
  int b = blockIdx.x, tid = threadIdx.x;
  float acc = 0.f;
  #pragma unroll
  for (int p = 0; p < 8; ++p) acc += pprod[((size_t)(b*8 + p))*576 + tid];
  sig_s[tid] = 1.f/(1.f + expf(-(acc + be[tid])));
  __syncthreads();
  {
    int t = tid / TT, r = tid % TT;
    float a = 0.f;
    for (int s = 0; s < TT; ++s) a += ve[t*TT + s]*sig_s[s*TT + r];
    E_s[tid] = a;
  }
  __syncthreads();
  if (tid < TT){
    int r = tid;
    float mx = -1e30f;
    for (int t = 0; t < TT; ++t) mx = fmaxf(mx, E_s[t*TT + r]);
    float sum = 0.f;
    for (int t = 0; t < TT; ++t) sum += expf(E_s[t*TT + r] - mx);
    float inv = 1.f/sum;
    for (int t = 0; t < TT; ++t) E[(size_t)b*TT*TT + t*TT + r] = expf(E_s[t*TT + r] - mx)*inv;
  }
}

// ---------------- lx/r2 for spatial attention
__global__ void k_xtat(const float* __restrict__ x, const float* __restrict__ E1,
                       const float* __restrict__ sw1, const float* __restrict__ sw2,
                       const float* __restrict__ sw3,
                       float* __restrict__ lx, float* __restrict__ r2){
  __shared__ float E_s[TT*TT], sw1_s[TT], sw2_s[TT];
  int b = blockIdx.x >> 1, half = blockIdx.x & 1, tid = threadIdx.x;
  for (int i = tid; i < 576; i += 256) E_s[i] = E1[(size_t)b*576 + i];
  if (tid < TT){ sw1_s[tid] = sw1[tid]; sw2_s[tid] = sw2[tid]; }
  __syncthreads();
  int n = half*256 + tid;
  float xr[TT];
  const float* xp = x + (size_t)(b*NN + n)*TT;
  for (int t = 0; t < TT; ++t) xr[t] = xp[t];
  float l = 0.f, r = 0.f;
  for (int s = 0; s < TT; ++s){
    float acc = 0.f;
    for (int t = 0; t < TT; ++t) acc += xr[t]*E_s[t*TT + s];
    l += acc*sw1_s[s];
    r += acc*sw2_s[s];
  }
  lx[b*NN + n] = l;
  r2[b*NN + n] = r*sw3[0];
}

// ---------------- s_vs fp32 -> bf16
__global__ void k_convS(const float* __restrict__ S, __hip_bfloat16* __restrict__ Sb){
  int i = (blockIdx.x*256 + threadIdx.x)*4;
  float4 v = *(const float4*)(S + i);
  Sb[i+0] = __float2bfloat16(v.x);
  Sb[i+1] = __float2bfloat16(v.y);
  Sb[i+2] = __float2bfloat16(v.z);
  Sb[i+3] = __float2bfloat16(v.w);
}

// ---------------- ST[b][k][n] = sum_m s_vs[n][m]*sigmoid(lx[m]*r2[k]+s_bs[m][k])  (MFMA)
__global__ __launch_bounds__(256) void k_S0(const __hip_bfloat16* __restrict__ svB,
                    const float* __restrict__ s_bs,
                    const float* __restrict__ lx, const float* __restrict__ r2,
                    float* __restrict__ ST){
  __shared__ __align__(16) short lA[128*32];
  __shared__ __align__(16) short lQ[128*32];
  __shared__ float sb_s[32][132];
  __shared__ float lx_s[32];
  int kt = blockIdx.x, nt = blockIdx.y, b = blockIdx.z;
  int n0 = nt*128, k0 = kt*128;
  int tid = threadIdx.x;
  int w = tid >> 6, l = tid & 63;
  int wr = w >> 1, wc = w & 1;
  int lrow = l & 15, lk = l >> 4;
  f32x4 acc[4][4];
  #pragma unroll
  for (int m = 0; m < 4; ++m)
    #pragma unroll
    for (int n = 0; n < 4; ++n) acc[m][n] = (f32x4){0.f,0.f,0.f,0.f};
  const float* lxb = lx + b*NN;
  int kq = tid >> 1;
  float r2q = r2[b*NN + k0 + kq];
  for (int m0 = 0; m0 < NN; m0 += 32){
    if (tid < 32) lx_s[tid] = lxb[m0 + tid];
    #pragma unroll
    for (int p = 0; p < 2; ++p){
      int c = p*4 + w;
      int off = c*512 + l*8;
      int row = off >> 5, col = off & 31;
      __builtin_amdgcn_global_load_lds(
        (const __attribute__((address_space(1))) void*)(svB + (size_t)(n0 + row)*NN + m0 + col),
        (__attribute__((address_space(3))) void*)(lA + c*512), 16, 0, 0);
    }
    #pragma unroll
    for (int q = 0; q < 4; ++q){
      int idx = tid + q*256;
      int mm = idx >> 5, k4 = idx & 31;
      float4 v = *(const float4*)(s_bs + (size_t)(mm)*NN + (size_t)m0*NN + k0 + k4*4);
      *(float4*)(&sb_s[mm][k4*4]) = v;
    }
    __syncthreads();
    #pragma unroll
    for (int c2 = 0; c2 < 2; ++c2){
      int mc = (tid & 1)*2 + c2;
      bf16x8 pk;
      #pragma unroll
      for (int j = 0; j < 8; ++j){
        int m = mc*8 + j;
        float v = lx_s[m]*r2q + sb_s[m][kq];
        float sg = 1.f/(1.f + __expf(-v));
        pk[j] = f2bf(sg);
      }
      *(bf16x8*)(lQ + kq*32 + mc*8) = pk;
    }
    __syncthreads();
    bf16x8 a[4], bv[4];
    #pragma unroll
    for (int m = 0; m < 4; ++m) a[m] = *(const bf16x8*)(lA + (wr*64 + m*16 + lrow)*32 + lk*8);
    #pragma unroll
    for (int n = 0; n < 4; ++n) bv[n] = *(const bf16x8*)(lQ + (wc*64 + n*16 + lrow)*32 + lk*8);
    #pragma unroll
    for (int m = 0; m < 4; ++m)
      #pragma unroll
      for (int n = 0; n < 4; ++n)
        acc[m][n] = __builtin_amdgcn_mfma_f32_16x16x32_bf16(a[m], bv[n], acc[m][n], 0, 0, 0);
    __syncthreads();
  }
  #pragma unroll
  for (int m = 0; m < 4; ++m){
    #pragma unroll
    for (int n = 0; n < 4; ++n){
      int col = k0 + wc*64 + n*16 + lrow;
      int row = n0 + wr*64 + m*16 + lk*4;
      float4 v; v.x = acc[m][n][0]; v.y = acc[m][n][1]; v.z = acc[m][n][2]; v.w = acc[m][n][3];
      *(float4*)(ST + (size_t)b*NN*NN + (size_t)col*NN + row) = v;
    }
  }
}

// ---------------- cheb[k][j][i] -> chebT[k][i][j] bf16
__global__ __launch_bounds__(256) void k_chebT(const float* __restrict__ cheb, short* __restrict__ chebT){
  __shared__ float ts[32][33];
  int jt = blockIdx.x, it = blockIdx.y, k = blockIdx.z;
  int tid = threadIdx.x;
  int c = tid & 31, r8 = tid >> 5;
  #pragma unroll
  for (int p = 0; p < 4; ++p){
    int r = p*8 + r8;
    ts[r][c] = cheb[((size_t)k*NN + jt*32 + r)*NN + it*32 + c];
  }
  __syncthreads();
  #pragma unroll
  for (int p = 0; p < 4; ++p){
    int r = p*8 + r8;   // i-row
    chebT[((size_t)k*NN + it*32 + r)*NN + jt*32 + c] = f2bf(ts[c][r]);
  }
}

// ---------------- xT[b][t][j] = bf16(x[b][j][t]), rows t=24..31 zero
__global__ __launch_bounds__(256) void k_xT(const float* __restrict__ x, short* __restrict__ xT){
  __shared__ float xs[512*25];
  int b = blockIdx.x, tid = threadIdx.x;
  for (int idx = tid; idx < NN*TT; idx += 256){
    int j = idx / TT, t = idx % TT;
    xs[j*25 + t] = x[(size_t)b*NN*TT + idx];
  }
  __syncthreads();
  for (int u = tid; u < 32*64; u += 256){
    int t = u >> 6, j8 = (u & 63)*8;
    bf16x8 o;
    if (t < TT){
      #pragma unroll
      for (int e = 0; e < 8; ++e) o[e] = f2bf(xs[(j8 + e)*25 + t]);
    } else {
      #pragma unroll
      for (int e = 0; e < 8; ++e) o[e] = 0;
    }
    *(bf16x8*)(xT + ((size_t)b*32 + t)*NN + j8) = o;
  }
}

// ---------------- row softmax of ST -> P bf16 (unnormalized exp) + invZ
__global__ __launch_bounds__(256) void k_expS(const float* __restrict__ ST, short* __restrict__ P,
                      float* __restrict__ invZ){
  int b = blockIdx.y;
  int row = blockIdx.x*4 + (threadIdx.x >> 6);
  int l = threadIdx.x & 63;
  const float* R = ST + (size_t)b*NN*NN + (size_t)row*NN;
  float4 v0 = *(const float4*)(R + l*8);
  float4 v1 = *(const float4*)(R + l*8 + 4);
  float mx = fmaxf(fmaxf(fmaxf(v0.x,v0.y),fmaxf(v0.z,v0.w)),
                   fmaxf(fmaxf(v1.x,v1.y),fmaxf(v1.z,v1.w)));
  for (int off = 32; off; off >>= 1) mx = fmaxf(mx, __shfl_xor(mx, off));
  v0.x = __expf(v0.x-mx); v0.y = __expf(v0.y-mx); v0.z = __expf(v0.z-mx); v0.w = __expf(v0.w-mx);
  v1.x = __expf(v1.x-mx); v1.y = __expf(v1.y-mx); v1.z = __expf(v1.z-mx); v1.w = __expf(v1.w-mx);
  float s = v0.x+v0.y+v0.z+v0.w+v1.x+v1.y+v1.z+v1.w;
  for (int off = 32; off; off >>= 1) s += __shfl_xor(s, off);
  bf16x8 o;
  o[0]=f2bf(v0.x); o[1]=f2bf(v0.y); o[2]=f2bf(v0.z); o[3]=f2bf(v0.w);
  o[4]=f2bf(v1.x); o[5]=f2bf(v1.y); o[6]=f2bf(v1.z); o[7]=f2bf(v1.w);
  *(bf16x8*)(P + ((size_t)b*NN + row)*NN + l*8) = o;
  if (l == 0) invZ[b*NN + row] = 1.f/s;
}

// ---------------- tmp_kc[b] = (P[b] .* chebT[kc]) @ xT[b]^T, scaled by invZ  (MFMA)
__global__ __launch_bounds__(256) void k_tmpG(const short* __restrict__ P, const short* __restrict__ chebT,
                      const short* __restrict__ xT, const float* __restrict__ invZ,
                      float* __restrict__ tmp){
  __shared__ __align__(16) short lP[128*32];
  __shared__ __align__(16) short lC[128*32];
  __shared__ __align__(16) short lX[32*32];
  __shared__ float iz_s[128];
  int it = blockIdx.x, kc = blockIdx.y, b = blockIdx.z;
  int i0 = it*128;
  int tid = threadIdx.x;
  int w = tid >> 6, l = tid & 63;
  int lrow = l & 15, lk = l >> 4;
  if (tid < 128) iz_s[tid] = invZ[b*NN + i0 + tid];
  f32x4 acc[2][2];
  #pragma unroll
  for (int m = 0; m < 2; ++m)
    #pragma unroll
    for (int n = 0; n < 2; ++n) acc[m][n] = (f32x4){0.f,0.f,0.f,0.f};
  for (int ks = 0; ks < 16; ++ks){
    int k0 = ks*32;
    #pragma unroll
    for (int p = 0; p < 2; ++p){
      int c = p*4 + w;
      int off = c*512 + l*8;
      int row = off >> 5, col = off & 31;
      __builtin_amdgcn_global_load_lds(
        (const __attribute__((address_space(1))) void*)(P + ((size_t)b*NN + i0 + row)*NN + k0 + col),
        (__attribute__((address_space(3))) void*)(lP + c*512), 16, 0, 0);
      __builtin_amdgcn_global_load_lds(
        (const __attribute__((address_space(1))) void*)(chebT + ((size_t)kc*NN + i0 + row)*NN + k0 + col),
        (__attribute__((address_space(3))) void*)(lC + c*512), 16, 0, 0);
    }
    if (w < 2){
      int off = w*512 + l*8;
      int row = off >> 5, col = off & 31;
      __builtin_amdgcn_global_load_lds(
        (const __attribute__((address_space(1))) void*)(xT + ((size_t)b*32 + row)*NN + k0 + col),
        (__attribute__((address_space(3))) void*)(lX + w*512), 16, 0, 0);
    }
    __syncthreads();
    bf16x8 a[2], bv[2];
    #pragma unroll
    for (int m = 0; m < 2; ++m){
      int r = w*32 + m*16 + lrow;
      bf16x8 pp = *(const bf16x8*)(lP + r*32 + lk*8);
      bf16x8 cc = *(const bf16x8*)(lC + r*32 + lk*8);
      bf16x8 af;
      #pragma unroll
      for (int e = 0; e < 8; ++e) af[e] = f2bf(bf2f(pp[e])*bf2f(cc[e]));
      a[m] = af;
    }
    #pragma unroll
    for (int n = 0; n < 2; ++n) bv[n] = *(const bf16x8*)(lX + (n*16 + lrow)*32 + lk*8);
    #pragma unroll
    for (int m = 0; m < 2; ++m)
      #pragma unroll
      for (int n = 0; n < 2; ++n)
        acc[m][n] = __builtin_amdgcn_mfma_f32_16x16x32_bf16(a[m], bv[n], acc[m][n], 0, 0, 0);
    __syncthreads();
  }
  // C/D: col(t) = n*16 + (lane&15), row(i) = i0 + w*32 + m*16 + (lane>>4)*4 + reg
  #pragma unroll
  for (int m = 0; m < 2; ++m){
    #pragma unroll
    for (int n = 0; n < 2; ++n){
      int t = n*16 + lrow;
      if (t < TT){
        #pragma unroll
        for (int j = 0; j < 4; ++j){
          int ir = w*32 + m*16 + lk*4 + j;
          tmp[((size_t)(kc*BB + b)*NN + i0 + ir)*TT + t] = acc[m][n][j]*iz_s[ir];
        }
      }
    }
  }
}

// ---------------- att2: per-16-n-tile two-pass: rhsg + partial w1g
__global__ __launch_bounds__(384) void k_gsum(const float* __restrict__ tmp, const float* __restrict__ theta,
                      const float* __restrict__ u1b, const float* __restrict__ u3b,
                      const float* __restrict__ du3b,
                      float* __restrict__ rhsg, float* __restrict__ pw1g){
  __shared__ float A0[16*TT], A1[16*TT], A2[16*TT], th_s[192], u3_s[CC], u1_s[16], du_s[TT];
  int nt = blockIdx.x, b = blockIdx.y;
  int n0 = nt*16, tid = threadIdx.x;
  for (int i = tid; i < 192; i += 384) th_s[i] = theta[i];
  if (tid < CC) u3_s[tid] = u3b[tid];
  if (tid < 16) u1_s[tid] = u1b[n0 + tid];
  if (tid < TT) du_s[tid] = du3b[b*TT + tid];
  A0[tid] = tmp[((size_t)(0*BB + b)*NN + n0)*TT + tid];
  A1[tid] = tmp[((size_t)(1*BB + b)*NN + n0)*TT + tid];
  A2[tid] = tmp[((size_t)(2*BB + b)*NN + n0)*TT + tid];
  __syncthreads();
  {
    int nn = tid / TT, t = tid % TT;
    float a0 = A0[nn*TT + t], a1 = A1[nn*TT + t], a2 = A2[nn*TT + t];
    float acc = du_s[t];
    #pragma unroll 8
    for (int f = 0; f < CC; ++f){
      float v = th_s[f]*a0 + th_s[64 + f]*a1 + th_s[128 + f]*a2;
      acc += u3_s[f]*fmaxf(v, 0.f);
    }
    rhsg[(size_t)b*NN*TT + (n0 + nn)*TT + t] = acc;
  }
  #pragma unroll
  for (int p = 0; p < 4; ++p){
    int o = tid + p*384;
    int f = o / TT, t = o % TT;
    float t0 = th_s[f], t1 = th_s[64 + f], t2 = th_s[128 + f];
    float acc = 0.f;
    #pragma unroll
    for (int m = 0; m < 16; ++m){
      float v = t0*A0[m*TT + t] + t1*A1[m*TT + t] + t2*A2[m*TT + t];
      acc += u1_s[m]*fmaxf(v, 0.f);
    }
    pw1g[((size_t)(b*32 + nt))*CC*TT + o] = acc;
  }
}

// ---------------- reduce partial w1g + S2*dt
__global__ void k_w1g_red(const float* __restrict__ pw1g, const float* __restrict__ dt,
                          const float* __restrict__ sums, float* __restrict__ w1g){
  int b = blockIdx.x, tid = threadIdx.x;
  float S2 = sums[1];
  for (int o = tid; o < CC*TT; o += 256){
    int f = o / TT, t = o % TT;
    float acc = 0.f;
    for (int nt = 0; nt < 32; ++nt) acc += pw1g[((size_t)(b*32 + nt))*CC*TT + o];
    w1g[b*CC*TT + o] = acc + S2*dt[b*CT + t*CC + f];
  }
}

// ---------------- g2 (bf16) = relu(theta·tmp) @ E2
__global__ void k_g2(const float* __restrict__ tmp, const float* __restrict__ E2,
                     const float* __restrict__ theta, __hip_bfloat16* __restrict__ g2){
  __shared__ float E_s[TT*TT], th_s[192], tr[3*4*TT], g_s[4*CT];
  int b = blockIdx.y, n0 = blockIdx.x*4, tid = threadIdx.x;
  for (int i = tid; i < 576; i += 256) E_s[i] = E2[(size_t)b*576 + i];
  for (int i = tid; i < 192; i += 256) th_s[i] = theta[i];
  for (int i = tid; i < 288; i += 256){
    int k = i / 96, rem = i % 96, nn = rem / TT, s = rem % TT;
    tr[i] = tmp[((size_t)(k*BB + b)*NN + n0 + nn)*TT + s];
  }
  __syncthreads();
  for (int idx = tid; idx < 4*CT; idx += 256){
    int nn = idx / CT, rem = idx % CT, f = rem / TT, s = rem % TT;
    float v = th_s[f]*tr[nn*TT + s] + th_s[64 + f]*tr[96 + nn*TT + s] + th_s[128 + f]*tr[192 + nn*TT + s];
    g_s[idx] = fmaxf(v, 0.f);
  }
  __syncthreads();
  for (int idx = tid; idx < 4*CT; idx += 256){
    int nn = idx / CT, rem = idx % CT, f = rem / TT, t = rem % TT;
    float acc = 0.f;
    const float* gr = g_s + nn*CT + f*TT;
    for (int s = 0; s < TT; ++s) acc += gr[s]*E_s[s*TT + t];
    g2[(size_t)(b*NN + n0 + nn)*CT + rem] = __float2bfloat16(acc);
  }
}

// ---------------- l1_w fp32 -> bf16
__global__ void k_convW(const float* __restrict__ W, __hip_bfloat16* __restrict__ Wb){
  int i = (blockIdx.x*256 + threadIdx.x)*4;
  float4 v = *(const float4*)(W + i);
  Wb[i+0] = __float2bfloat16(v.x);
  Wb[i+1] = __float2bfloat16(v.y);
  Wb[i+2] = __float2bfloat16(v.z);
  Wb[i+3] = __float2bfloat16(v.w);
}

// ---------------- tlin = A(16384x1536,bf16) @ W^T(bf16) + l1_b
__global__ __launch_bounds__(256) void k_gemm_bf16(const __hip_bfloat16* __restrict__ A,
                      const __hip_bfloat16* __restrict__ W,
                      const float* __restrict__ bias, float* __restrict__ Cout){
  __shared__ __align__(16) short lA[128*32];
  __shared__ __align__(16) short lB[128*32];
  int i0 = blockIdx.y*128, o0 = blockIdx.x*128;
  int tid = threadIdx.x;
  int w = tid >> 6, l = tid & 63;
  int wr = w >> 1, wc = w & 1;
  f32x4 acc[4][4];
  #pragma unroll
  for (int m = 0; m < 4; ++m)
    #pragma unroll
    for (int n = 0; n < 4; ++n) acc[m][n] = (f32x4){0.f,0.f,0.f,0.f};
  int lrow = l & 15, lk = (l >> 4);
  for (int k0 = 0; k0 < CT; k0 += 32){
    #pragma unroll
    for (int p = 0; p < 2; ++p){
      int c = p*4 + w;
      int off = c*512 + l*8;
      int row = off >> 5, col = off & 31;
      __builtin_amdgcn_global_load_lds(
        (const __attribute__((address_space(1))) void*)(A + (size_t)(i0 + row)*CT + k0 + col),
        (__attribute__((address_space(3))) void*)(lA + c*512), 16, 0, 0);
      __builtin_amdgcn_global_load_lds(
        (const __attribute__((address_space(1))) void*)(W + (size_t)(o0 + row)*CT + k0 + col),
        (__attribute__((address_space(3))) void*)(lB + c*512), 16, 0, 0);
    }
    __syncthreads();
    bf16x8 a[4], bv[4];
    #pragma unroll
    for (int m = 0; m < 4; ++m) a[m] = *(const bf16x8*)(lA + (wr*64 + m*16 + lrow)*32 + lk*8);
    #pragma unroll
    for (int n = 0; n < 4; ++n) bv[n] = *(const bf16x8*)(lB + (wc*64 + n*16 + lrow)*32 + lk*8);
    #pragma unroll
    for (int m = 0; m < 4; ++m)
      #pragma unroll
      for (int n = 0; n < 4; ++n)
        acc[m][n] = __builtin_amdgcn_mfma_f32_16x16x32_bf16(a[m], bv[n], acc[m][n], 0, 0, 0);
    __syncthreads();
  }
  #pragma unroll
  for (int m = 0; m < 4; ++m){
    #pragma unroll
    for (int n = 0; n < 4; ++n){
      int o = o0 + wc*64 + n*16 + lrow;
      float bo = bias[o];
      #pragma unroll
      for (int j = 0; j < 4; ++j){
        int i = i0 + wr*64 + m*16 + lk*4 + j;
        Cout[(size_t)i*CT + o] = acc[m][n][j] + bo;
      }
    }
  }
}

// ---------------- reshape + residual + relu + LayerNorm (LDS-staged)
__global__ __launch_bounds__(128) void k_final(const float* __restrict__ tlin, const float* __restrict__ x,
                      const float* __restrict__ res_w, const float* __restrict__ res_b,
                      const float* __restrict__ ln_g, const float* __restrict__ ln_b,
                      float* __restrict__ out){
  __shared__ float Ls[64][132];
  __shared__ float rw_s[64], rb_s[64], lg_s[64], lb_s[64];
  int ot = blockIdx.x, dlt = blockIdx.y, b = blockIdx.z;
  int o0 = ot*128, tid = threadIdx.x;
  if (tid < 64){ rw_s[tid]=res_w[tid]; rb_s[tid]=res_b[tid]; lg_s[tid]=ln_g[tid]; lb_s[tid]=ln_b[tid]; }
  const float* tb = tlin + (size_t)b*NN*CT;
  #pragma unroll 4
  for (int c = 0; c < 64; ++c)
    Ls[c][tid] = tb[(size_t)(c*8 + dlt)*CT + o0 + tid];
  __syncthreads();
  int p = dlt*CT + o0 + tid;
  int np = p / TT, tp = p % TT;
  float xv = x[(size_t)(b*NN + np)*TT + tp];
  float z[CC];
  float sum = 0.f, sq = 0.f;
  #pragma unroll
  for (int c = 0; c < CC; ++c){
    float v = Ls[c][tid] + xv*rw_s[c] + rb_s[c];
    v = fmaxf(v, 0.f);
    z[c] = v; sum += v; sq += v*v;
  }
  float mu = sum*(1.f/64.f);
  float var = sq*(1.f/64.f) - mu*mu;
  float rstd = rsqrtf(var + 1e-5f);
  float* ob = out + (size_t)(b*NN + np)*CC*TT + tp;
  #pragma unroll
  for (int c = 0; c < CC; ++c)
    ob[c*TT] = (z[c] - mu)*rstd*lg_s[c] + lb_s[c];
}

extern "C" void kernel_launch(void* const* d_in, const int* in_sizes, int n_in,
                              void* d_out, int out_size, void* d_ws, size_t ws_size,
                              hipStream_t stream){
  const float* x    = (const float*)d_in[0];
  const float* y    = (const float*)d_in[1];
  const float* tl_w = (const float*)d_in[2];
  const float* tl_b = (const float*)d_in[3];
  const float* u0_w = (const float*)d_in[4];
  const float* u0_b = (const float*)d_in[5];
  const float* u1a  = (const float*)d_in[6];
  const float* u2a  = (const float*)d_in[7];
  const float* u3a  = (const float*)d_in[8];
  const float* be_a = (const float*)d_in[9];
  const float* ve_a = (const float*)d_in[10];
  const float* u1b  = (const float*)d_in[11];
  const float* u2b  = (const float*)d_in[12];
  const float* u3b  = (const float*)d_in[13];
  const float* be_b = (const float*)d_in[14];
  const float* ve_b = (const float*)d_in[15];
  const float* sw1  = (const float*)d_in[16];
  const float* sw2  = (const float*)d_in[17];
  const float* sw3  = (const float*)d_in[18];
  const float* s_bs = (const float*)d_in[19];
  const float* s_vs = (const float*)d_in[20];
  const float* cheb = (const float*)d_in[21];
  const float* theta= (const float*)d_in[22];
  const float* l1_w = (const float*)d_in[23];
  const float* l1_b = (const float*)d_in[24];
  const float* res_w= (const float*)d_in[25];
  const float* res_b= (const float*)d_in[26];
  const float* ln_g = (const float*)d_in[27];
  const float* ln_b = (const float*)d_in[28];
  float* out = (float*)d_out;
  float* ws  = (float*)d_ws;

  // ws layout (floats). Alias lifetimes (serial stream order):
  //  - WB/yB/pdt (dt pipeline): big[0..3.79M), dead after k_dtred (before k_S0 writes ST).
  //  - ST: big[0..8388608). Pb/xTb/iZ/chT: big[8388608..13254656) — written by
  //    k_expS/k_xT/k_chebT, consumed by k_tmpG, all dead before k_gemm writes tlin.
  //  - Wb (bf16, spans lhs1+rhs1+lhsg): k_convW only after E2 (2nd k_att_post2).
  //  - pw1g/tlin share big with the above per schedule; g2b lives in d_out.
  float* dt   = ws;               // 49152
  float* E    = dt   + 49152;     // 18432 (E1 then E2)
  float* lxp  = E    + 18432;     // 16384
  float* r2p  = lxp  + 16384;     // 16384
  float* w0u3 = r2p  + 16384;     // 640
  float* b0u3 = w0u3 + 640;       // 64
  float* sums = b0u3 + 64;        // 64
  float* du3a = sums + 64;        // 768
  float* du3b = du3a + 768;       // 768
  float* w1a  = du3b + 768;       // 49152
  float* w1g  = w1a  + 49152;     // 49152
  float* lhs1 = w1g  + 49152;     // 393216
  float* rhs1 = lhs1 + 393216;    // 393216
  float* lhsg = rhs1 + 393216;    // 393216
  float* rhsg = lhsg + 393216;    // 393216
  float* svBf = rhsg + 393216;    // 131072 (bf16 512x512)
  float* ppr  = svBf + 131072;    // 147456
  float* tmp  = ppr  + 147456;    // 1179648
  float* big  = tmp  + 1179648;   // 25165824 floats
  float* ST   = big;              // 8388608
  float* pw1g = big;
  float* tlin = big;
  __hip_bfloat16* WB = (__hip_bfloat16*)big;                 // dt pipeline (early)
  __hip_bfloat16* yB = (__hip_bfloat16*)(big + 2801664);
  float* pdt = big + 2801664 + 58368;
  short* Pb  = (short*)(big + 8388608);                      // 8388608 shorts
  short* xTb = (short*)(big + 8388608 + 4194304);            // 524288 shorts
  float* iZ  = big + 8388608 + 4194304 + 262144;             // 16384 floats
  short* chT = (short*)(big + 8388608 + 4194304 + 262144 + 16384);  // 786432 shorts
  __hip_bfloat16* svB = (__hip_bfloat16*)svBf;
  __hip_bfloat16* Wb  = (__hip_bfloat16*)lhs1;   // valid only after E2
  __hip_bfloat16* g2b = (__hip_bfloat16*)d_out;

  k_prep0<<<dim3(1), dim3(576), 0, stream>>>(u0_w, u0_b, u1a, u3a, u1b, w0u3, b0u3, sums);
  k_convS<<<dim3(256), dim3(256), 0, stream>>>(s_vs, svB);
  k_convPad<<<dim3((32*(YP/8) + 255)/256), dim3(256), 0, stream>>>(y, yB, 32);
  k_convPad<<<dim3((1536*(YP/8) + 255)/256), dim3(256), 0, stream>>>(tl_w, WB, 1536);
  k_dtgemm<<<dim3(6, 19), dim3(256), 0, stream>>>(yB, WB, pdt);
  k_dtred<<<dim3(192), dim3(256), 0, stream>>>(pdt, tl_b, dt);
  k_chebT<<<dim3(16, 16, 3), dim3(256), 0, stream>>>(cheb, chT);
  k_xT<<<dim3(32), dim3(256), 0, stream>>>(x, xTb);
  k_small<<<dim3(32), dim3(256), 0, stream>>>(x, dt, u0_w, u0_b, u1a, u3a, u3b, sums, w1a, du3a, du3b);
  k_rhs1<<<dim3(32, 32), dim3(384), 0, stream>>>(x, w0u3, b0u3, du3a, rhs1);
  k_lhs<<<dim3(48, 32), dim3(256), 0, stream>>>(u2a, w1a, lhs1);
  k_prod<<<dim3(8, 32), dim3(576), 0, stream>>>(lhs1, rhs1, ppr);
  k_att_post2<<<dim3(32), dim3(576), 0, stream>>>(ppr, ve_a, be_a, E);
  k_xtat<<<dim3(64), dim3(256), 0, stream>>>(x, E, sw1, sw2, sw3, lxp, r2p);
  k_S0<<<dim3(4, 4, 32), dim3(256), 0, stream>>>(svB, s_bs, lxp, r2p, ST);
  k_expS<<<dim3(128, 32), dim3(256), 0, stream>>>(ST, Pb, iZ);
  k_tmpG<<<dim3(4, 3, 32), dim3(256), 0, stream>>>(Pb, chT, xTb, iZ, tmp);
  k_gsum<<<dim3(32, 32), dim3(384), 0, stream>>>(tmp, theta, u1b, u3b, du3b, rhsg, pw1g);
  k_w1g_red<<<dim3(32), dim3(256), 0, stream>>>(pw1g, dt, sums, w1g);
  k_lhs<<<dim3(48, 32), dim3(256), 0, stream>>>(u2b, w1g, lhsg);
  k_prod<<<dim3(8, 32), dim3(576), 0, stream>>>(lhsg, rhsg, ppr);
  k_att_post2<<<dim3(32), dim3(576), 0, stream>>>(ppr, ve_b, be_b, E);
  k_convW<<<dim3(2304), dim3(256), 0, stream>>>(l1_w, Wb);   // after E2: lhs1/rhs1/lhsg dead
  k_g2<<<dim3(128, 32), dim3(256), 0, stream>>>(tmp, E, theta, g2b);
  k_gemm_bf16<<<dim3(12, 128), dim3(256), 0, stream>>>(g2b, Wb, l1_b, tlin);
  k_final<<<dim3(12, 8, 32), dim3(128), 0, stream>>>(tlin, x, res_w, res_b, ln_g, ln_b, out);
}

// Round 9
// 424.664 us; speedup vs baseline: 6.8664x; 1.0491x over previous
//
#include <hip/hip_runtime.h>
#include <hip/hip_bf16.h>
#include <math.h>

#define BB 32
#define NN 512
#define TT 24
#define CC 64
#define CT 1536   // CC*TT
#define YD 3624   // 151*TT
#define YP 3648   // YD padded to 114*32

typedef __attribute__((ext_vector_type(4))) float f32x4;
typedef __attribute__((ext_vector_type(8))) short bf16x8;

static __device__ __forceinline__ short f2bf(float f){
  union { float f; unsigned u; } v; v.f = f;
  unsigned r = (v.u + 0x7FFF + ((v.u >> 16) & 1)) >> 16;
  return (short)r;
}
static __device__ __forceinline__ float bf2f(short s){
  union { unsigned u; float f; } v; v.u = ((unsigned)(unsigned short)s) << 16;
  return v.f;
}

// ---------------- small precompute
__global__ void k_prep0(const float* __restrict__ u0_w, const float* __restrict__ u0_b,
                        const float* __restrict__ u1a, const float* __restrict__ u3a,
                        const float* __restrict__ u1b,
                        float* __restrict__ w0u3, float* __restrict__ b0u3, float* __restrict__ sums){
  int tid = threadIdx.x;
  if (tid < 576){
    int tp = tid / TT, t = tid % TT;
    float acc = 0.f;
    for (int f = 0; f < CC; ++f) acc += u3a[f] * u0_w[(f*TT + tp)*TT + t];
    w0u3[tid] = acc;
  }
  if (tid < TT){
    float acc = 0.f;
    for (int f = 0; f < CC; ++f) acc += u3a[f] * u0_b[f*TT + tid];
    b0u3[tid] = acc;
  }
  if (tid == 0){ float s = 0.f; for (int n = 0; n < NN; ++n) s += u1a[n]; sums[0] = s; }
  if (tid == 1){ float s = 0.f; for (int n = 0; n < NN; ++n) s += u1b[n]; sums[1] = s; }
}

// ---------------- fp32 [rows][3624] -> bf16 [rows][3648] zero-padded
__global__ void k_convPad(const float* __restrict__ src, __hip_bfloat16* __restrict__ dst, int rows){
  int gid = blockIdx.x*256 + threadIdx.x;
  int r = gid / (YP/8), c8 = (gid % (YP/8))*8;
  if (r >= rows) return;
  bf16x8 o;
  if (c8 < YD){
    float4 a = *(const float4*)(src + (size_t)r*YD + c8);
    float4 b = *(const float4*)(src + (size_t)r*YD + c8 + 4);
    o[0]=f2bf(a.x); o[1]=f2bf(a.y); o[2]=f2bf(a.z); o[3]=f2bf(a.w);
    o[4]=f2bf(b.x); o[5]=f2bf(b.y); o[6]=f2bf(b.z); o[7]=f2bf(b.w);
  } else {
    for (int j = 0; j < 8; ++j) o[j] = 0;
  }
  *(bf16x8*)((short*)dst + (size_t)r*YP + c8) = o;
}

// ---------------- pdt[ks][32][1536] = y-slice @ tl_w-slice^T  (MFMA, M=32)
__global__ __launch_bounds__(256) void k_dtgemm(const __hip_bfloat16* __restrict__ yB,
                       const __hip_bfloat16* __restrict__ WB, float* __restrict__ pdt){
  __shared__ __align__(16) short lA[32*32];
  __shared__ __align__(16) short lB[256*32];
  int nt = blockIdx.x, ks = blockIdx.y;
  int o0 = nt*256;
  int tid = threadIdx.x;
  int w = tid >> 6, l = tid & 63;
  int lrow = l & 15, lk = l >> 4;
  f32x4 acc[2][4];
  #pragma unroll
  for (int m = 0; m < 2; ++m)
    #pragma unroll
    for (int n = 0; n < 4; ++n) acc[m][n] = (f32x4){0.f,0.f,0.f,0.f};
  for (int step = 0; step < 6; ++step){
    int k0 = (ks*6 + step)*32;
    #pragma unroll
    for (int p = 0; p < 4; ++p){
      int c = p*4 + w;
      int off = c*512 + l*8;
      int row = off >> 5, col = off & 31;
      __builtin_amdgcn_global_load_lds(
        (const __attribute__((address_space(1))) void*)((const short*)WB + (size_t)(o0 + row)*YP + k0 + col),
        (__attribute__((address_space(3))) void*)(lB + c*512), 16, 0, 0);
    }
    if (w < 2){
      int off = w*512 + l*8;
      int row = off >> 5, col = off & 31;
      __builtin_amdgcn_global_load_lds(
        (const __attribute__((address_space(1))) void*)((const short*)yB + (size_t)row*YP + k0 + col),
        (__attribute__((address_space(3))) void*)(lA + w*512), 16, 0, 0);
    }
    __syncthreads();
    bf16x8 a[2], bv[4];
    #pragma unroll
    for (int m = 0; m < 2; ++m) a[m] = *(const bf16x8*)(lA + (m*16 + lrow)*32 + lk*8);
    #pragma unroll
    for (int n = 0; n < 4; ++n) bv[n] = *(const bf16x8*)(lB + (w*64 + n*16 + lrow)*32 + lk*8);
    #pragma unroll
    for (int m = 0; m < 2; ++m)
      #pragma unroll
      for (int n = 0; n < 4; ++n)
        acc[m][n] = __builtin_amdgcn_mfma_f32_16x16x32_bf16(a[m], bv[n], acc[m][n], 0, 0, 0);
    __syncthreads();
  }
  #pragma unroll
  for (int m = 0; m < 2; ++m){
    #pragma unroll
    for (int n = 0; n < 4; ++n){
      int o = o0 + w*64 + n*16 + lrow;
      #pragma unroll
      for (int j = 0; j < 4; ++j){
        int b = m*16 + lk*4 + j;
        pdt[((size_t)(ks*32 + b))*CT + o] = acc[m][n][j];
      }
    }
  }
}

// ---------------- dt = sum_ks pdt + tl_b
__global__ void k_dtred(const float* __restrict__ pdt, const float* __restrict__ tl_b,
                        float* __restrict__ dt){
  int gid = blockIdx.x*256 + threadIdx.x;
  int b = gid / CT, o = gid % CT;
  float acc = tl_b[o];
  #pragma unroll
  for (int ks = 0; ks < 19; ++ks) acc += pdt[((size_t)(ks*32 + b))*CT + o];
  dt[gid] = acc;
}

// ---------------- per-b small reductions: xu, du3a, du3b, w1a
__global__ void k_small(const float* __restrict__ x, const float* __restrict__ dt,
                        const float* __restrict__ u0_w, const float* __restrict__ u0_b,
                        const float* __restrict__ u1a, const float* __restrict__ u3a,
                        const float* __restrict__ u3b, const float* __restrict__ sums,
                        float* __restrict__ w1a, float* __restrict__ du3a, float* __restrict__ du3b){
  __shared__ float xu_s[TT], u1a_s[NN];
  int b = blockIdx.x, tid = threadIdx.x;
  for (int i = tid; i < NN; i += 256) u1a_s[i] = u1a[i];
  __syncthreads();
  int wv = tid >> 6, ln = tid & 63;
  for (int t = wv; t < TT; t += 4){
    float acc = 0.f;
    for (int n = ln; n < NN; n += 64) acc += u1a_s[n]*x[(size_t)(b*NN + n)*TT + t];
    for (int off = 32; off; off >>= 1) acc += __shfl_down(acc, off);
    if (ln == 0) xu_s[t] = acc;
  }
  if (tid < TT){
    float a = 0.f, c = 0.f;
    for (int f = 0; f < CC; ++f){
      float d = dt[b*CT + tid*CC + f];
      a += u3a[f]*d; c += u3b[f]*d;
    }
    du3a[b*TT + tid] = a;
    du3b[b*TT + tid] = c;
  }
  __syncthreads();
  float S1 = sums[0];
  for (int idx = tid; idx < CC*TT; idx += 256){
    int f = idx / TT, tp = idx % TT;
    float acc = 0.f;
    const float* wrow = u0_w + (f*TT + tp)*TT;
    for (int t = 0; t < TT; ++t) acc += wrow[t]*xu_s[t];
    w1a[b*CC*TT + idx] = acc + S1*(u0_b[f*TT + tp] + dt[b*CT + tp*CC + f]);
  }
}

// ---------------- rhs1[b][n][t'] = b0u3[t'] + du3a[b][t'] + sum_t w0u3[t'][t]*x[b,n,t]
__global__ __launch_bounds__(384) void k_rhs1(const float* __restrict__ x, const float* __restrict__ w0u3,
                      const float* __restrict__ b0u3, const float* __restrict__ du3a,
                      float* __restrict__ rhs1){
  __shared__ float xs[16*TT], w0_s[576], bd_s[TT];
  int b = blockIdx.y, n0 = blockIdx.x*16, tid = threadIdx.x;
  for (int i = tid; i < 576; i += 384) w0_s[i] = w0u3[i];
  if (tid < TT) bd_s[tid] = b0u3[tid] + du3a[b*TT + tid];
  xs[tid] = x[(size_t)(b*NN + n0)*TT + tid];
  __syncthreads();
  int nn = tid / TT, tp = tid % TT;
  float acc = bd_s[tp];
  const float* wr = w0_s + tp*TT;
  const float* xr = xs + nn*TT;
  for (int t = 0; t < TT; ++t) acc += wr[t]*xr[t];
  rhs1[(size_t)b*NN*TT + (n0 + nn)*TT + tp] = acc;
}

// ---------------- lhs[b][t][m] = sum_f u2[f,m]*w1[b][f][t]
__global__ void k_lhs(const float* __restrict__ u2, const float* __restrict__ w1,
                      float* __restrict__ lhs){
  int b = blockIdx.y;
  int j = blockIdx.x*256 + threadIdx.x;
  int t = j >> 9, m = j & 511;
  const float* w = w1 + b*CC*TT;
  float acc = 0.f;
  #pragma unroll 8
  for (int f = 0; f < CC; ++f) acc += u2[f*NN + m]*w[f*TT + t];
  lhs[(size_t)b*TT*NN + j] = acc;
}

// ---------------- partial prod over 64-n slices
__global__ __launch_bounds__(576) void k_prod(const float* __restrict__ lhs, const float* __restrict__ rhs,
                      float* __restrict__ pprod){
  __shared__ float lh[TT][64], rh[64][TT];
  int ns = blockIdx.x, b = blockIdx.y;
  int n0 = ns*64, tid = threadIdx.x;
  for (int i = tid; i < 1536; i += 576){ int t = i >> 6, n = i & 63; lh[t][n] = lhs[(size_t)b*TT*NN + t*NN + n0 + n]; }
  for (int i = tid; i < 1536; i += 576){ ((float*)rh)[i] = rhs[(size_t)b*NN*TT + n0*TT + i]; }
  __syncthreads();
  int t = tid / TT, s = tid % TT;
  float acc = 0.f;
  #pragma unroll 4
  for (int n = 0; n < 64; ++n) acc += lh[t][n]*rh[n][s];
  pprod[((size_t)(b*8 + ns))*576 + tid] = acc;
}

// ---------------- attention tail: sum partials -> sigmoid -> ve -> softmax(axis t)
__global__ void k_att_post2(const float* __restrict__ pprod, const float* __restrict__ ve,
                            const float* __restrict__ be, float* __restrict__ E){
  __shared__ float sig_s[TT*TT], E_s[TT*TT];
  int b = blockIdx.x, tid = threadIdx.x;
  float acc = 0.f;
  #pragma unroll
  for (int p = 0; p < 8; ++p) acc += pprod[((size_t)(b*8 + p))*576 + tid];
  sig_s[tid] = 1.f/(1.f + expf(-(acc + be[tid])));
  __syncthreads();
  {
    int t = tid / TT, r = tid % TT;
    float a = 0.f;
    for (int s = 0; s < TT; ++s) a += ve[t*TT + s]*sig_s[s*TT + r];
    E_s[tid] = a;
  }
  __syncthreads();
  if (tid < TT){
    int r = tid;
    float mx = -1e30f;
    for (int t = 0; t < TT; ++t) mx = fmaxf(mx, E_s[t*TT + r]);
    float sum = 0.f;
    for (int t = 0; t < TT; ++t) sum += expf(E_s[t*TT + r] - mx);
    float inv = 1.f/sum;
    for (int t = 0; t < TT; ++t) E[(size_t)b*TT*TT + t*TT + r] = expf(E_s[t*TT + r] - mx)*inv;
  }
}

// ---------------- lx/r2 for spatial attention
__global__ void k_xtat(const float* __restrict__ x, const float* __restrict__ E1,
                       const float* __restrict__ sw1, const float* __restrict__ sw2,
                       const float* __restrict__ sw3,
                       float* __restrict__ lx, float* __restrict__ r2){
  __shared__ float E_s[TT*TT], sw1_s[TT], sw2_s[TT];
  int b = blockIdx.x >> 1, half = blockIdx.x & 1, tid = threadIdx.x;
  for (int i = tid; i < 576; i += 256) E_s[i] = E1[(size_t)b*576 + i];
  if (tid < TT){ sw1_s[tid] = sw1[tid]; sw2_s[tid] = sw2[tid]; }
  __syncthreads();
  int n = half*256 + tid;
  float xr[TT];
  const float* xp = x + (size_t)(b*NN + n)*TT;
  for (int t = 0; t < TT; ++t) xr[t] = xp[t];
  float l = 0.f, r = 0.f;
  for (int s = 0; s < TT; ++s){
    float acc = 0.f;
    for (int t = 0; t < TT; ++t) acc += xr[t]*E_s[t*TT + s];
    l += acc*sw1_s[s];
    r += acc*sw2_s[s];
  }
  lx[b*NN + n] = l;
  r2[b*NN + n] = r*sw3[0];
}

// ---------------- s_vs fp32 -> bf16
__global__ void k_convS(const float* __restrict__ S, __hip_bfloat16* __restrict__ Sb){
  int i = (blockIdx.x*256 + threadIdx.x)*4;
  float4 v = *(const float4*)(S + i);
  Sb[i+0] = __float2bfloat16(v.x);
  Sb[i+1] = __float2bfloat16(v.y);
  Sb[i+2] = __float2bfloat16(v.z);
  Sb[i+3] = __float2bfloat16(v.w);
}

// ---------------- ST[b][k][n] = sum_m s_vs[n][m]*sigmoid(lx[m]*r2[k]+s_bs[m][k])  (MFMA)
__global__ __launch_bounds__(256) void k_S0(const __hip_bfloat16* __restrict__ svB,
                    const float* __restrict__ s_bs,
                    const float* __restrict__ lx, const float* __restrict__ r2,
                    float* __restrict__ ST){
  __shared__ __align__(16) short lA[128*32];
  __shared__ __align__(16) short lQ[128*32];
  __shared__ float sb_s[32][132];
  __shared__ float lx_s[32];
  int kt = blockIdx.x, nt = blockIdx.y, b = blockIdx.z;
  int n0 = nt*128, k0 = kt*128;
  int tid = threadIdx.x;
  int w = tid >> 6, l = tid & 63;
  int wr = w >> 1, wc = w & 1;
  int lrow = l & 15, lk = l >> 4;
  f32x4 acc[4][4];
  #pragma unroll
  for (int m = 0; m < 4; ++m)
    #pragma unroll
    for (int n = 0; n < 4; ++n) acc[m][n] = (f32x4){0.f,0.f,0.f,0.f};
  const float* lxb = lx + b*NN;
  int kq = tid >> 1;
  float r2q = r2[b*NN + k0 + kq];
  for (int m0 = 0; m0 < NN; m0 += 32){
    if (tid < 32) lx_s[tid] = lxb[m0 + tid];
    #pragma unroll
    for (int p = 0; p < 2; ++p){
      int c = p*4 + w;
      int off = c*512 + l*8;
      int row = off >> 5, col = off & 31;
      __builtin_amdgcn_global_load_lds(
        (const __attribute__((address_space(1))) void*)(svB + (size_t)(n0 + row)*NN + m0 + col),
        (__attribute__((address_space(3))) void*)(lA + c*512), 16, 0, 0);
    }
    #pragma unroll
    for (int q = 0; q < 4; ++q){
      int idx = tid + q*256;
      int mm = idx >> 5, k4 = idx & 31;
      float4 v = *(const float4*)(s_bs + (size_t)(mm)*NN + (size_t)m0*NN + k0 + k4*4);
      *(float4*)(&sb_s[mm][k4*4]) = v;
    }
    __syncthreads();
    #pragma unroll
    for (int c2 = 0; c2 < 2; ++c2){
      int mc = (tid & 1)*2 + c2;
      bf16x8 pk;
      #pragma unroll
      for (int j = 0; j < 8; ++j){
        int m = mc*8 + j;
        float v = lx_s[m]*r2q + sb_s[m][kq];
        float sg = 1.f/(1.f + __expf(-v));
        pk[j] = f2bf(sg);
      }
      *(bf16x8*)(lQ + kq*32 + mc*8) = pk;
    }
    __syncthreads();
    bf16x8 a[4], bv[4];
    #pragma unroll
    for (int m = 0; m < 4; ++m) a[m] = *(const bf16x8*)(lA + (wr*64 + m*16 + lrow)*32 + lk*8);
    #pragma unroll
    for (int n = 0; n < 4; ++n) bv[n] = *(const bf16x8*)(lQ + (wc*64 + n*16 + lrow)*32 + lk*8);
    #pragma unroll
    for (int m = 0; m < 4; ++m)
      #pragma unroll
      for (int n = 0; n < 4; ++n)
        acc[m][n] = __builtin_amdgcn_mfma_f32_16x16x32_bf16(a[m], bv[n], acc[m][n], 0, 0, 0);
    __syncthreads();
  }
  #pragma unroll
  for (int m = 0; m < 4; ++m){
    #pragma unroll
    for (int n = 0; n < 4; ++n){
      int col = k0 + wc*64 + n*16 + lrow;
      int row = n0 + wr*64 + m*16 + lk*4;
      float4 v; v.x = acc[m][n][0]; v.y = acc[m][n][1]; v.z = acc[m][n][2]; v.w = acc[m][n][3];
      *(float4*)(ST + (size_t)b*NN*NN + (size_t)col*NN + row) = v;
    }
  }
}

// ---------------- cheb[k][j][i] -> chebT[k][i][j] bf16
__global__ __launch_bounds__(256) void k_chebT(const float* __restrict__ cheb, short* __restrict__ chebT){
  __shared__ float ts[32][33];
  int jt = blockIdx.x, it = blockIdx.y, k = blockIdx.z;
  int tid = threadIdx.x;
  int c = tid & 31, r8 = tid >> 5;
  #pragma unroll
  for (int p = 0; p < 4; ++p){
    int r = p*8 + r8;
    ts[r][c] = cheb[((size_t)k*NN + jt*32 + r)*NN + it*32 + c];
  }
  __syncthreads();
  #pragma unroll
  for (int p = 0; p < 4; ++p){
    int r = p*8 + r8;   // i-row
    chebT[((size_t)k*NN + it*32 + r)*NN + jt*32 + c] = f2bf(ts[c][r]);
  }
}

// ---------------- xT[b][t][j] = bf16(x[b][j][t]), rows t=24..31 zero
__global__ __launch_bounds__(256) void k_xT(const float* __restrict__ x, short* __restrict__ xT){
  __shared__ float xs[512*25];
  int b = blockIdx.x, tid = threadIdx.x;
  for (int idx = tid; idx < NN*TT; idx += 256){
    int j = idx / TT, t = idx % TT;
    xs[j*25 + t] = x[(size_t)b*NN*TT + idx];
  }
  __syncthreads();
  for (int u = tid; u < 32*64; u += 256){
    int t = u >> 6, j8 = (u & 63)*8;
    bf16x8 o;
    if (t < TT){
      #pragma unroll
      for (int e = 0; e < 8; ++e) o[e] = f2bf(xs[(j8 + e)*25 + t]);
    } else {
      #pragma unroll
      for (int e = 0; e < 8; ++e) o[e] = 0;
    }
    *(bf16x8*)(xT + ((size_t)b*32 + t)*NN + j8) = o;
  }
}

// ---------------- row softmax of ST -> P bf16 (unnormalized exp) + invZ
__global__ __launch_bounds__(256) void k_expS(const float* __restrict__ ST, short* __restrict__ P,
                      float* __restrict__ invZ){
  int b = blockIdx.y;
  int row = blockIdx.x*4 + (threadIdx.x >> 6);
  int l = threadIdx.x & 63;
  const float* R = ST + (size_t)b*NN*NN + (size_t)row*NN;
  float4 v0 = *(const float4*)(R + l*8);
  float4 v1 = *(const float4*)(R + l*8 + 4);
  float mx = fmaxf(fmaxf(fmaxf(v0.x,v0.y),fmaxf(v0.z,v0.w)),
                   fmaxf(fmaxf(v1.x,v1.y),fmaxf(v1.z,v1.w)));
  for (int off = 32; off; off >>= 1) mx = fmaxf(mx, __shfl_xor(mx, off));
  v0.x = __expf(v0.x-mx); v0.y = __expf(v0.y-mx); v0.z = __expf(v0.z-mx); v0.w = __expf(v0.w-mx);
  v1.x = __expf(v1.x-mx); v1.y = __expf(v1.y-mx); v1.z = __expf(v1.z-mx); v1.w = __expf(v1.w-mx);
  float s = v0.x+v0.y+v0.z+v0.w+v1.x+v1.y+v1.z+v1.w;
  for (int off = 32; off; off >>= 1) s += __shfl_xor(s, off);
  bf16x8 o;
  o[0]=f2bf(v0.x); o[1]=f2bf(v0.y); o[2]=f2bf(v0.z); o[3]=f2bf(v0.w);
  o[4]=f2bf(v1.x); o[5]=f2bf(v1.y); o[6]=f2bf(v1.z); o[7]=f2bf(v1.w);
  *(bf16x8*)(P + ((size_t)b*NN + row)*NN + l*8) = o;
  if (l == 0) invZ[b*NN + row] = 1.f/s;
}

// ---------------- tmp_kc[b] = (P[b] .* chebT[kc]) @ xT[b]^T, scaled by invZ  (MFMA)
__global__ __launch_bounds__(256) void k_tmpG(const short* __restrict__ P, const short* __restrict__ chebT,
                      const short* __restrict__ xT, const float* __restrict__ invZ,
                      float* __restrict__ tmp){
  __shared__ __align__(16) short lP[128*32];
  __shared__ __align__(16) short lC[128*32];
  __shared__ __align__(16) short lX[32*32];
  __shared__ float iz_s[128];
  int it = blockIdx.x, kc = blockIdx.y, b = blockIdx.z;
  int i0 = it*128;
  int tid = threadIdx.x;
  int w = tid >> 6, l = tid & 63;
  int lrow = l & 15, lk = l >> 4;
  if (tid < 128) iz_s[tid] = invZ[b*NN + i0 + tid];
  f32x4 acc[2][2];
  #pragma unroll
  for (int m = 0; m < 2; ++m)
    #pragma unroll
    for (int n = 0; n < 2; ++n) acc[m][n] = (f32x4){0.f,0.f,0.f,0.f};
  for (int ks = 0; ks < 16; ++ks){
    int k0 = ks*32;
    #pragma unroll
    for (int p = 0; p < 2; ++p){
      int c = p*4 + w;
      int off = c*512 + l*8;
      int row = off >> 5, col = off & 31;
      __builtin_amdgcn_global_load_lds(
        (const __attribute__((address_space(1))) void*)(P + ((size_t)b*NN + i0 + row)*NN + k0 + col),
        (__attribute__((address_space(3))) void*)(lP + c*512), 16, 0, 0);
      __builtin_amdgcn_global_load_lds(
        (const __attribute__((address_space(1))) void*)(chebT + ((size_t)kc*NN + i0 + row)*NN + k0 + col),
        (__attribute__((address_space(3))) void*)(lC + c*512), 16, 0, 0);
    }
    if (w < 2){
      int off = w*512 + l*8;
      int row = off >> 5, col = off & 31;
      __builtin_amdgcn_global_load_lds(
        (const __attribute__((address_space(1))) void*)(xT + ((size_t)b*32 + row)*NN + k0 + col),
        (__attribute__((address_space(3))) void*)(lX + w*512), 16, 0, 0);
    }
    __syncthreads();
    bf16x8 a[2], bv[2];
    #pragma unroll
    for (int m = 0; m < 2; ++m){
      int r = w*32 + m*16 + lrow;
      bf16x8 pp = *(const bf16x8*)(lP + r*32 + lk*8);
      bf16x8 cc = *(const bf16x8*)(lC + r*32 + lk*8);
      bf16x8 af;
      #pragma unroll
      for (int e = 0; e < 8; ++e) af[e] = f2bf(bf2f(pp[e])*bf2f(cc[e]));
      a[m] = af;
    }
    #pragma unroll
    for (int n = 0; n < 2; ++n) bv[n] = *(const bf16x8*)(lX + (n*16 + lrow)*32 + lk*8);
    #pragma unroll
    for (int m = 0; m < 2; ++m)
      #pragma unroll
      for (int n = 0; n < 2; ++n)
        acc[m][n] = __builtin_amdgcn_mfma_f32_16x16x32_bf16(a[m], bv[n], acc[m][n], 0, 0, 0);
    __syncthreads();
  }
  #pragma unroll
  for (int m = 0; m < 2; ++m){
    #pragma unroll
    for (int n = 0; n < 2; ++n){
      int t = n*16 + lrow;
      if (t < TT){
        #pragma unroll
        for (int j = 0; j < 4; ++j){
          int ir = w*32 + m*16 + lk*4 + j;
          tmp[((size_t)(kc*BB + b)*NN + i0 + ir)*TT + t] = acc[m][n][j]*iz_s[ir];
        }
      }
    }
  }
}

// ---------------- att2: per-16-n-tile two-pass: rhsg + partial w1g
__global__ __launch_bounds__(384) void k_gsum(const float* __restrict__ tmp, const float* __restrict__ theta,
                      const float* __restrict__ u1b, const float* __restrict__ u3b,
                      const float* __restrict__ du3b,
                      float* __restrict__ rhsg, float* __restrict__ pw1g){
  __shared__ float A0[16*TT], A1[16*TT], A2[16*TT], th_s[192], u3_s[CC], u1_s[16], du_s[TT];
  int nt = blockIdx.x, b = blockIdx.y;
  int n0 = nt*16, tid = threadIdx.x;
  for (int i = tid; i < 192; i += 384) th_s[i] = theta[i];
  if (tid < CC) u3_s[tid] = u3b[tid];
  if (tid < 16) u1_s[tid] = u1b[n0 + tid];
  if (tid < TT) du_s[tid] = du3b[b*TT + tid];
  A0[tid] = tmp[((size_t)(0*BB + b)*NN + n0)*TT + tid];
  A1[tid] = tmp[((size_t)(1*BB + b)*NN + n0)*TT + tid];
  A2[tid] = tmp[((size_t)(2*BB + b)*NN + n0)*TT + tid];
  __syncthreads();
  {
    int nn = tid / TT, t = tid % TT;
    float a0 = A0[nn*TT + t], a1 = A1[nn*TT + t], a2 = A2[nn*TT + t];
    float acc = du_s[t];
    #pragma unroll 8
    for (int f = 0; f < CC; ++f){
      float v = th_s[f]*a0 + th_s[64 + f]*a1 + th_s[128 + f]*a2;
      acc += u3_s[f]*fmaxf(v, 0.f);
    }
    rhsg[(size_t)b*NN*TT + (n0 + nn)*TT + t] = acc;
  }
  #pragma unroll
  for (int p = 0; p < 4; ++p){
    int o = tid + p*384;
    int f = o / TT, t = o % TT;
    float t0 = th_s[f], t1 = th_s[64 + f], t2 = th_s[128 + f];
    float acc = 0.f;
    #pragma unroll
    for (int m = 0; m < 16; ++m){
      float v = t0*A0[m*TT + t] + t1*A1[m*TT + t] + t2*A2[m*TT + t];
      acc += u1_s[m]*fmaxf(v, 0.f);
    }
    pw1g[((size_t)(b*32 + nt))*CC*TT + o] = acc;
  }
}

// ---------------- reduce partial w1g + S2*dt
__global__ void k_w1g_red(const float* __restrict__ pw1g, const float* __restrict__ dt,
                          const float* __restrict__ sums, float* __restrict__ w1g){
  int b = blockIdx.x, tid = threadIdx.x;
  float S2 = sums[1];
  for (int o = tid; o < CC*TT; o += 256){
    int f = o / TT, t = o % TT;
    float acc = 0.f;
    for (int nt = 0; nt < 32; ++nt) acc += pw1g[((size_t)(b*32 + nt))*CC*TT + o];
    w1g[b*CC*TT + o] = acc + S2*dt[b*CT + t*CC + f];
  }
}

// ---------------- g2 (bf16) = relu(theta·tmp) @ E2
__global__ void k_g2(const float* __restrict__ tmp, const float* __restrict__ E2,
                     const float* __restrict__ theta, __hip_bfloat16* __restrict__ g2){
  __shared__ float E_s[TT*TT], th_s[192], tr[3*4*TT], g_s[4*CT];
  int b = blockIdx.y, n0 = blockIdx.x*4, tid = threadIdx.x;
  for (int i = tid; i < 576; i += 256) E_s[i] = E2[(size_t)b*576 + i];
  for (int i = tid; i < 192; i += 256) th_s[i] = theta[i];
  for (int i = tid; i < 288; i += 256){
    int k = i / 96, rem = i % 96, nn = rem / TT, s = rem % TT;
    tr[i] = tmp[((size_t)(k*BB + b)*NN + n0 + nn)*TT + s];
  }
  __syncthreads();
  for (int idx = tid; idx < 4*CT; idx += 256){
    int nn = idx / CT, rem = idx % CT, f = rem / TT, s = rem % TT;
    float v = th_s[f]*tr[nn*TT + s] + th_s[64 + f]*tr[96 + nn*TT + s] + th_s[128 + f]*tr[192 + nn*TT + s];
    g_s[idx] = fmaxf(v, 0.f);
  }
  __syncthreads();
  for (int idx = tid; idx < 4*CT; idx += 256){
    int nn = idx / CT, rem = idx % CT, f = rem / TT, t = rem % TT;
    float acc = 0.f;
    const float* gr = g_s + nn*CT + f*TT;
    for (int s = 0; s < TT; ++s) acc += gr[s]*E_s[s*TT + t];
    g2[(size_t)(b*NN + n0 + nn)*CT + rem] = __float2bfloat16(acc);
  }
}

// ---------------- l1_w fp32 -> bf16
__global__ void k_convW(const float* __restrict__ W, __hip_bfloat16* __restrict__ Wb){
  int i = (blockIdx.x*256 + threadIdx.x)*4;
  float4 v = *(const float4*)(W + i);
  Wb[i+0] = __float2bfloat16(v.x);
  Wb[i+1] = __float2bfloat16(v.y);
  Wb[i+2] = __float2bfloat16(v.z);
  Wb[i+3] = __float2bfloat16(v.w);
}

// ---------------- tlin(bf16) = A(16384x1536,bf16) @ W^T(bf16) + l1_b  — XCD-swizzled grid
__global__ __launch_bounds__(256) void k_gemm_bf16(const __hip_bfloat16* __restrict__ A,
                      const __hip_bfloat16* __restrict__ W,
                      const float* __restrict__ bias, __hip_bfloat16* __restrict__ Cout){
  // bijective XCD swizzle: 1536 blocks = 8 XCDs x 192
  int bid = blockIdx.x;
  int nb = (bid & 7)*192 + (bid >> 3);
  int o0 = (nb % 12)*128, i0 = (nb / 12)*128;
  __shared__ __align__(16) short lA[128*32];
  __shared__ __align__(16) short lB[128*32];
  int tid = threadIdx.x;
  int w = tid >> 6, l = tid & 63;
  int wr = w >> 1, wc = w & 1;
  f32x4 acc[4][4];
  #pragma unroll
  for (int m = 0; m < 4; ++m)
    #pragma unroll
    for (int n = 0; n < 4; ++n) acc[m][n] = (f32x4){0.f,0.f,0.f,0.f};
  int lrow = l & 15, lk = (l >> 4);
  for (int k0 = 0; k0 < CT; k0 += 32){
    #pragma unroll
    for (int p = 0; p < 2; ++p){
      int c = p*4 + w;
      int off = c*512 + l*8;
      int row = off >> 5, col = off & 31;
      __builtin_amdgcn_global_load_lds(
        (const __attribute__((address_space(1))) void*)(A + (size_t)(i0 + row)*CT + k0 + col),
        (__attribute__((address_space(3))) void*)(lA + c*512), 16, 0, 0);
      __builtin_amdgcn_global_load_lds(
        (const __attribute__((address_space(1))) void*)(W + (size_t)(o0 + row)*CT + k0 + col),
        (__attribute__((address_space(3))) void*)(lB + c*512), 16, 0, 0);
    }
    __syncthreads();
    bf16x8 a[4], bv[4];
    #pragma unroll
    for (int m = 0; m < 4; ++m) a[m] = *(const bf16x8*)(lA + (wr*64 + m*16 + lrow)*32 + lk*8);
    #pragma unroll
    for (int n = 0; n < 4; ++n) bv[n] = *(const bf16x8*)(lB + (wc*64 + n*16 + lrow)*32 + lk*8);
    #pragma unroll
    for (int m = 0; m < 4; ++m)
      #pragma unroll
      for (int n = 0; n < 4; ++n)
        acc[m][n] = __builtin_amdgcn_mfma_f32_16x16x32_bf16(a[m], bv[n], acc[m][n], 0, 0, 0);
    __syncthreads();
  }
  #pragma unroll
  for (int m = 0; m < 4; ++m){
    #pragma unroll
    for (int n = 0; n < 4; ++n){
      int o = o0 + wc*64 + n*16 + lrow;
      float bo = bias[o];
      #pragma unroll
      for (int j = 0; j < 4; ++j){
        int i = i0 + wr*64 + m*16 + lk*4 + j;
        Cout[(size_t)i*CT + o] = __float2bfloat16(acc[m][n][j] + bo);
      }
    }
  }
}

// ---------------- reshape + residual + relu + LayerNorm (LDS-staged, bf16 tlin)
__global__ __launch_bounds__(128) void k_final(const __hip_bfloat16* __restrict__ tlin, const float* __restrict__ x,
                      const float* __restrict__ res_w, const float* __restrict__ res_b,
                      const float* __restrict__ ln_g, const float* __restrict__ ln_b,
                      float* __restrict__ out){
  __shared__ float Ls[64][132];
  __shared__ float rw_s[64], rb_s[64], lg_s[64], lb_s[64];
  int ot = blockIdx.x, dlt = blockIdx.y, b = blockIdx.z;
  int o0 = ot*128, tid = threadIdx.x;
  if (tid < 64){ rw_s[tid]=res_w[tid]; rb_s[tid]=res_b[tid]; lg_s[tid]=ln_g[tid]; lb_s[tid]=ln_b[tid]; }
  const __hip_bfloat16* tb = tlin + (size_t)b*NN*CT;
  #pragma unroll 4
  for (int c = 0; c < 64; ++c)
    Ls[c][tid] = __bfloat162float(tb[(size_t)(c*8 + dlt)*CT + o0 + tid]);
  __syncthreads();
  int p = dlt*CT + o0 + tid;
  int np = p / TT, tp = p % TT;
  float xv = x[(size_t)(b*NN + np)*TT + tp];
  float z[CC];
  float sum = 0.f, sq = 0.f;
  #pragma unroll
  for (int c = 0; c < CC; ++c){
    float v = Ls[c][tid] + xv*rw_s[c] + rb_s[c];
    v = fmaxf(v, 0.f);
    z[c] = v; sum += v; sq += v*v;
  }
  float mu = sum*(1.f/64.f);
  float var = sq*(1.f/64.f) - mu*mu;
  float rstd = rsqrtf(var + 1e-5f);
  float* ob = out + (size_t)(b*NN + np)*CC*TT + tp;
  #pragma unroll
  for (int c = 0; c < CC; ++c)
    ob[c*TT] = (z[c] - mu)*rstd*lg_s[c] + lb_s[c];
}

extern "C" void kernel_launch(void* const* d_in, const int* in_sizes, int n_in,
                              void* d_out, int out_size, void* d_ws, size_t ws_size,
                              hipStream_t stream){
  const float* x    = (const float*)d_in[0];
  const float* y    = (const float*)d_in[1];
  const float* tl_w = (const float*)d_in[2];
  const float* tl_b = (const float*)d_in[3];
  const float* u0_w = (const float*)d_in[4];
  const float* u0_b = (const float*)d_in[5];
  const float* u1a  = (const float*)d_in[6];
  const float* u2a  = (const float*)d_in[7];
  const float* u3a  = (const float*)d_in[8];
  const float* be_a = (const float*)d_in[9];
  const float* ve_a = (const float*)d_in[10];
  const float* u1b  = (const float*)d_in[11];
  const float* u2b  = (const float*)d_in[12];
  const float* u3b  = (const float*)d_in[13];
  const float* be_b = (const float*)d_in[14];
  const float* ve_b = (const float*)d_in[15];
  const float* sw1  = (const float*)d_in[16];
  const float* sw2  = (const float*)d_in[17];
  const float* sw3  = (const float*)d_in[18];
  const float* s_bs = (const float*)d_in[19];
  const float* s_vs = (const float*)d_in[20];
  const float* cheb = (const float*)d_in[21];
  const float* theta= (const float*)d_in[22];
  const float* l1_w = (const float*)d_in[23];
  const float* l1_b = (const float*)d_in[24];
  const float* res_w= (const float*)d_in[25];
  const float* res_b= (const float*)d_in[26];
  const float* ln_g = (const float*)d_in[27];
  const float* ln_b = (const float*)d_in[28];
  float* out = (float*)d_out;
  float* ws  = (float*)d_ws;

  // ws layout (floats). Alias lifetimes (serial stream order):
  //  - WB/yB/pdt (dt pipeline): big[0..3.79M), dead after k_dtred (before k_S0 writes ST).
  //  - ST: big[0..8388608). Pb/xTb/iZ/chT: big[8388608..13254656) — dead after k_tmpG.
  //  - tlin (bf16, 12.58M floats worth): big[0..12582912) — overlaps ST (dead) and
  //    part of Pb (dead); written by k_gemm, read by k_final.
  //  - Wb (bf16, spans lhs1+rhs1+lhsg): k_convW only after E2 (2nd k_att_post2).
  //  - g2b lives in d_out: dead once k_gemm consumed it; k_final rewrites d_out.
  float* dt   = ws;               // 49152
  float* E    = dt   + 49152;     // 18432 (E1 then E2)
  float* lxp  = E    + 18432;     // 16384
  float* r2p  = lxp  + 16384;     // 16384
  float* w0u3 = r2p  + 16384;     // 640
  float* b0u3 = w0u3 + 640;       // 64
  float* sums = b0u3 + 64;        // 64
  float* du3a = sums + 64;        // 768
  float* du3b = du3a + 768;       // 768
  float* w1a  = du3b + 768;       // 49152
  float* w1g  = w1a  + 49152;     // 49152
  float* lhs1 = w1g  + 49152;     // 393216
  float* rhs1 = lhs1 + 393216;    // 393216
  float* lhsg = rhs1 + 393216;    // 393216
  float* rhsg = lhsg + 393216;    // 393216
  float* svBf = rhsg + 393216;    // 131072 (bf16 512x512)
  float* ppr  = svBf + 131072;    // 147456
  float* tmp  = ppr  + 147456;    // 1179648
  float* big  = tmp  + 1179648;   // 25165824 floats
  float* ST   = big;              // 8388608
  float* pw1g = big;
  __hip_bfloat16* tlin = (__hip_bfloat16*)big;               // bf16 16384x1536
  __hip_bfloat16* WB = (__hip_bfloat16*)big;                 // dt pipeline (early)
  __hip_bfloat16* yB = (__hip_bfloat16*)(big + 2801664);
  float* pdt = big + 2801664 + 58368;
  short* Pb  = (short*)(big + 8388608);                      // 8388608 shorts
  short* xTb = (short*)(big + 8388608 + 4194304);            // 524288 shorts
  float* iZ  = big + 8388608 + 4194304 + 262144;             // 16384 floats
  short* chT = (short*)(big + 8388608 + 4194304 + 262144 + 16384);  // 786432 shorts
  __hip_bfloat16* svB = (__hip_bfloat16*)svBf;
  __hip_bfloat16* Wb  = (__hip_bfloat16*)lhs1;   // valid only after E2
  __hip_bfloat16* g2b = (__hip_bfloat16*)d_out;

  k_prep0<<<dim3(1), dim3(576), 0, stream>>>(u0_w, u0_b, u1a, u3a, u1b, w0u3, b0u3, sums);
  k_convS<<<dim3(256), dim3(256), 0, stream>>>(s_vs, svB);
  k_convPad<<<dim3((32*(YP/8) + 255)/256), dim3(256), 0, stream>>>(y, yB, 32);
  k_convPad<<<dim3((1536*(YP/8) + 255)/256), dim3(256), 0, stream>>>(tl_w, WB, 1536);
  k_dtgemm<<<dim3(6, 19), dim3(256), 0, stream>>>(yB, WB, pdt);
  k_dtred<<<dim3(192), dim3(256), 0, stream>>>(pdt, tl_b, dt);
  k_chebT<<<dim3(16, 16, 3), dim3(256), 0, stream>>>(cheb, chT);
  k_xT<<<dim3(32), dim3(256), 0, stream>>>(x, xTb);
  k_small<<<dim3(32), dim3(256), 0, stream>>>(x, dt, u0_w, u0_b, u1a, u3a, u3b, sums, w1a, du3a, du3b);
  k_rhs1<<<dim3(32, 32), dim3(384), 0, stream>>>(x, w0u3, b0u3, du3a, rhs1);
  k_lhs<<<dim3(48, 32), dim3(256), 0, stream>>>(u2a, w1a, lhs1);
  k_prod<<<dim3(8, 32), dim3(576), 0, stream>>>(lhs1, rhs1, ppr);
  k_att_post2<<<dim3(32), dim3(576), 0, stream>>>(ppr, ve_a, be_a, E);
  k_xtat<<<dim3(64), dim3(256), 0, stream>>>(x, E, sw1, sw2, sw3, lxp, r2p);
  k_S0<<<dim3(4, 4, 32), dim3(256), 0, stream>>>(svB, s_bs, lxp, r2p, ST);
  k_expS<<<dim3(128, 32), dim3(256), 0, stream>>>(ST, Pb, iZ);
  k_tmpG<<<dim3(4, 3, 32), dim3(256), 0, stream>>>(Pb, chT, xTb, iZ, tmp);
  k_gsum<<<dim3(32, 32), dim3(384), 0, stream>>>(tmp, theta, u1b, u3b, du3b, rhsg, pw1g);
  k_w1g_red<<<dim3(32), dim3(256), 0, stream>>>(pw1g, dt, sums, w1g);
  k_lhs<<<dim3(48, 32), dim3(256), 0, stream>>>(u2b, w1g, lhsg);
  k_prod<<<dim3(8, 32), dim3(576), 0, stream>>>(lhsg, rhsg, ppr);
  k_att_post2<<<dim3(32), dim3(576), 0, stream>>>(ppr, ve_b, be_b, E);
  k_convW<<<dim3(2304), dim3(256), 0, stream>>>(l1_w, Wb);   // after E2: lhs1/rhs1/lhsg dead
  k_g2<<<dim3(128, 32), dim3(256), 0, stream>>>(tmp, E, theta, g2b);
  k_gemm_bf16<<<dim3(1536), dim3(256), 0, stream>>>(g2b, Wb, l1_b, tlin);
  k_final<<<dim3(12, 8, 32), dim3(128), 0, stream>>>(tlin, x, res_w, res_b, ln_g, ln_b, out);
}